// Round 1
// baseline (522.543 us; speedup 1.0000x reference)
//
#include <hip/hip_runtime.h>
#include <stdint.h>

#define BB   16
#define NN   1024
#define KSEL 170   // (32*32)/6

// ---------------- K1: exact k-th-largest per row (radix select) + packed mask --------
__global__ __launch_bounds__(256) void k_topk_mask(
    const float* __restrict__ adj, uint64_t* __restrict__ mask)
{
    const int row = blockIdx.x;                 // b*N + u
    const float* a = adj + (size_t)row * NN;
    __shared__ uint32_t keys[NN];
    __shared__ uint32_t hist[256];
    __shared__ uint32_t wtot[4];
    __shared__ uint32_t s_prefix, s_k;
    const int t = threadIdx.x;
    const int lane = t & 63, w = t >> 6;

    for (int i = t; i < NN; i += 256) {
        uint32_t u = __float_as_uint(a[i]);
        keys[i] = u ^ ((u >> 31) ? 0xFFFFFFFFu : 0x80000000u);   // order-preserving map
    }
    if (t == 0) { s_prefix = 0u; s_k = KSEL; }
    __syncthreads();

    for (int pass = 0; pass < 4; ++pass) {
        const int shift = 24 - 8 * pass;
        const uint32_t prefix = s_prefix;
        const uint32_t kk = s_k;
        const uint32_t hi_mask = pass ? (0xFFFFFFFFu << (shift + 8)) : 0u;
        hist[t] = 0u;
        __syncthreads();
        for (int i = t; i < NN; i += 256) {
            uint32_t kv = keys[i];
            if ((kv & hi_mask) == prefix)
                atomicAdd(&hist[(kv >> shift) & 255], 1u);
        }
        __syncthreads();
        uint32_t c = hist[t];
        uint32_t s = c;
        #pragma unroll
        for (int off = 1; off < 64; off <<= 1) {     // in-wave inclusive suffix sum
            uint32_t vsh = __shfl_down(s, off);
            s += (lane + off < 64) ? vsh : 0u;
        }
        if (lane == 0) wtot[w] = s;
        __syncthreads();
        uint32_t above = 0;
        for (int w2 = w + 1; w2 < 4; ++w2) above += wtot[w2];
        uint32_t cum_incl = s + above;               // count of bins >= t
        uint32_t cum_excl = cum_incl - c;            // count of bins >  t
        if (cum_excl < kk && kk <= cum_incl) {       // exactly one winner
            s_prefix = prefix | ((uint32_t)t << shift);
            s_k = kk - cum_excl;
        }
        __syncthreads();
    }

    const uint32_t thr_key = s_prefix;               // key of k-th largest (exact)
    #pragma unroll
    for (int i = 0; i < 4; ++i) {
        uint32_t kv = keys[i * 256 + t];
        bool pred = (kv >= thr_key) && (kv > 0x80000000u);   // adj>=thr && adj>0
        uint64_t bal = __ballot(pred);
        if (lane == 0) mask[(size_t)row * 16 + i * 4 + w] = bal;
    }
}

// ---------------- K2: f = x@W, res = x@rW, el/er dots ------------------
template<int K>
__global__ __launch_bounds__(256) void k_features(
    const float* __restrict__ x,   // [B*N][K]
    const float* __restrict__ W,   // [K][256]
    const float* __restrict__ rW,  // [K][256]
    const float* __restrict__ al,  // [256]
    const float* __restrict__ ar,  // [256]
    float* __restrict__ f,         // [B*N][256]
    float* __restrict__ res,       // [B*N][256]  (may alias x: rows read to LDS first)
    float* __restrict__ el,        // [B*N][4]
    float* __restrict__ er)        // [B*N][4]
{
    __shared__ float xs[K * 16];   // [k][i] transposed tile of 16 node rows
    const int t = threadIdx.x;
    const size_t n0 = (size_t)blockIdx.x * 16;
    const float* xb = x + n0 * K;
    for (int idx = t; idx < 16 * K; idx += 256)
        xs[(idx % K) * 16 + (idx / K)] = xb[idx];
    __syncthreads();

    float accf[16], accr[16];
    #pragma unroll
    for (int i = 0; i < 16; ++i) { accf[i] = 0.f; accr[i] = 0.f; }
    const int o = t;
    for (int k = 0; k < K; ++k) {
        float wv = W[k * 256 + o];
        float rv = rW[k * 256 + o];
        const float4* xr = (const float4*)&xs[k * 16];
        float4 x0 = xr[0], x1 = xr[1], x2 = xr[2], x3 = xr[3];
        accf[0]  += x0.x * wv;  accr[0]  += x0.x * rv;
        accf[1]  += x0.y * wv;  accr[1]  += x0.y * rv;
        accf[2]  += x0.z * wv;  accr[2]  += x0.z * rv;
        accf[3]  += x0.w * wv;  accr[3]  += x0.w * rv;
        accf[4]  += x1.x * wv;  accr[4]  += x1.x * rv;
        accf[5]  += x1.y * wv;  accr[5]  += x1.y * rv;
        accf[6]  += x1.z * wv;  accr[6]  += x1.z * rv;
        accf[7]  += x1.w * wv;  accr[7]  += x1.w * rv;
        accf[8]  += x2.x * wv;  accr[8]  += x2.x * rv;
        accf[9]  += x2.y * wv;  accr[9]  += x2.y * rv;
        accf[10] += x2.z * wv;  accr[10] += x2.z * rv;
        accf[11] += x2.w * wv;  accr[11] += x2.w * rv;
        accf[12] += x3.x * wv;  accr[12] += x3.x * rv;
        accf[13] += x3.y * wv;  accr[13] += x3.y * rv;
        accf[14] += x3.z * wv;  accr[14] += x3.z * rv;
        accf[15] += x3.w * wv;  accr[15] += x3.w * rv;
    }
    #pragma unroll
    for (int i = 0; i < 16; ++i) {
        f[(n0 + i) * 256 + o]   = accf[i];
        res[(n0 + i) * 256 + o] = accr[i];
    }
    // el/er: wave w handles head h=w (o = h*64+d), reduce over d (64 lanes)
    const float alv = al[o], arv = ar[o];
    const int lane = t & 63, h = t >> 6;
    #pragma unroll
    for (int i = 0; i < 16; ++i) {
        float pe = accf[i] * alv;
        float pr = accf[i] * arv;
        #pragma unroll
        for (int off = 32; off; off >>= 1) {
            pe += __shfl_xor(pe, off);
            pr += __shfl_xor(pr, off);
        }
        if (lane == 0) {
            el[(n0 + i) * 4 + h] = pe;
            er[(n0 + i) * 4 + h] = pr;
        }
    }
}

// ---------------- K3: unmasked max over src nodes of el ----------------
__global__ __launch_bounds__(256) void k_elmax(
    const float* __restrict__ el, float* __restrict__ elmax)
{
    const int b = blockIdx.x >> 2, h = blockIdx.x & 3;
    const int t = threadIdx.x;
    float m = -1e30f;
    for (int n = t; n < NN; n += 256)
        m = fmaxf(m, el[((size_t)b * NN + n) * 4 + h]);
    #pragma unroll
    for (int off = 32; off; off >>= 1) m = fmaxf(m, __shfl_xor(m, off));
    __shared__ float sm[4];
    if ((t & 63) == 0) sm[t >> 6] = m;
    __syncthreads();
    if (t == 0) elmax[blockIdx.x] = fmaxf(fmaxf(sm[0], sm[1]), fmaxf(sm[2], sm[3]));
}

// ---------------- K4: masked softmax over u + PV + residual + bias (+ELU) ------
template<int ELU_ON>
__global__ __launch_bounds__(256) void k_attn(
    const float* __restrict__ f,      // [B*N][256]
    const float* __restrict__ res,    // [B*N][256]
    const float* __restrict__ el,     // [B*N][4]
    const float* __restrict__ er,     // [B*N][4]
    const float* __restrict__ elmax,  // [B][4]
    const uint64_t* __restrict__ mask,// [B*N][16]
    const float* __restrict__ bias,   // [256]
    float* __restrict__ out)          // [B*N][256] (may alias res: in-place per element)
{
    const int vt = blockIdx.x;        // v-tile (16 of 64)
    const int h  = blockIdx.y;
    const int b  = blockIdx.z;
    const int v0 = vt * 64;
    const int t = threadIdx.x;
    const int lane = t & 63, g = t >> 6;   // staging mapping
    const int dq = t & 15, vq = t >> 4;    // FMA mapping (4v x 4d per thread)

    __shared__ __align__(16) float p_lds[64][64];
    __shared__ __align__(16) float f_lds[64][64];
    __shared__ float c_lds[64];
    __shared__ float er_lds[64];
    __shared__ float el_lds[64];
    __shared__ float den_lds[4][64];
    __shared__ float den_fin[64];

    const size_t bN = (size_t)b * NN;
    if (t < 64) {
        float erv = er[(bN + v0 + t) * 4 + h];
        er_lds[t] = erv;
        float e = elmax[b * 4 + h] + erv;          // unmasked max of el + er[v]
        c_lds[t] = e > 0.f ? e : 0.2f * e;         // lrelu is monotone -> valid shift
    }

    float acc[4][4];
    #pragma unroll
    for (int i = 0; i < 4; ++i)
        #pragma unroll
        for (int j = 0; j < 4; ++j) acc[i][j] = 0.f;
    float den_reg = 0.f;

    for (int u0 = 0; u0 < NN; u0 += 64) {
        __syncthreads();                            // protect LDS vs prev reads
        // stage f tile [64u][64d]
        const float* fb = f + (bN + u0) * 256 + h * 64;
        #pragma unroll
        for (int r = 0; r < 4; ++r) {
            int idx = t + r * 256;
            int u = idx >> 4, q = idx & 15;
            ((float4*)&f_lds[u][0])[q] = ((const float4*)(fb + (size_t)u * 256))[q];
        }
        if (t < 64) el_lds[t] = el[(bN + u0 + t) * 4 + h];
        __syncthreads();
        // stage p tile: thread owns v=lane, u-range [g*16, g*16+16)
        {
            const float cv  = c_lds[lane];
            const float erv = er_lds[lane];
            float pr = 0.f;
            #pragma unroll
            for (int jj = 0; jj < 16; ++jj) {
                int u_l = g * 16 + jj;
                uint64_t wd = mask[(bN + u0 + u_l) * 16 + vt];
                float e = el_lds[u_l] + erv;
                float lr = e > 0.f ? e : 0.2f * e;
                float pv = ((wd >> lane) & 1ull) ? __expf(lr - cv) : 0.f;
                p_lds[u_l][lane] = pv;
                pr += pv;
            }
            den_reg += pr;
        }
        __syncthreads();
        // PV: 16 FMA per 2 broadcast b128 reads
        #pragma unroll 2
        for (int u_l = 0; u_l < 64; ++u_l) {
            float4 pv = ((const float4*)&p_lds[u_l][0])[vq];
            float4 fv = ((const float4*)&f_lds[u_l][0])[dq];
            acc[0][0] += pv.x * fv.x; acc[0][1] += pv.x * fv.y; acc[0][2] += pv.x * fv.z; acc[0][3] += pv.x * fv.w;
            acc[1][0] += pv.y * fv.x; acc[1][1] += pv.y * fv.y; acc[1][2] += pv.y * fv.z; acc[1][3] += pv.y * fv.w;
            acc[2][0] += pv.z * fv.x; acc[2][1] += pv.z * fv.y; acc[2][2] += pv.z * fv.z; acc[2][3] += pv.z * fv.w;
            acc[3][0] += pv.w * fv.x; acc[3][1] += pv.w * fv.y; acc[3][2] += pv.w * fv.z; acc[3][3] += pv.w * fv.w;
        }
    }
    den_lds[g][lane] = den_reg;
    __syncthreads();
    if (t < 64) {
        float dsum = den_lds[0][t] + den_lds[1][t] + den_lds[2][t] + den_lds[3][t];
        den_fin[t] = fmaxf(dsum, 1e-9f);            // jnp.clip(sum, 1e-9)
    }
    __syncthreads();

    const float4 bv = ((const float4*)(bias + h * 64))[dq];
    #pragma unroll
    for (int i = 0; i < 4; ++i) {
        const int v = v0 + vq * 4 + i;
        const float dn = den_fin[vq * 4 + i];
        const float4 rv = ((const float4*)(res + (bN + v) * 256 + h * 64))[dq];
        float4 ov;
        ov.x = acc[i][0] / dn + rv.x + bv.x;
        ov.y = acc[i][1] / dn + rv.y + bv.y;
        ov.z = acc[i][2] / dn + rv.z + bv.z;
        ov.w = acc[i][3] / dn + rv.w + bv.w;
        if (ELU_ON) {
            ov.x = ov.x > 0.f ? ov.x : __expf(ov.x) - 1.f;
            ov.y = ov.y > 0.f ? ov.y : __expf(ov.y) - 1.f;
            ov.z = ov.z > 0.f ? ov.z : __expf(ov.z) - 1.f;
            ov.w = ov.w > 0.f ? ov.w : __expf(ov.w) - 1.f;
        }
        ((float4*)(out + (bN + v) * 256 + h * 64))[dq] = ov;
    }
}

// ---------------- K5: mean over heads -> d_out ----------------
__global__ __launch_bounds__(256) void k_headmean(
    const float* __restrict__ fea, float* __restrict__ outp)
{
    int i = blockIdx.x * 256 + threadIdx.x;     // i over B*N*64
    int d = i & 63;
    size_t node = (size_t)(i >> 6);
    const float* p = fea + node * 256;
    outp[i] = 0.25f * (p[d] + p[64 + d] + p[128 + d] + p[192 + d]);
}

extern "C" void kernel_launch(void* const* d_in, const int* in_sizes, int n_in,
                              void* d_out, int out_size, void* d_ws, size_t ws_size,
                              hipStream_t stream) {
    const float* seg = (const float*)d_in[0];
    const float* adj = (const float*)d_in[1];
    const float* W0  = (const float*)d_in[2];
    const float* al0 = (const float*)d_in[3];
    const float* ar0 = (const float*)d_in[4];
    const float* rW0 = (const float*)d_in[5];
    const float* b0  = (const float*)d_in[6];
    const float* W1  = (const float*)d_in[7];
    const float* al1 = (const float*)d_in[8];
    const float* ar1 = (const float*)d_in[9];
    const float* rW1 = (const float*)d_in[10];
    const float* b1  = (const float*)d_in[11];
    float* out = (float*)d_out;

    char* ws = (char*)d_ws;
    uint64_t* mask = (uint64_t*)ws;                      // 16*1024*16*8 = 2 MB
    size_t off = (size_t)BB * NN * 16 * 8;
    float* fbuf = (float*)(ws + off); off += (size_t)BB * NN * 256 * 4;   // 16 MB
    float* resA = (float*)(ws + off); off += (size_t)BB * NN * 256 * 4;   // 16 MB
    float* el   = (float*)(ws + off); off += (size_t)BB * NN * 4 * 4;
    float* er   = (float*)(ws + off); off += (size_t)BB * NN * 4 * 4;
    float* emx  = (float*)(ws + off); off += (size_t)BB * 4 * 4;

    k_topk_mask<<<BB * NN, 256, 0, stream>>>(adj, mask);

    // layer 0: x = seg (K=64)
    k_features<64><<<BB * NN / 16, 256, 0, stream>>>(seg, W0, rW0, al0, ar0,
                                                     fbuf, resA, el, er);
    k_elmax<<<BB * 4, 256, 0, stream>>>(el, emx);
    k_attn<1><<<dim3(16, 4, BB), 256, 0, stream>>>(fbuf, resA, el, er, emx, mask,
                                                   b0, resA);   // out in-place -> fea0
    // layer 1: x = fea0 (K=256); res written in-place over fea0 after LDS load
    k_features<256><<<BB * NN / 16, 256, 0, stream>>>(resA, W1, rW1, al1, ar1,
                                                      fbuf, resA, el, er);
    k_elmax<<<BB * 4, 256, 0, stream>>>(el, emx);
    k_attn<0><<<dim3(16, 4, BB), 256, 0, stream>>>(fbuf, resA, el, er, emx, mask,
                                                   b1, resA);   // out in-place -> fea1

    k_headmean<<<BB * NN * 64 / 256, 256, 0, stream>>>(resA, out);
}

// Round 2
// 370.979 us; speedup vs baseline: 1.4086x; 1.4086x over previous
//
#include <hip/hip_runtime.h>
#include <hip/hip_bf16.h>
#include <stdint.h>

#define BB   16
#define NN   1024
#define KSEL 170   // (32*32)/6

typedef __attribute__((ext_vector_type(8))) short short8;
typedef __attribute__((ext_vector_type(4))) float f32x4;

static __device__ __forceinline__ short f2bf(float x) {
    __hip_bfloat16 h = __float2bfloat16(x);
    return *reinterpret_cast<short*>(&h);
}
static __device__ __forceinline__ float bf2f(short x) {
    __hip_bfloat16 h = *reinterpret_cast<__hip_bfloat16*>(&x);
    return __bfloat162float(h);
}

// ---------------- K1: exact k-th-largest per row (radix select) + packed mask --------
__global__ __launch_bounds__(256) void k_topk_mask(
    const float* __restrict__ adj, uint64_t* __restrict__ mask)
{
    const int row = blockIdx.x;                 // b*N + u
    const float* a = adj + (size_t)row * NN;
    __shared__ uint32_t keys[NN];
    __shared__ uint32_t hist[256];
    __shared__ uint32_t wtot[4];
    __shared__ uint32_t s_prefix, s_k;
    const int t = threadIdx.x;
    const int lane = t & 63, w = t >> 6;

    for (int i = t; i < NN; i += 256) {
        uint32_t u = __float_as_uint(a[i]);
        keys[i] = u ^ ((u >> 31) ? 0xFFFFFFFFu : 0x80000000u);   // order-preserving map
    }
    if (t == 0) { s_prefix = 0u; s_k = KSEL; }
    __syncthreads();

    for (int pass = 0; pass < 4; ++pass) {
        const int shift = 24 - 8 * pass;
        const uint32_t prefix = s_prefix;
        const uint32_t kk = s_k;
        const uint32_t hi_mask = pass ? (0xFFFFFFFFu << (shift + 8)) : 0u;
        hist[t] = 0u;
        __syncthreads();
        for (int i = t; i < NN; i += 256) {
            uint32_t kv = keys[i];
            if ((kv & hi_mask) == prefix)
                atomicAdd(&hist[(kv >> shift) & 255], 1u);
        }
        __syncthreads();
        uint32_t c = hist[t];
        uint32_t s = c;
        #pragma unroll
        for (int off = 1; off < 64; off <<= 1) {     // in-wave inclusive suffix sum
            uint32_t vsh = __shfl_down(s, off);
            s += (lane + off < 64) ? vsh : 0u;
        }
        if (lane == 0) wtot[w] = s;
        __syncthreads();
        uint32_t above = 0;
        for (int w2 = w + 1; w2 < 4; ++w2) above += wtot[w2];
        uint32_t cum_incl = s + above;               // count of bins >= t
        uint32_t cum_excl = cum_incl - c;            // count of bins >  t
        if (cum_excl < kk && kk <= cum_incl) {       // exactly one winner
            s_prefix = prefix | ((uint32_t)t << shift);
            s_k = kk - cum_excl;
        }
        __syncthreads();
    }

    const uint32_t thr_key = s_prefix;               // key of k-th largest (exact)
    #pragma unroll
    for (int i = 0; i < 4; ++i) {
        uint32_t kv = keys[i * 256 + t];
        bool pred = (kv >= thr_key) && (kv > 0x80000000u);   // adj>=thr && adj>0
        uint64_t bal = __ballot(pred);
        if (lane == 0) mask[(size_t)row * 16 + i * 4 + w] = bal;
    }
}

// ---------------- K2: f_t = bf16((x@W)^T per (b,h)), res = x@rW, el/er dots ----------
template<int K>
__global__ __launch_bounds__(256) void k_features(
    const float* __restrict__ x,   // [B*N][K]
    const float* __restrict__ W,   // [K][256]
    const float* __restrict__ rW,  // [K][256]
    const float* __restrict__ al,  // [256]
    const float* __restrict__ ar,  // [256]
    short* __restrict__ ft,        // [(B*4+h)*64+d][NN] bf16, transposed features
    float* __restrict__ res,       // [B*N][256]  (may alias x: rows read to LDS first)
    float* __restrict__ el,        // [B*N][4]
    float* __restrict__ er)        // [B*N][4]
{
    __shared__ float xs[K * 16];   // [k][i] transposed tile of 16 node rows
    const int t = threadIdx.x;
    const size_t n0 = (size_t)blockIdx.x * 16;
    const float* xb = x + n0 * K;
    for (int idx = t; idx < 16 * K; idx += 256)
        xs[(idx % K) * 16 + (idx / K)] = xb[idx];
    __syncthreads();

    float accf[16], accr[16];
    #pragma unroll
    for (int i = 0; i < 16; ++i) { accf[i] = 0.f; accr[i] = 0.f; }
    const int o = t;
    for (int k = 0; k < K; ++k) {
        float wv = W[k * 256 + o];
        float rv = rW[k * 256 + o];
        const float4* xr = (const float4*)&xs[k * 16];
        float4 x0 = xr[0], x1 = xr[1], x2 = xr[2], x3 = xr[3];
        accf[0]  += x0.x * wv;  accr[0]  += x0.x * rv;
        accf[1]  += x0.y * wv;  accr[1]  += x0.y * rv;
        accf[2]  += x0.z * wv;  accr[2]  += x0.z * rv;
        accf[3]  += x0.w * wv;  accr[3]  += x0.w * rv;
        accf[4]  += x1.x * wv;  accr[4]  += x1.x * rv;
        accf[5]  += x1.y * wv;  accr[5]  += x1.y * rv;
        accf[6]  += x1.z * wv;  accr[6]  += x1.z * rv;
        accf[7]  += x1.w * wv;  accr[7]  += x1.w * rv;
        accf[8]  += x2.x * wv;  accr[8]  += x2.x * rv;
        accf[9]  += x2.y * wv;  accr[9]  += x2.y * rv;
        accf[10] += x2.z * wv;  accr[10] += x2.z * rv;
        accf[11] += x2.w * wv;  accr[11] += x2.w * rv;
        accf[12] += x3.x * wv;  accr[12] += x3.x * rv;
        accf[13] += x3.y * wv;  accr[13] += x3.y * rv;
        accf[14] += x3.z * wv;  accr[14] += x3.z * rv;
        accf[15] += x3.w * wv;  accr[15] += x3.w * rv;
    }
    const int b_idx = (int)(n0 / NN);
    const int nb = (int)(n0 % NN);
    // res fp32 row-major, f bf16 transposed [(b,h,d)][u]
    short8 t0, t1;
    #pragma unroll
    for (int i = 0; i < 8; ++i)  t0[i] = f2bf(accf[i]);
    #pragma unroll
    for (int i = 0; i < 8; ++i)  t1[i] = f2bf(accf[8 + i]);
    {
        short* dst = ft + ((size_t)(b_idx * 4 + (t >> 6)) * 64 + (t & 63)) * NN + nb;
        *(short8*)dst = t0;
        *(short8*)(dst + 8) = t1;
    }
    #pragma unroll
    for (int i = 0; i < 16; ++i)
        res[(n0 + i) * 256 + o] = accr[i];

    // el/er: wave w handles head h=w (o = h*64+d), reduce over d (64 lanes)
    const float alv = al[o], arv = ar[o];
    const int lane = t & 63, h = t >> 6;
    #pragma unroll
    for (int i = 0; i < 16; ++i) {
        float pe = accf[i] * alv;
        float pr = accf[i] * arv;
        #pragma unroll
        for (int off = 32; off; off >>= 1) {
            pe += __shfl_xor(pe, off);
            pr += __shfl_xor(pr, off);
        }
        if (lane == 0) {
            el[(n0 + i) * 4 + h] = pe;
            er[(n0 + i) * 4 + h] = pr;
        }
    }
}

// ---------------- K3: unmasked max over src nodes of el ----------------
__global__ __launch_bounds__(256) void k_elmax(
    const float* __restrict__ el, float* __restrict__ elmax)
{
    const int b = blockIdx.x >> 2, h = blockIdx.x & 3;
    const int t = threadIdx.x;
    float m = -1e30f;
    for (int n = t; n < NN; n += 256)
        m = fmaxf(m, el[((size_t)b * NN + n) * 4 + h]);
    #pragma unroll
    for (int off = 32; off; off >>= 1) m = fmaxf(m, __shfl_xor(m, off));
    __shared__ float sm[4];
    if ((t & 63) == 0) sm[t >> 6] = m;
    __syncthreads();
    if (t == 0) elmax[blockIdx.x] = fmaxf(fmaxf(sm[0], sm[1]), fmaxf(sm[2], sm[3]));
}

// ---------------- K4: masked softmax over u + MFMA PV + residual + bias (+ELU) ------
template<int ELU_ON>
__global__ __launch_bounds__(256) void k_attn(
    const short* __restrict__ ft,     // [(b*4+h)*64+d][NN] bf16
    const float* __restrict__ res,    // [B*N][256]
    const float* __restrict__ el,     // [B*N][4]
    const float* __restrict__ er,     // [B*N][4]
    const float* __restrict__ elmax,  // [B][4]
    const uint64_t* __restrict__ mask,// [B*N][16]
    const float* __restrict__ bias,   // [256]
    float* __restrict__ out)          // [B*N][256] (may alias res: in-place per element)
{
    const int vt = blockIdx.x;        // v-tile (16 of 64)
    const int h  = blockIdx.y;
    const int b  = blockIdx.z;
    const int v0 = vt * 64;
    const int t = threadIdx.x;
    const int lane = t & 63, g = t >> 6;       // g = wave id
    const int l15 = lane & 15, l4 = lane >> 4;

    __shared__ short p_lds[64][72];   // p^T: [v][u], padded (144B stride -> slot spread)
    __shared__ short f_lds[64][72];   // f^T: [d][u], padded
    __shared__ float el_all[NN];
    __shared__ float er_c[64], c_c[64];
    __shared__ float den_lds[4][64];
    __shared__ float den_fin[64];

    const size_t bN = (size_t)b * NN;
    if (t < 64) {
        float erv = er[(bN + v0 + t) * 4 + h];
        er_c[t] = erv;
        float e = elmax[b * 4 + h] + erv;      // unmasked max of el + er[v]
        c_c[t] = e > 0.f ? e : 0.2f * e;       // lrelu monotone -> valid softmax shift
    }
    for (int i = t; i < NN; i += 256) el_all[i] = el[(bN + i) * 4 + h];
    __syncthreads();

    const short* ftb = ft + ((size_t)(b * 4 + h) * 64) * NN;
    f32x4 acc[4];
    #pragma unroll
    for (int i = 0; i < 4; ++i) acc[i] = (f32x4){0.f, 0.f, 0.f, 0.f};
    float den_reg = 0.f;
    const float cv  = c_c[lane];
    const float erv = er_c[lane];

    for (int u0 = 0; u0 < NN; u0 += 64) {
        // ---- stage f^T tile (straight copy, contiguous rows) ----
        {
            const int d = t >> 2, q = t & 3;
            const short* src = ftb + (size_t)d * NN + u0 + q * 8;
            *(short8*)&f_lds[d][q * 8]      = *(const short8*)(src);
            *(short8*)&f_lds[d][q * 8 + 32] = *(const short8*)(src + 32);
        }
        // ---- p-gen: thread owns v=lane, u in [g*16, g*16+16) ----
        {
            short8 t0, t1;
            float ds = 0.f;
            #pragma unroll
            for (int jj = 0; jj < 16; ++jj) {
                const int u_l = g * 16 + jj;
                uint64_t wd = mask[(bN + u0 + u_l) * 16 + vt];
                float e = el_all[u0 + u_l] + erv;
                float lr = e > 0.f ? e : 0.2f * e;
                float pv = ((wd >> lane) & 1ull) ? __expf(lr - cv) : 0.f;
                short pb = f2bf(pv);
                if (jj < 8) t0[jj & 7] = pb; else t1[jj & 7] = pb;
                ds += bf2f(pb);                 // denom from the SAME rounded values
            }
            den_reg += ds;
            *(short8*)&p_lds[lane][g * 16]     = t0;
            *(short8*)&p_lds[lane][g * 16 + 8] = t1;
        }
        __syncthreads();
        // ---- MFMA: wave g owns v-rows [g*16, g*16+16), all 64 d ----
        #pragma unroll
        for (int kc = 0; kc < 2; ++kc) {
            const int k8 = kc * 32 + l4 * 8;
            short8 av = *(const short8*)&p_lds[g * 16 + l15][k8];
            short8 b0 = *(const short8*)&f_lds[l15][k8];
            short8 b1 = *(const short8*)&f_lds[16 + l15][k8];
            short8 b2 = *(const short8*)&f_lds[32 + l15][k8];
            short8 b3 = *(const short8*)&f_lds[48 + l15][k8];
            acc[0] = __builtin_amdgcn_mfma_f32_16x16x32_bf16(av, b0, acc[0], 0, 0, 0);
            acc[1] = __builtin_amdgcn_mfma_f32_16x16x32_bf16(av, b1, acc[1], 0, 0, 0);
            acc[2] = __builtin_amdgcn_mfma_f32_16x16x32_bf16(av, b2, acc[2], 0, 0, 0);
            acc[3] = __builtin_amdgcn_mfma_f32_16x16x32_bf16(av, b3, acc[3], 0, 0, 0);
        }
        __syncthreads();
    }
    den_lds[g][lane] = den_reg;
    __syncthreads();
    if (t < 64) {
        float s = den_lds[0][t] + den_lds[1][t] + den_lds[2][t] + den_lds[3][t];
        den_fin[t] = 1.f / fmaxf(s, 1e-9f);    // jnp.clip(sum, 1e-9)
    }
    __syncthreads();

    // D layout: col(l15)=d-local, row=(l4*4+r)=v-local within wave strip
    #pragma unroll
    for (int dt = 0; dt < 4; ++dt) {
        const int d = dt * 16 + l15;
        const float bv = bias[h * 64 + d];
        #pragma unroll
        for (int r = 0; r < 4; ++r) {
            const int vl = g * 16 + l4 * 4 + r;
            const float rcp = den_fin[vl];
            const size_t row = (bN + v0 + vl) * 256 + h * 64 + d;
            float ov = acc[dt][r] * rcp + res[row] + bv;
            if (ELU_ON) ov = ov > 0.f ? ov : __expf(ov) - 1.f;
            out[row] = ov;
        }
    }
}

// ---------------- K5: mean over heads -> d_out ----------------
__global__ __launch_bounds__(256) void k_headmean(
    const float* __restrict__ fea, float* __restrict__ outp)
{
    int i = blockIdx.x * 256 + threadIdx.x;     // i over B*N*64
    int d = i & 63;
    size_t node = (size_t)(i >> 6);
    const float* p = fea + node * 256;
    outp[i] = 0.25f * (p[d] + p[64 + d] + p[128 + d] + p[192 + d]);
}

extern "C" void kernel_launch(void* const* d_in, const int* in_sizes, int n_in,
                              void* d_out, int out_size, void* d_ws, size_t ws_size,
                              hipStream_t stream) {
    const float* seg = (const float*)d_in[0];
    const float* adj = (const float*)d_in[1];
    const float* W0  = (const float*)d_in[2];
    const float* al0 = (const float*)d_in[3];
    const float* ar0 = (const float*)d_in[4];
    const float* rW0 = (const float*)d_in[5];
    const float* b0  = (const float*)d_in[6];
    const float* W1  = (const float*)d_in[7];
    const float* al1 = (const float*)d_in[8];
    const float* ar1 = (const float*)d_in[9];
    const float* rW1 = (const float*)d_in[10];
    const float* b1  = (const float*)d_in[11];
    float* out = (float*)d_out;

    char* ws = (char*)d_ws;
    uint64_t* mask = (uint64_t*)ws;                      // 2 MB
    size_t off = (size_t)BB * NN * 16 * 8;
    short* ftb  = (short*)(ws + off); off += (size_t)BB * 4 * 64 * NN * 2;  // 8 MB bf16
    float* resA = (float*)(ws + off); off += (size_t)BB * NN * 256 * 4;     // 16 MB
    float* el   = (float*)(ws + off); off += (size_t)BB * NN * 4 * 4;
    float* er   = (float*)(ws + off); off += (size_t)BB * NN * 4 * 4;
    float* emx  = (float*)(ws + off); off += (size_t)BB * 4 * 4;

    k_topk_mask<<<BB * NN, 256, 0, stream>>>(adj, mask);

    // layer 0: x = seg (K=64)
    k_features<64><<<BB * NN / 16, 256, 0, stream>>>(seg, W0, rW0, al0, ar0,
                                                     ftb, resA, el, er);
    k_elmax<<<BB * 4, 256, 0, stream>>>(el, emx);
    k_attn<1><<<dim3(16, 4, BB), 256, 0, stream>>>(ftb, resA, el, er, emx, mask,
                                                   b0, resA);   // out in-place -> fea0
    // layer 1: x = fea0 (K=256)
    k_features<256><<<BB * NN / 16, 256, 0, stream>>>(resA, W1, rW1, al1, ar1,
                                                      ftb, resA, el, er);
    k_elmax<<<BB * 4, 256, 0, stream>>>(el, emx);
    k_attn<0><<<dim3(16, 4, BB), 256, 0, stream>>>(ftb, resA, el, er, emx, mask,
                                                   b1, resA);   // out in-place -> fea1

    k_headmean<<<BB * NN * 64 / 256, 256, 0, stream>>>(resA, out);
}

// Round 3
// 320.434 us; speedup vs baseline: 1.6307x; 1.1577x over previous
//
#include <hip/hip_runtime.h>
#include <hip/hip_bf16.h>
#include <stdint.h>

#define BB   16
#define NN   1024
#define KSEL 170   // (32*32)/6
#define LOG2E 1.4426950408889634f

typedef __attribute__((ext_vector_type(8))) short short8;
typedef __attribute__((ext_vector_type(4))) float f32x4;

static __device__ __forceinline__ short f2bf(float x) {
    __hip_bfloat16 h = __float2bfloat16(x);
    return *reinterpret_cast<short*>(&h);
}
static __device__ __forceinline__ float bfbits2f(short x) {
    uint32_t u = ((uint32_t)(uint16_t)x) << 16;
    return __uint_as_float(u);
}

// ---------------- K1: exact k-th-largest per row (radix select) + packed mask --------
__global__ __launch_bounds__(256) void k_topk_mask(
    const float* __restrict__ adj, uint64_t* __restrict__ mask)
{
    const int row = blockIdx.x;                 // b*N + u
    const float* a = adj + (size_t)row * NN;
    __shared__ uint32_t keys[NN];
    __shared__ uint32_t hist[256];
    __shared__ uint32_t wtot[4];
    __shared__ uint32_t s_prefix, s_k;
    const int t = threadIdx.x;
    const int lane = t & 63, w = t >> 6;

    for (int i = t; i < NN; i += 256) {
        uint32_t u = __float_as_uint(a[i]);
        keys[i] = u ^ ((u >> 31) ? 0xFFFFFFFFu : 0x80000000u);   // order-preserving map
    }
    if (t == 0) { s_prefix = 0u; s_k = KSEL; }
    __syncthreads();

    for (int pass = 0; pass < 4; ++pass) {
        const int shift = 24 - 8 * pass;
        const uint32_t prefix = s_prefix;
        const uint32_t kk = s_k;
        const uint32_t hi_mask = pass ? (0xFFFFFFFFu << (shift + 8)) : 0u;
        hist[t] = 0u;
        __syncthreads();
        for (int i = t; i < NN; i += 256) {
            uint32_t kv = keys[i];
            if ((kv & hi_mask) == prefix)
                atomicAdd(&hist[(kv >> shift) & 255], 1u);
        }
        __syncthreads();
        uint32_t c = hist[t];
        uint32_t s = c;
        #pragma unroll
        for (int off = 1; off < 64; off <<= 1) {     // in-wave inclusive suffix sum
            uint32_t vsh = __shfl_down(s, off);
            s += (lane + off < 64) ? vsh : 0u;
        }
        if (lane == 0) wtot[w] = s;
        __syncthreads();
        uint32_t above = 0;
        for (int w2 = w + 1; w2 < 4; ++w2) above += wtot[w2];
        uint32_t cum_incl = s + above;               // count of bins >= t
        uint32_t cum_excl = cum_incl - c;            // count of bins >  t
        if (cum_excl < kk && kk <= cum_incl) {       // exactly one winner
            s_prefix = prefix | ((uint32_t)t << shift);
            s_k = kk - cum_excl;
        }
        __syncthreads();
    }

    const uint32_t thr_key = s_prefix;               // key of k-th largest (exact)
    #pragma unroll
    for (int i = 0; i < 4; ++i) {
        uint32_t kv = keys[i * 256 + t];
        bool pred = (kv >= thr_key) && (kv > 0x80000000u);   // adj>=thr && adj>0
        uint64_t bal = __ballot(pred);
        if (lane == 0) mask[(size_t)row * 16 + i * 4 + w] = bal;
    }
}

// ---------------- K2: f_t = bf16((x@W)^T per (b,h)), res = x@rW, el/er dots ----------
template<int K>
__global__ __launch_bounds__(256) void k_features(
    const float* __restrict__ x,   // [B*N][K]
    const float* __restrict__ W,   // [K][256]
    const float* __restrict__ rW,  // [K][256]
    const float* __restrict__ al,  // [256]
    const float* __restrict__ ar,  // [256]
    short* __restrict__ ft,        // [(B*4+h)*64+d][NN] bf16, transposed features
    float* __restrict__ res,       // [B*N][256]  (may alias x: rows read to LDS first)
    float* __restrict__ el_t,      // [(b*4+h)][NN], scaled by LOG2E
    float* __restrict__ er_t)      // [(b*4+h)][NN], scaled by LOG2E
{
    __shared__ float xs[K * 16];   // [k][i] transposed tile of 16 node rows
    const int t = threadIdx.x;
    const size_t n0 = (size_t)blockIdx.x * 16;
    const float* xb = x + n0 * K;
    for (int idx = t; idx < 16 * K; idx += 256)
        xs[(idx % K) * 16 + (idx / K)] = xb[idx];
    __syncthreads();

    float accf[16], accr[16];
    #pragma unroll
    for (int i = 0; i < 16; ++i) { accf[i] = 0.f; accr[i] = 0.f; }
    const int o = t;
    for (int k = 0; k < K; ++k) {
        float wv = W[k * 256 + o];
        float rv = rW[k * 256 + o];
        const float4* xr = (const float4*)&xs[k * 16];
        float4 x0 = xr[0], x1 = xr[1], x2 = xr[2], x3 = xr[3];
        accf[0]  += x0.x * wv;  accr[0]  += x0.x * rv;
        accf[1]  += x0.y * wv;  accr[1]  += x0.y * rv;
        accf[2]  += x0.z * wv;  accr[2]  += x0.z * rv;
        accf[3]  += x0.w * wv;  accr[3]  += x0.w * rv;
        accf[4]  += x1.x * wv;  accr[4]  += x1.x * rv;
        accf[5]  += x1.y * wv;  accr[5]  += x1.y * rv;
        accf[6]  += x1.z * wv;  accr[6]  += x1.z * rv;
        accf[7]  += x1.w * wv;  accr[7]  += x1.w * rv;
        accf[8]  += x2.x * wv;  accr[8]  += x2.x * rv;
        accf[9]  += x2.y * wv;  accr[9]  += x2.y * rv;
        accf[10] += x2.z * wv;  accr[10] += x2.z * rv;
        accf[11] += x2.w * wv;  accr[11] += x2.w * rv;
        accf[12] += x3.x * wv;  accr[12] += x3.x * rv;
        accf[13] += x3.y * wv;  accr[13] += x3.y * rv;
        accf[14] += x3.z * wv;  accr[14] += x3.z * rv;
        accf[15] += x3.w * wv;  accr[15] += x3.w * rv;
    }
    const int b_idx = (int)(n0 / NN);
    const int nb = (int)(n0 % NN);
    // res fp32 row-major, f bf16 transposed [(b,h,d)][u]
    short8 t0, t1;
    #pragma unroll
    for (int i = 0; i < 8; ++i)  t0[i] = f2bf(accf[i]);
    #pragma unroll
    for (int i = 0; i < 8; ++i)  t1[i] = f2bf(accf[8 + i]);
    {
        short* dst = ft + ((size_t)(b_idx * 4 + (t >> 6)) * 64 + (t & 63)) * NN + nb;
        *(short8*)dst = t0;
        *(short8*)(dst + 8) = t1;
    }
    #pragma unroll
    for (int i = 0; i < 16; ++i)
        res[(n0 + i) * 256 + o] = accr[i];

    // el/er: wave w handles head h=w (o = h*64+d), reduce over d (64 lanes)
    const float alv = al[o], arv = ar[o];
    const int lane = t & 63, h = t >> 6;
    #pragma unroll
    for (int i = 0; i < 16; ++i) {
        float pe = accf[i] * alv;
        float pr = accf[i] * arv;
        #pragma unroll
        for (int off = 32; off; off >>= 1) {
            pe += __shfl_xor(pe, off);
            pr += __shfl_xor(pr, off);
        }
        if (lane == 0) {
            el_t[(size_t)(b_idx * 4 + h) * NN + nb + i] = pe * LOG2E;
            er_t[(size_t)(b_idx * 4 + h) * NN + nb + i] = pr * LOG2E;
        }
    }
}

// ---------------- K3: unmasked max over src nodes of el (per (b,h)) ----------------
__global__ __launch_bounds__(256) void k_elmax(
    const float* __restrict__ el_t, float* __restrict__ elmax)
{
    const int bh = blockIdx.x;
    const int t = threadIdx.x;
    float m = -1e30f;
    for (int n = t; n < NN; n += 256)
        m = fmaxf(m, el_t[(size_t)bh * NN + n]);
    #pragma unroll
    for (int off = 32; off; off >>= 1) m = fmaxf(m, __shfl_xor(m, off));
    __shared__ float sm[4];
    if ((t & 63) == 0) sm[t >> 6] = m;
    __syncthreads();
    if (t == 0) elmax[bh] = fmaxf(fmaxf(sm[0], sm[1]), fmaxf(sm[2], sm[3]));
}

// ---------------- K4: masked softmax over u + MFMA PV + residual + bias (+ELU) ------
// P computed per-lane directly in MFMA A-fragment layout: zero barriers in u-loop,
// zero LDS for P; B-fragments read straight from L2-resident ft.
template<int ELU_ON>
__global__ __launch_bounds__(256, 4) void k_attn(
    const short* __restrict__ ft,     // [(b*4+h)*64+d][NN] bf16
    const float* __restrict__ res,    // [B*N][256]
    const float* __restrict__ el_t,   // [(b*4+h)][NN] scaled
    const float* __restrict__ er_t,   // [(b*4+h)][NN] scaled
    const float* __restrict__ elmax,  // [(b*4+h)]
    const uint64_t* __restrict__ mask,// [B*N][16]
    const float* __restrict__ bias,   // [256]
    float* __restrict__ out)          // [B*N][256] (may alias res: in-place per element)
{
    const int vt = blockIdx.x;        // v-tile (16 of 64)
    const int h  = blockIdx.y;
    const int b  = blockIdx.z;
    const int v0 = vt * 64;
    const int t = threadIdx.x;
    const int lane = t & 63, g = t >> 6;       // g = wave id
    const int l15 = lane & 15, l4 = (lane >> 4) & 3;
    const int vloc = g * 16 + l15;             // this lane's A-row (v within 64-tile)
    const int bh = b * 4 + h;
    const size_t bN = (size_t)b * NN;

    __shared__ float el_lds[NN];
    // stage el strip (coalesced, one b128 per thread)
    ((float4*)el_lds)[t] = ((const float4*)(el_t + (size_t)bh * NN))[t];

    const float erv = er_t[(size_t)bh * NN + v0 + vloc];
    {
        // nothing else before barrier
    }
    __syncthreads();
    float e0 = elmax[bh] + erv;
    const float cv = e0 > 0.f ? e0 : 0.2f * e0;    // lrelu monotone -> valid shift

    const uint32_t* mask32 = (const uint32_t*)mask;
    const int hsel = vloc >> 5;
    const uint32_t vb = (uint32_t)(vloc & 31);
    const short* fB = ft + ((size_t)bh * 64 + l15) * NN + l4 * 8;

    f32x4 acc[4];
    #pragma unroll
    for (int i = 0; i < 4; ++i) acc[i] = (f32x4){0.f, 0.f, 0.f, 0.f};
    float den = 0.f;

    for (int u0 = 0; u0 < NN; u0 += 64) {
        #pragma unroll
        for (int kc = 0; kc < 2; ++kc) {
            const int ub = u0 + kc * 32 + l4 * 8;   // first u this lane covers
            // ---- B fragments (global, L2-resident) ----
            short8 bf0 = *(const short8*)(fB + u0 + kc * 32);
            short8 bf1 = *(const short8*)(fB + (size_t)16 * NN + u0 + kc * 32);
            short8 bf2 = *(const short8*)(fB + (size_t)32 * NN + u0 + kc * 32);
            short8 bf3 = *(const short8*)(fB + (size_t)48 * NN + u0 + kc * 32);
            // ---- mask words (one 4B half-word per u, L1/L2-cached) ----
            const uint32_t* mp = mask32 + ((size_t)(bN + ub) * 16 + vt) * 2 + hsel;
            uint32_t mw[8];
            #pragma unroll
            for (int j = 0; j < 8; ++j) mw[j] = mp[j * 32];
            // ---- el values (LDS broadcast reads) ----
            float4 ev0 = *(const float4*)&el_lds[ub];
            float4 ev1 = *(const float4*)&el_lds[ub + 4];
            float ev[8] = {ev0.x, ev0.y, ev0.z, ev0.w, ev1.x, ev1.y, ev1.z, ev1.w};
            // ---- p-gen directly into A-fragment ----
            short8 av;
            #pragma unroll
            for (int j = 0; j < 8; ++j) {
                float e = ev[j] + erv;
                float lr = e > 0.f ? e : 0.2f * e;
                float pv = ((mw[j] >> vb) & 1u) ? exp2f(lr - cv) : 0.f;
                short pb = f2bf(pv);
                av[j] = pb;
                den += bfbits2f(pb);           // denom from the SAME rounded values
            }
            acc[0] = __builtin_amdgcn_mfma_f32_16x16x32_bf16(av, bf0, acc[0], 0, 0, 0);
            acc[1] = __builtin_amdgcn_mfma_f32_16x16x32_bf16(av, bf1, acc[1], 0, 0, 0);
            acc[2] = __builtin_amdgcn_mfma_f32_16x16x32_bf16(av, bf2, acc[2], 0, 0, 0);
            acc[3] = __builtin_amdgcn_mfma_f32_16x16x32_bf16(av, bf3, acc[3], 0, 0, 0);
        }
    }

    // ---- denominator: reduce over the 4 l4 sub-lanes holding the same v ----
    den += __shfl_xor(den, 16);
    den += __shfl_xor(den, 32);
    // lane l (l<16 pattern repeated) now holds den for v = g*16 + (l&15)

    float rcp[4];
    #pragma unroll
    for (int r = 0; r < 4; ++r) {
        float dv = __shfl(den, l4 * 4 + r);    // lane l4*4+r holds den[v=g*16+l4*4+r]
        rcp[r] = 1.f / fmaxf(dv, 1e-9f);       // jnp.clip(sum, 1e-9)
    }

    // D layout: col(l15)=d-local, row = l4*4+r = v-local within wave strip
    #pragma unroll
    for (int dt = 0; dt < 4; ++dt) {
        const int d = dt * 16 + l15;
        const float bv = bias[h * 64 + d];
        #pragma unroll
        for (int r = 0; r < 4; ++r) {
            const int vl = g * 16 + l4 * 4 + r;
            const size_t row = (bN + v0 + vl) * 256 + h * 64 + d;
            float ov = acc[dt][r] * rcp[r] + res[row] + bv;
            if (ELU_ON) ov = ov > 0.f ? ov : __expf(ov) - 1.f;
            out[row] = ov;
        }
    }
}

// ---------------- K5: mean over heads -> d_out ----------------
__global__ __launch_bounds__(256) void k_headmean(
    const float* __restrict__ fea, float* __restrict__ outp)
{
    int i = blockIdx.x * 256 + threadIdx.x;     // i over B*N*64
    int d = i & 63;
    size_t node = (size_t)(i >> 6);
    const float* p = fea + node * 256;
    outp[i] = 0.25f * (p[d] + p[64 + d] + p[128 + d] + p[192 + d]);
}

extern "C" void kernel_launch(void* const* d_in, const int* in_sizes, int n_in,
                              void* d_out, int out_size, void* d_ws, size_t ws_size,
                              hipStream_t stream) {
    const float* seg = (const float*)d_in[0];
    const float* adj = (const float*)d_in[1];
    const float* W0  = (const float*)d_in[2];
    const float* al0 = (const float*)d_in[3];
    const float* ar0 = (const float*)d_in[4];
    const float* rW0 = (const float*)d_in[5];
    const float* b0  = (const float*)d_in[6];
    const float* W1  = (const float*)d_in[7];
    const float* al1 = (const float*)d_in[8];
    const float* ar1 = (const float*)d_in[9];
    const float* rW1 = (const float*)d_in[10];
    const float* b1  = (const float*)d_in[11];
    float* out = (float*)d_out;

    char* ws = (char*)d_ws;
    uint64_t* mask = (uint64_t*)ws;                      // 2 MB
    size_t off = (size_t)BB * NN * 16 * 8;
    short* ftb  = (short*)(ws + off); off += (size_t)BB * 4 * 64 * NN * 2;  // 8 MB bf16
    float* resA = (float*)(ws + off); off += (size_t)BB * NN * 256 * 4;     // 16 MB
    float* el   = (float*)(ws + off); off += (size_t)BB * 4 * NN * 4;       // 256 KB
    float* er   = (float*)(ws + off); off += (size_t)BB * 4 * NN * 4;       // 256 KB
    float* emx  = (float*)(ws + off); off += (size_t)BB * 4 * 4;

    k_topk_mask<<<BB * NN, 256, 0, stream>>>(adj, mask);

    // layer 0: x = seg (K=64)
    k_features<64><<<BB * NN / 16, 256, 0, stream>>>(seg, W0, rW0, al0, ar0,
                                                     ftb, resA, el, er);
    k_elmax<<<BB * 4, 256, 0, stream>>>(el, emx);
    k_attn<1><<<dim3(16, 4, BB), 256, 0, stream>>>(ftb, resA, el, er, emx, mask,
                                                   b0, resA);   // out in-place -> fea0
    // layer 1: x = fea0 (K=256)
    k_features<256><<<BB * NN / 16, 256, 0, stream>>>(resA, W1, rW1, al1, ar1,
                                                      ftb, resA, el, er);
    k_elmax<<<BB * 4, 256, 0, stream>>>(el, emx);
    k_attn<0><<<dim3(16, 4, BB), 256, 0, stream>>>(ftb, resA, el, er, emx, mask,
                                                   b1, resA);   // out in-place -> fea1

    k_headmean<<<BB * NN * 64 / 256, 256, 0, stream>>>(resA, out);
}

// Round 4
// 318.100 us; speedup vs baseline: 1.6427x; 1.0073x over previous
//
#include <hip/hip_runtime.h>
#include <hip/hip_bf16.h>
#include <stdint.h>

#define BB   16
#define NN   1024
#define KSEL 170   // (32*32)/6
#define LOG2E 1.4426950408889634f

typedef __attribute__((ext_vector_type(8))) short short8;
typedef __attribute__((ext_vector_type(4))) float f32x4;

static __device__ __forceinline__ short f2bf(float x) {
    __hip_bfloat16 h = __float2bfloat16(x);
    return *reinterpret_cast<short*>(&h);
}

// ---------------- K1: exact k-th-largest per row (radix select) + packed mask --------
__global__ __launch_bounds__(256) void k_topk_mask(
    const float* __restrict__ adj, uint64_t* __restrict__ mask)
{
    const int row = blockIdx.x;                 // b*N + u
    const float* a = adj + (size_t)row * NN;
    __shared__ uint32_t keys[NN];
    __shared__ uint32_t hist[256];
    __shared__ uint32_t wtot[4];
    __shared__ uint32_t s_prefix, s_k;
    const int t = threadIdx.x;
    const int lane = t & 63, w = t >> 6;

    for (int i = t; i < NN; i += 256) {
        uint32_t u = __float_as_uint(a[i]);
        keys[i] = u ^ ((u >> 31) ? 0xFFFFFFFFu : 0x80000000u);   // order-preserving map
    }
    if (t == 0) { s_prefix = 0u; s_k = KSEL; }
    __syncthreads();

    for (int pass = 0; pass < 4; ++pass) {
        const int shift = 24 - 8 * pass;
        const uint32_t prefix = s_prefix;
        const uint32_t kk = s_k;
        const uint32_t hi_mask = pass ? (0xFFFFFFFFu << (shift + 8)) : 0u;
        hist[t] = 0u;
        __syncthreads();
        for (int i = t; i < NN; i += 256) {
            uint32_t kv = keys[i];
            if ((kv & hi_mask) == prefix)
                atomicAdd(&hist[(kv >> shift) & 255], 1u);
        }
        __syncthreads();
        uint32_t c = hist[t];
        uint32_t s = c;
        #pragma unroll
        for (int off = 1; off < 64; off <<= 1) {     // in-wave inclusive suffix sum
            uint32_t vsh = __shfl_down(s, off);
            s += (lane + off < 64) ? vsh : 0u;
        }
        if (lane == 0) wtot[w] = s;
        __syncthreads();
        uint32_t above = 0;
        for (int w2 = w + 1; w2 < 4; ++w2) above += wtot[w2];
        uint32_t cum_incl = s + above;               // count of bins >= t
        uint32_t cum_excl = cum_incl - c;            // count of bins >  t
        if (cum_excl < kk && kk <= cum_incl) {       // exactly one winner
            s_prefix = prefix | ((uint32_t)t << shift);
            s_k = kk - cum_excl;
        }
        __syncthreads();
    }

    const uint32_t thr_key = s_prefix;               // key of k-th largest (exact)
    #pragma unroll
    for (int i = 0; i < 4; ++i) {
        uint32_t kv = keys[i * 256 + t];
        bool pred = (kv >= thr_key) && (kv > 0x80000000u);   // adj>=thr && adj>0
        uint64_t bal = __ballot(pred);
        if (lane == 0) mask[(size_t)row * 16 + i * 4 + w] = bal;
    }
}

// ---------------- K1b: 64x64 bit-transpose of the mask (ballot-based) ----------------
__global__ __launch_bounds__(256) void k_maskT(
    const uint64_t* __restrict__ mask, uint64_t* __restrict__ maskT)
{
    const int tile = blockIdx.x * 4 + (threadIdx.x >> 6);  // b*256 + uw*16 + vw
    const int lane = threadIdx.x & 63;
    const int b  = tile >> 8;
    const int uw = (tile >> 4) & 15;
    const int vw = tile & 15;
    const size_t bN = (size_t)b * NN;
    uint64_t w = mask[(bN + uw * 64 + lane) * 16 + vw];
    uint64_t r_out = 0;
    #pragma unroll
    for (int j = 0; j < 64; ++j) {
        uint64_t r = __ballot((w >> j) & 1ull);
        if (lane == j) r_out = r;
    }
    maskT[(bN + vw * 64 + lane) * 16 + uw] = r_out;
}

// ---------------- K2: f_t = bf16((x@W)^T per (b,h)), res = x@rW, el/er dots ----------
template<int K>
__global__ __launch_bounds__(256) void k_features(
    const float* __restrict__ x,   // [B*N][K]
    const float* __restrict__ W,   // [K][256]
    const float* __restrict__ rW,  // [K][256]
    const float* __restrict__ al,  // [256]
    const float* __restrict__ ar,  // [256]
    short* __restrict__ ft,        // [(B*4+h)*64+d][NN] bf16, transposed features
    float* __restrict__ res,       // [B*N][256]  (may alias x: rows read to LDS first)
    float* __restrict__ el_t,      // [(b*4+h)][NN], scaled by LOG2E
    float* __restrict__ er_t)      // [(b*4+h)][NN], scaled by LOG2E
{
    __shared__ float xs[K * 16];   // [k][i] transposed tile of 16 node rows
    const int t = threadIdx.x;
    const size_t n0 = (size_t)blockIdx.x * 16;
    const float* xb = x + n0 * K;
    for (int idx = t; idx < 16 * K; idx += 256)
        xs[(idx % K) * 16 + (idx / K)] = xb[idx];
    __syncthreads();

    float accf[16], accr[16];
    #pragma unroll
    for (int i = 0; i < 16; ++i) { accf[i] = 0.f; accr[i] = 0.f; }
    const int o = t;
    for (int k = 0; k < K; ++k) {
        float wv = W[k * 256 + o];
        float rv = rW[k * 256 + o];
        const float4* xr = (const float4*)&xs[k * 16];
        float4 x0 = xr[0], x1 = xr[1], x2 = xr[2], x3 = xr[3];
        accf[0]  += x0.x * wv;  accr[0]  += x0.x * rv;
        accf[1]  += x0.y * wv;  accr[1]  += x0.y * rv;
        accf[2]  += x0.z * wv;  accr[2]  += x0.z * rv;
        accf[3]  += x0.w * wv;  accr[3]  += x0.w * rv;
        accf[4]  += x1.x * wv;  accr[4]  += x1.x * rv;
        accf[5]  += x1.y * wv;  accr[5]  += x1.y * rv;
        accf[6]  += x1.z * wv;  accr[6]  += x1.z * rv;
        accf[7]  += x1.w * wv;  accr[7]  += x1.w * rv;
        accf[8]  += x2.x * wv;  accr[8]  += x2.x * rv;
        accf[9]  += x2.y * wv;  accr[9]  += x2.y * rv;
        accf[10] += x2.z * wv;  accr[10] += x2.z * rv;
        accf[11] += x2.w * wv;  accr[11] += x2.w * rv;
        accf[12] += x3.x * wv;  accr[12] += x3.x * rv;
        accf[13] += x3.y * wv;  accr[13] += x3.y * rv;
        accf[14] += x3.z * wv;  accr[14] += x3.z * rv;
        accf[15] += x3.w * wv;  accr[15] += x3.w * rv;
    }
    const int b_idx = (int)(n0 / NN);
    const int nb = (int)(n0 % NN);
    // res fp32 row-major, f bf16 transposed [(b,h,d)][u]
    short8 t0, t1;
    #pragma unroll
    for (int i = 0; i < 8; ++i)  t0[i] = f2bf(accf[i]);
    #pragma unroll
    for (int i = 0; i < 8; ++i)  t1[i] = f2bf(accf[8 + i]);
    {
        short* dst = ft + ((size_t)(b_idx * 4 + (t >> 6)) * 64 + (t & 63)) * NN + nb;
        *(short8*)dst = t0;
        *(short8*)(dst + 8) = t1;
    }
    #pragma unroll
    for (int i = 0; i < 16; ++i)
        res[(n0 + i) * 256 + o] = accr[i];

    // el/er: wave w handles head h=w (o = h*64+d), reduce over d (64 lanes)
    const float alv = al[o], arv = ar[o];
    const int lane = t & 63, h = t >> 6;
    #pragma unroll
    for (int i = 0; i < 16; ++i) {
        float pe = accf[i] * alv;
        float pr = accf[i] * arv;
        #pragma unroll
        for (int off = 32; off; off >>= 1) {
            pe += __shfl_xor(pe, off);
            pr += __shfl_xor(pr, off);
        }
        if (lane == 0) {
            el_t[(size_t)(b_idx * 4 + h) * NN + nb + i] = pe * LOG2E;
            er_t[(size_t)(b_idx * 4 + h) * NN + nb + i] = pr * LOG2E;
        }
    }
}

// ---------------- K3: unmasked max over src nodes of el (per (b,h)) ----------------
__global__ __launch_bounds__(256) void k_elmax(
    const float* __restrict__ el_t, float* __restrict__ elmax)
{
    const int bh = blockIdx.x;
    const int t = threadIdx.x;
    float m = -1e30f;
    for (int n = t; n < NN; n += 256)
        m = fmaxf(m, el_t[(size_t)bh * NN + n]);
    #pragma unroll
    for (int off = 32; off; off >>= 1) m = fmaxf(m, __shfl_xor(m, off));
    __shared__ float sm[4];
    if ((t & 63) == 0) sm[t >> 6] = m;
    __syncthreads();
    if (t == 0) elmax[bh] = fmaxf(fmaxf(sm[0], sm[1]), fmaxf(sm[2], sm[3]));
}

// ---------------- K4: masked softmax over u + MFMA PV + residual + bias (+ELU) ------
// P computed per-lane directly in MFMA A-fragment layout; mask bits register-held
// (transposed layout); denominator via 5th MFMA with all-ones B; zero barriers in loop.
template<int ELU_ON>
__global__ __launch_bounds__(256, 4) void k_attn(
    const short* __restrict__ ft,     // [(b*4+h)*64+d][NN] bf16
    const float* __restrict__ res,    // [B*N][256]
    const float* __restrict__ el_t,   // [(b*4+h)][NN] scaled
    const float* __restrict__ er_t,   // [(b*4+h)][NN] scaled
    const float* __restrict__ elmax,  // [(b*4+h)]
    const uint64_t* __restrict__ maskT,// [b*N + v][16] u-words
    const float* __restrict__ bias,   // [256]
    float* __restrict__ out)          // [B*N][256] (may alias res: in-place per element)
{
    const int vt = blockIdx.x;        // v-tile (16 of 64)
    const int h  = blockIdx.y;
    const int b  = blockIdx.z;
    const int v0 = vt * 64;
    const int t = threadIdx.x;
    const int lane = t & 63, g = t >> 6;       // g = wave id
    const int l15 = lane & 15, l4 = (lane >> 4) & 3;
    const int vloc = g * 16 + l15;             // this lane's A-row (v within 64-tile)
    const int bh = b * 4 + h;
    const size_t bN = (size_t)b * NN;

    __shared__ float el_lds[NN];
    ((float4*)el_lds)[t] = ((const float4*)(el_t + (size_t)bh * NN))[t];

    const float erv = er_t[(size_t)bh * NN + v0 + vloc];
    const uint64_t* mrow = maskT + (size_t)(bN + v0 + vloc) * 16;
    __syncthreads();

    float e0 = elmax[bh] + erv;
    const float cv = fmaxf(e0, 0.2f * e0);         // lrelu monotone -> valid shift
    const float c1 = erv - cv;
    const float c2 = 0.2f * erv - cv;

    const short* fB = ft + ((size_t)bh * 64 + l15) * NN + l4 * 8;
    const size_t dstride = (size_t)16 * NN;

    short8 ones8;
    #pragma unroll
    for (int i = 0; i < 8; ++i) ones8[i] = (short)0x3F80;   // bf16 1.0

    f32x4 acc[4];
    #pragma unroll
    for (int i = 0; i < 4; ++i) acc[i] = (f32x4){0.f, 0.f, 0.f, 0.f};
    f32x4 accd = (f32x4){0.f, 0.f, 0.f, 0.f};

    // pipeline prologue: chunk 0
    short8 cb0 = *(const short8*)(fB);
    short8 cb1 = *(const short8*)(fB + dstride);
    short8 cb2 = *(const short8*)(fB + 2 * dstride);
    short8 cb3 = *(const short8*)(fB + 3 * dstride);
    uint64_t mt = mrow[0];

    #pragma unroll 2
    for (int c = 0; c < 32; ++c) {
        const int cn = (c < 31) ? c + 1 : 31;
        // prefetch next chunk
        short8 nb0 = *(const short8*)(fB + cn * 32);
        short8 nb1 = *(const short8*)(fB + cn * 32 + dstride);
        short8 nb2 = *(const short8*)(fB + cn * 32 + 2 * dstride);
        short8 nb3 = *(const short8*)(fB + cn * 32 + 3 * dstride);
        uint64_t mtn = ((cn >> 1) != (c >> 1)) ? mrow[cn >> 1] : mt;

        // mask bits for this lane's 8 u's: one register dword
        uint32_t dw = (uint32_t)((c & 1) ? (mt >> 32) : mt);
        uint32_t shifted = dw >> (l4 * 8);

        const float* evp = &el_lds[c * 32 + l4 * 8];
        float4 ev0 = *(const float4*)(evp);
        float4 ev1 = *(const float4*)(evp + 4);
        float ev[8] = {ev0.x, ev0.y, ev0.z, ev0.w, ev1.x, ev1.y, ev1.z, ev1.w};

        short8 av;
        #pragma unroll
        for (int j = 0; j < 8; ++j) {
            float e1 = ev[j] + c1;
            float e2 = fmaf(0.2f, ev[j], c2);
            float arg = fmaxf(e1, e2);                  // lrelu(e) - cv, in log2 units
            float pv = ((shifted >> j) & 1u) ? exp2f(arg) : 0.f;
            av[j] = f2bf(pv);
        }
        acc[0] = __builtin_amdgcn_mfma_f32_16x16x32_bf16(av, cb0, acc[0], 0, 0, 0);
        acc[1] = __builtin_amdgcn_mfma_f32_16x16x32_bf16(av, cb1, acc[1], 0, 0, 0);
        acc[2] = __builtin_amdgcn_mfma_f32_16x16x32_bf16(av, cb2, acc[2], 0, 0, 0);
        acc[3] = __builtin_amdgcn_mfma_f32_16x16x32_bf16(av, cb3, acc[3], 0, 0, 0);
        accd   = __builtin_amdgcn_mfma_f32_16x16x32_bf16(av, ones8, accd, 0, 0, 0);

        cb0 = nb0; cb1 = nb1; cb2 = nb2; cb3 = nb3; mt = mtn;
    }

    // accd[r] = den for v = g*16 + l4*4 + r (all 16 cols identical)
    float rcp[4];
    #pragma unroll
    for (int r = 0; r < 4; ++r)
        rcp[r] = 1.f / fmaxf(accd[r], 1e-9f);          // jnp.clip(sum, 1e-9)

    // D layout: col(l15)=d-local, row = l4*4+r = v-local within wave strip
    #pragma unroll
    for (int dt = 0; dt < 4; ++dt) {
        const int d = dt * 16 + l15;
        const float bv = bias[h * 64 + d];
        #pragma unroll
        for (int r = 0; r < 4; ++r) {
            const int vl = g * 16 + l4 * 4 + r;
            const size_t row = (bN + v0 + vl) * 256 + h * 64 + d;
            float ov = acc[dt][r] * rcp[r] + res[row] + bv;
            if (ELU_ON) ov = ov > 0.f ? ov : __expf(ov) - 1.f;
            out[row] = ov;
        }
    }
}

// ---------------- K5: mean over heads -> d_out ----------------
__global__ __launch_bounds__(256) void k_headmean(
    const float* __restrict__ fea, float* __restrict__ outp)
{
    int i = blockIdx.x * 256 + threadIdx.x;     // i over B*N*64
    int d = i & 63;
    size_t node = (size_t)(i >> 6);
    const float* p = fea + node * 256;
    outp[i] = 0.25f * (p[d] + p[64 + d] + p[128 + d] + p[192 + d]);
}

extern "C" void kernel_launch(void* const* d_in, const int* in_sizes, int n_in,
                              void* d_out, int out_size, void* d_ws, size_t ws_size,
                              hipStream_t stream) {
    const float* seg = (const float*)d_in[0];
    const float* adj = (const float*)d_in[1];
    const float* W0  = (const float*)d_in[2];
    const float* al0 = (const float*)d_in[3];
    const float* ar0 = (const float*)d_in[4];
    const float* rW0 = (const float*)d_in[5];
    const float* b0  = (const float*)d_in[6];
    const float* W1  = (const float*)d_in[7];
    const float* al1 = (const float*)d_in[8];
    const float* ar1 = (const float*)d_in[9];
    const float* rW1 = (const float*)d_in[10];
    const float* b1  = (const float*)d_in[11];
    float* out = (float*)d_out;

    char* ws = (char*)d_ws;
    uint64_t* mask  = (uint64_t*)ws;                     // 2 MB
    size_t off = (size_t)BB * NN * 16 * 8;
    uint64_t* maskT = (uint64_t*)(ws + off); off += (size_t)BB * NN * 16 * 8;   // 2 MB
    short* ftb  = (short*)(ws + off); off += (size_t)BB * 4 * 64 * NN * 2;  // 8 MB bf16
    float* resA = (float*)(ws + off); off += (size_t)BB * NN * 256 * 4;     // 16 MB
    float* el   = (float*)(ws + off); off += (size_t)BB * 4 * NN * 4;       // 256 KB
    float* er   = (float*)(ws + off); off += (size_t)BB * 4 * NN * 4;       // 256 KB
    float* emx  = (float*)(ws + off); off += (size_t)BB * 4 * 4;

    k_topk_mask<<<BB * NN, 256, 0, stream>>>(adj, mask);
    k_maskT<<<BB * 256 / 4, 256, 0, stream>>>(mask, maskT);

    // layer 0: x = seg (K=64)
    k_features<64><<<BB * NN / 16, 256, 0, stream>>>(seg, W0, rW0, al0, ar0,
                                                     ftb, resA, el, er);
    k_elmax<<<BB * 4, 256, 0, stream>>>(el, emx);
    k_attn<1><<<dim3(16, 4, BB), 256, 0, stream>>>(ftb, resA, el, er, emx, maskT,
                                                   b0, resA);   // out in-place -> fea0
    // layer 1: x = fea0 (K=256)
    k_features<256><<<BB * NN / 16, 256, 0, stream>>>(resA, W1, rW1, al1, ar1,
                                                      ftb, resA, el, er);
    k_elmax<<<BB * 4, 256, 0, stream>>>(el, emx);
    k_attn<0><<<dim3(16, 4, BB), 256, 0, stream>>>(ftb, resA, el, er, emx, maskT,
                                                   b1, resA);   // out in-place -> fea1

    k_headmean<<<BB * NN * 64 / 256, 256, 0, stream>>>(resA, out);
}

// Round 5
// 309.429 us; speedup vs baseline: 1.6887x; 1.0280x over previous
//
#include <hip/hip_runtime.h>
#include <hip/hip_bf16.h>
#include <stdint.h>

#define BB   16
#define NN   1024
#define KSEL 170   // (32*32)/6
#define LOG2E 1.4426950408889634f

typedef __attribute__((ext_vector_type(8))) short short8;
typedef __attribute__((ext_vector_type(4))) short short4v;
typedef __attribute__((ext_vector_type(4))) float f32x4;

static __device__ __forceinline__ short f2bf(float x) {
    __hip_bfloat16 h = __float2bfloat16(x);
    return *reinterpret_cast<short*>(&h);
}
static __device__ __forceinline__ float bf2f(short x) {
    uint32_t u = ((uint32_t)(uint16_t)x) << 16;
    return __uint_as_float(u);
}

// ---------------- K1: exact k-th-largest per row (radix select) + packed mask --------
__global__ __launch_bounds__(256) void k_topk_mask(
    const float* __restrict__ adj, uint64_t* __restrict__ mask)
{
    const int row = blockIdx.x;                 // b*N + u
    const float* a = adj + (size_t)row * NN;
    __shared__ uint32_t hist[256];
    __shared__ uint32_t wtot[4];
    __shared__ uint32_t s_prefix, s_k;
    const int t = threadIdx.x;
    const int lane = t & 63, w = t >> 6;

    uint32_t key[4];
    #pragma unroll
    for (int j = 0; j < 4; ++j) {
        uint32_t u = __float_as_uint(a[j * 256 + t]);
        key[j] = u ^ ((u >> 31) ? 0xFFFFFFFFu : 0x80000000u);   // order-preserving map
    }
    if (t == 0) { s_prefix = 0u; s_k = KSEL; }
    __syncthreads();

    for (int pass = 0; pass < 4; ++pass) {
        const int shift = 24 - 8 * pass;
        const uint32_t prefix = s_prefix;
        const uint32_t kk = s_k;
        const uint32_t hi_mask = pass ? (0xFFFFFFFFu << (shift + 8)) : 0u;
        hist[t] = 0u;
        __syncthreads();
        #pragma unroll
        for (int j = 0; j < 4; ++j) {
            if ((key[j] & hi_mask) == prefix)
                atomicAdd(&hist[(key[j] >> shift) & 255], 1u);
        }
        __syncthreads();
        uint32_t c = hist[t];
        uint32_t s = c;
        #pragma unroll
        for (int off = 1; off < 64; off <<= 1) {     // in-wave inclusive suffix sum
            uint32_t vsh = __shfl_down(s, off);
            s += (lane + off < 64) ? vsh : 0u;
        }
        if (lane == 0) wtot[w] = s;
        __syncthreads();
        uint32_t above = 0;
        for (int w2 = w + 1; w2 < 4; ++w2) above += wtot[w2];
        uint32_t cum_incl = s + above;               // count of bins >= t
        uint32_t cum_excl = cum_incl - c;            // count of bins >  t
        if (cum_excl < kk && kk <= cum_incl) {       // exactly one winner
            s_prefix = prefix | ((uint32_t)t << shift);
            s_k = kk - cum_excl;
        }
        __syncthreads();
    }

    const uint32_t thr_key = s_prefix;               // key of k-th largest (exact)
    #pragma unroll
    for (int j = 0; j < 4; ++j) {
        bool pred = (key[j] >= thr_key) && (key[j] > 0x80000000u);   // adj>=thr && adj>0
        uint64_t bal = __ballot(pred);
        if (lane == 0) mask[(size_t)row * 16 + j * 4 + w] = bal;
    }
}

// ---------------- K1b: 64x64 bit-transpose of the mask (ballot-based) ----------------
__global__ __launch_bounds__(256) void k_maskT(
    const uint64_t* __restrict__ mask, uint64_t* __restrict__ maskT)
{
    const int tile = blockIdx.x * 4 + (threadIdx.x >> 6);  // b*256 + uw*16 + vw
    const int lane = threadIdx.x & 63;
    const int b  = tile >> 8;
    const int uw = (tile >> 4) & 15;
    const int vw = tile & 15;
    const size_t bN = (size_t)b * NN;
    uint64_t w = mask[(bN + uw * 64 + lane) * 16 + vw];
    uint64_t r_out = 0;
    #pragma unroll
    for (int j = 0; j < 64; ++j) {
        uint64_t r = __ballot((w >> j) & 1ull);
        if (lane == j) r_out = r;
    }
    maskT[(bN + vw * 64 + lane) * 16 + uw] = r_out;
}

// ---------------- K1c: transpose W [K][256] fp32 -> Wt [256][K] bf16 -----------------
__global__ __launch_bounds__(256) void k_prep(
    const float* __restrict__ W, short* __restrict__ Wt, int K)
{
    int idx = blockIdx.x * 256 + threadIdx.x;    // over 256*K
    int o = idx / K, k = idx - o * K;
    Wt[idx] = f2bf(W[(size_t)k * 256 + o]);
}

// ---------------- K1d: fp32 -> bf16 flat convert -------------------------------------
__global__ __launch_bounds__(256) void k_cvt(
    const float* __restrict__ src, short* __restrict__ dst)
{
    int i = (blockIdx.x * 256 + threadIdx.x) * 4;
    float4 v = *(const float4*)(src + i);
    short4v o;
    o[0] = f2bf(v.x); o[1] = f2bf(v.y); o[2] = f2bf(v.z); o[3] = f2bf(v.w);
    *(short4v*)(dst + i) = o;
}

// ---------------- K2: MFMA features: f^T bf16, res bf16, el/er -----------------------
// Per wave: 16 nodes x all 256 outputs. Two passes (W then rW). A=x rows, B=Wt rows.
template<int K>
__global__ __launch_bounds__(256) void k_features_mfma(
    const short* __restrict__ xb,   // [B*N][K] bf16 row-major
    const short* __restrict__ Wt,   // [256][K] bf16
    const short* __restrict__ rWt,  // [256][K] bf16
    const float* __restrict__ al,   // [256]
    const float* __restrict__ ar,   // [256]
    short* __restrict__ ft,         // [(b*4+h)*64+d][NN] bf16 transposed features
    short* __restrict__ fea,        // [B*N][256] bf16: res written here
    float* __restrict__ el_t,       // [(b*4+h)][NN] scaled by LOG2E
    float* __restrict__ er_t)       // [(b*4+h)][NN] scaled by LOG2E
{
    const int t = threadIdx.x, lane = t & 63, g = t >> 6;
    const int l15 = lane & 15, l4 = lane >> 4;
    const int n0 = blockIdx.x * 64 + g * 16;     // wave's 16-node strip
    const int b_idx = n0 >> 10;                  // NN = 1024
    const int nloc = n0 & (NN - 1);
    const short* xrow = xb + ((size_t)n0 + l15) * K + l4 * 8;

    // ---- pass 1: f = x @ W ----
    f32x4 accf[16];
    #pragma unroll
    for (int i = 0; i < 16; ++i) accf[i] = (f32x4){0.f, 0.f, 0.f, 0.f};
    #pragma unroll
    for (int ks = 0; ks < K / 32; ++ks) {
        short8 av = *(const short8*)(xrow + ks * 32);
        #pragma unroll
        for (int ot = 0; ot < 16; ++ot) {
            short8 bw = *(const short8*)(Wt + ((size_t)(ot * 16 + l15)) * K + ks * 32 + l4 * 8);
            accf[ot] = __builtin_amdgcn_mfma_f32_16x16x32_bf16(av, bw, accf[ot], 0, 0, 0);
        }
    }
    // store f^T: lane holds col o=ot*16+l15, rows n = n0 + l4*4 + r
    #pragma unroll
    for (int ot = 0; ot < 16; ++ot) {
        short4v pk;
        #pragma unroll
        for (int r = 0; r < 4; ++r) pk[r] = f2bf(accf[ot][r]);
        *(short4v*)(ft + ((size_t)(b_idx * 256 + ot * 16 + l15)) * NN + nloc + l4 * 4) = pk;
    }
    // el/er dots over o within each head (16 l15-lanes cover the 64 o's of a head)
    float elh[4][4], erh[4][4];
    #pragma unroll
    for (int hh = 0; hh < 4; ++hh)
        #pragma unroll
        for (int r = 0; r < 4; ++r) { elh[hh][r] = 0.f; erh[hh][r] = 0.f; }
    #pragma unroll
    for (int hh = 0; hh < 4; ++hh) {
        #pragma unroll
        for (int q = 0; q < 4; ++q) {
            const int ot = hh * 4 + q;
            const float alv = al[ot * 16 + l15];
            const float arv = ar[ot * 16 + l15];
            #pragma unroll
            for (int r = 0; r < 4; ++r) {
                elh[hh][r] = fmaf(accf[ot][r], alv, elh[hh][r]);
                erh[hh][r] = fmaf(accf[ot][r], arv, erh[hh][r]);
            }
        }
    }
    #pragma unroll
    for (int hh = 0; hh < 4; ++hh)
        #pragma unroll
        for (int r = 0; r < 4; ++r) {
            float e = elh[hh][r], rr = erh[hh][r];
            #pragma unroll
            for (int off = 1; off < 16; off <<= 1) {
                e  += __shfl_xor(e,  off);
                rr += __shfl_xor(rr, off);
            }
            elh[hh][r] = e; erh[hh][r] = rr;
        }
    #pragma unroll
    for (int hh = 0; hh < 4; ++hh) {
        if (l15 == hh) {
            #pragma unroll
            for (int r = 0; r < 4; ++r)
                el_t[((size_t)b_idx * 4 + hh) * NN + nloc + l4 * 4 + r] = elh[hh][r] * LOG2E;
        }
        if (l15 == hh + 4) {
            #pragma unroll
            for (int r = 0; r < 4; ++r)
                er_t[((size_t)b_idx * 4 + hh) * NN + nloc + l4 * 4 + r] = erh[hh][r] * LOG2E;
        }
    }
    // ---- pass 2: res = x @ rW ----
    f32x4 accr[16];
    #pragma unroll
    for (int i = 0; i < 16; ++i) accr[i] = (f32x4){0.f, 0.f, 0.f, 0.f};
    #pragma unroll
    for (int ks = 0; ks < K / 32; ++ks) {
        short8 av = *(const short8*)(xrow + ks * 32);
        #pragma unroll
        for (int ot = 0; ot < 16; ++ot) {
            short8 bw = *(const short8*)(rWt + ((size_t)(ot * 16 + l15)) * K + ks * 32 + l4 * 8);
            accr[ot] = __builtin_amdgcn_mfma_f32_16x16x32_bf16(av, bw, accr[ot], 0, 0, 0);
        }
    }
    #pragma unroll
    for (int ot = 0; ot < 16; ++ot)
        #pragma unroll
        for (int r = 0; r < 4; ++r)
            fea[((size_t)n0 + l4 * 4 + r) * 256 + ot * 16 + l15] = f2bf(accr[ot][r]);
}

// ---------------- K3: unmasked max over src nodes of el (per (b,h)) ----------------
__global__ __launch_bounds__(256) void k_elmax(
    const float* __restrict__ el_t, float* __restrict__ elmax)
{
    const int bh = blockIdx.x;
    const int t = threadIdx.x;
    float m = -1e30f;
    for (int n = t; n < NN; n += 256)
        m = fmaxf(m, el_t[(size_t)bh * NN + n]);
    #pragma unroll
    for (int off = 32; off; off >>= 1) m = fmaxf(m, __shfl_xor(m, off));
    __shared__ float sm[4];
    if ((t & 63) == 0) sm[t >> 6] = m;
    __syncthreads();
    if (t == 0) elmax[bh] = fmaxf(fmaxf(sm[0], sm[1]), fmaxf(sm[2], sm[3]));
}

// ---------------- K4: masked softmax + MFMA PV + residual + bias (+ELU), bf16 out ----
// 1-wave blocks (16 v x 64 d), explicit 2-deep register pipeline, zero barriers in loop.
template<int ELU_ON>
__global__ __launch_bounds__(64, 4) void k_attn(
    const short* __restrict__ ft,     // [(b*4+h)*64+d][NN] bf16
    const float* __restrict__ el_t,   // [(b*4+h)][NN] scaled
    const float* __restrict__ er_t,   // [(b*4+h)][NN] scaled
    const float* __restrict__ elmax,  // [(b*4+h)]
    const uint64_t* __restrict__ maskT,// [b*N + v][16] u-words
    const float* __restrict__ bias,   // [256]
    short* fea)                       // [B*N][256] bf16: res in, out in-place
{
    const int vt = blockIdx.x;        // 64 v-tiles of 16
    const int h  = blockIdx.y;
    const int b  = blockIdx.z;
    const int v0 = vt * 16;
    const int lane = threadIdx.x;
    const int l15 = lane & 15, l4 = lane >> 4;
    const int bh = b * 4 + h;
    const size_t bN = (size_t)b * NN;

    __shared__ float el_lds[NN];
    {
        const float4* src = (const float4*)(el_t + (size_t)bh * NN);
        float4* dst = (float4*)el_lds;
        #pragma unroll
        for (int i = 0; i < 4; ++i) dst[lane + 64 * i] = src[lane + 64 * i];
    }
    const float erv = er_t[(size_t)bh * NN + v0 + l15];
    const uint32_t* mrow = (const uint32_t*)(maskT + (size_t)(bN + v0 + l15) * 16);
    __syncthreads();

    const float e0 = elmax[bh] + erv;
    const float cv = fmaxf(e0, 0.2f * e0);     // lrelu monotone -> valid softmax shift
    const float c1 = erv - cv;
    const float c2 = 0.2f * erv - cv;

    const short* fB = ft + ((size_t)bh * 64 + l15) * NN + l4 * 8;
    const size_t dstr = (size_t)16 * NN;

    short8 ones8;
    #pragma unroll
    for (int i = 0; i < 8; ++i) ones8[i] = (short)0x3F80;   // bf16 1.0

    f32x4 acc[4];
    #pragma unroll
    for (int i = 0; i < 4; ++i) acc[i] = (f32x4){0.f, 0.f, 0.f, 0.f};
    f32x4 accd = (f32x4){0.f, 0.f, 0.f, 0.f};

    // 2-deep pipeline stage registers
    short8 A0, A1, A2, A3, B0, B1, B2, B3;
    float4 Ae0, Ae1, Be0, Be1;
    uint32_t Am, Bm;

    auto issue = [&](int cn, short8& s0, short8& s1, short8& s2, short8& s3,
                     float4& ev0, float4& ev1, uint32_t& mw) {
        const short* p = fB + cn * 32;
        s0 = *(const short8*)(p);
        s1 = *(const short8*)(p + dstr);
        s2 = *(const short8*)(p + 2 * dstr);
        s3 = *(const short8*)(p + 3 * dstr);
        mw = mrow[cn];
        const float* ep = &el_lds[cn * 32 + l4 * 8];
        ev0 = *(const float4*)(ep);
        ev1 = *(const float4*)(ep + 4);
        __builtin_amdgcn_sched_barrier(0);     // pin load-issue point
    };
    auto compute = [&](short8 s0, short8 s1, short8 s2, short8 s3,
                       float4 ev0, float4 ev1, uint32_t mw) {
        const float ev[8] = {ev0.x, ev0.y, ev0.z, ev0.w, ev1.x, ev1.y, ev1.z, ev1.w};
        const uint32_t sh = mw >> (l4 * 8);
        short8 av;
        #pragma unroll
        for (int j = 0; j < 8; ++j) {
            float a1 = ev[j] + c1;
            float a2 = fmaf(0.2f, ev[j], c2);
            float arg = fmaxf(a1, a2);                       // lrelu(e)-cv, log2 units
            float pv = ((sh >> j) & 1u) ? exp2f(arg) : 0.f;
            av[j] = f2bf(pv);
        }
        __builtin_amdgcn_s_setprio(1);
        acc[0] = __builtin_amdgcn_mfma_f32_16x16x32_bf16(av, s0, acc[0], 0, 0, 0);
        acc[1] = __builtin_amdgcn_mfma_f32_16x16x32_bf16(av, s1, acc[1], 0, 0, 0);
        acc[2] = __builtin_amdgcn_mfma_f32_16x16x32_bf16(av, s2, acc[2], 0, 0, 0);
        acc[3] = __builtin_amdgcn_mfma_f32_16x16x32_bf16(av, s3, acc[3], 0, 0, 0);
        accd   = __builtin_amdgcn_mfma_f32_16x16x32_bf16(av, ones8, accd, 0, 0, 0);
        __builtin_amdgcn_s_setprio(0);
    };

    issue(0, A0, A1, A2, A3, Ae0, Ae1, Am);
    issue(1, B0, B1, B2, B3, Be0, Be1, Bm);
    #pragma unroll 1
    for (int c = 0; c < 32; c += 2) {
        compute(A0, A1, A2, A3, Ae0, Ae1, Am);
        issue(c + 2 < 32 ? c + 2 : 30, A0, A1, A2, A3, Ae0, Ae1, Am);
        compute(B0, B1, B2, B3, Be0, Be1, Bm);
        issue(c + 3 < 32 ? c + 3 : 31, B0, B1, B2, B3, Be0, Be1, Bm);
    }

    // accd[r] = den for v = v0 + l4*4 + r (all 16 cols identical)
    float rcp[4];
    #pragma unroll
    for (int r = 0; r < 4; ++r)
        rcp[r] = 1.f / fmaxf(accd[r], 1e-9f);          // jnp.clip(sum, 1e-9)

    // D layout: col(l15) = d-local within dt block, row = l4*4+r = v-local
    #pragma unroll
    for (int dt = 0; dt < 4; ++dt) {
        const int d = dt * 16 + l15;
        const float bv = bias[h * 64 + d];
        #pragma unroll
        for (int r = 0; r < 4; ++r) {
            const int vl = l4 * 4 + r;
            const size_t row = (bN + v0 + vl) * 256 + h * 64 + d;
            float ov = acc[dt][r] * rcp[r] + bf2f(fea[row]) + bv;
            if (ELU_ON) ov = ov > 0.f ? ov : __expf(ov) - 1.f;
            fea[row] = f2bf(ov);                       // in-place res -> out
        }
    }
}

// ---------------- K5: mean over heads (bf16 in) -> d_out fp32 ----------------
__global__ __launch_bounds__(256) void k_headmean(
    const short* __restrict__ fea, float* __restrict__ outp)
{
    int i = blockIdx.x * 256 + threadIdx.x;     // i over B*N*64
    int d = i & 63;
    size_t node = (size_t)(i >> 6);
    const short* p = fea + node * 256;
    outp[i] = 0.25f * (bf2f(p[d]) + bf2f(p[64 + d]) + bf2f(p[128 + d]) + bf2f(p[192 + d]));
}

extern "C" void kernel_launch(void* const* d_in, const int* in_sizes, int n_in,
                              void* d_out, int out_size, void* d_ws, size_t ws_size,
                              hipStream_t stream) {
    const float* seg = (const float*)d_in[0];
    const float* adj = (const float*)d_in[1];
    const float* W0  = (const float*)d_in[2];
    const float* al0 = (const float*)d_in[3];
    const float* ar0 = (const float*)d_in[4];
    const float* rW0 = (const float*)d_in[5];
    const float* b0  = (const float*)d_in[6];
    const float* W1  = (const float*)d_in[7];
    const float* al1 = (const float*)d_in[8];
    const float* ar1 = (const float*)d_in[9];
    const float* rW1 = (const float*)d_in[10];
    const float* b1  = (const float*)d_in[11];
    float* out = (float*)d_out;

    char* ws = (char*)d_ws;
    size_t off = 0;
    uint64_t* mask  = (uint64_t*)ws;                 // 2 MB (dead after k_maskT)
    off += (size_t)BB * NN * 16 * 8;
    uint64_t* maskT = (uint64_t*)(ws + off); off += (size_t)BB * NN * 16 * 8;  // 2 MB
    short* ftb = (short*)(ws + off); off += (size_t)BB * 256 * NN * 2;         // 8 MB
    short* fea = (short*)(ws + off); off += (size_t)BB * NN * 256 * 2;         // 8 MB
    short* xb0 = (short*)(ws + off); off += (size_t)BB * NN * 64 * 2;          // 2 MB
    // small buffers reuse the dead `mask` region (valid after k_maskT completes)
    char* r0 = (char*)mask;
    short* Wt0  = (short*)r0;                 r0 += 256 * 64 * 2;
    short* rWt0 = (short*)r0;                 r0 += 256 * 64 * 2;
    short* Wt1  = (short*)r0;                 r0 += 256 * 256 * 2;
    short* rWt1 = (short*)r0;                 r0 += 256 * 256 * 2;
    float* el   = (float*)r0;                 r0 += (size_t)BB * 4 * NN * 4;
    float* er   = (float*)r0;                 r0 += (size_t)BB * 4 * NN * 4;
    float* emx  = (float*)r0;                 r0 += BB * 4 * 4;

    k_topk_mask<<<BB * NN, 256, 0, stream>>>(adj, mask);
    k_maskT<<<BB * 256 / 4, 256, 0, stream>>>(mask, maskT);
    // mask region now dead -> safe to fill Wt/el/er
    k_prep<<<64, 256, 0, stream>>>(W0, Wt0, 64);
    k_prep<<<64, 256, 0, stream>>>(rW0, rWt0, 64);
    k_prep<<<256, 256, 0, stream>>>(W1, Wt1, 256);
    k_prep<<<256, 256, 0, stream>>>(rW1, rWt1, 256);
    k_cvt<<<BB * NN * 64 / 1024, 256, 0, stream>>>(seg, xb0);

    // layer 0 (K=64)
    k_features_mfma<64><<<BB * NN / 64, 256, 0, stream>>>(xb0, Wt0, rWt0, al0, ar0,
                                                          ftb, fea, el, er);
    k_elmax<<<BB * 4, 256, 0, stream>>>(el, emx);
    k_attn<1><<<dim3(64, 4, BB), 64, 0, stream>>>(ftb, el, er, emx, maskT, b0, fea);
    // layer 1 (K=256): x = fea (bf16), res overwrites fea in-block after reads
    k_features_mfma<256><<<BB * NN / 64, 256, 0, stream>>>(fea, Wt1, rWt1, al1, ar1,
                                                           ftb, fea, el, er);
    k_elmax<<<BB * 4, 256, 0, stream>>>(el, emx);
    k_attn<0><<<dim3(64, 4, BB), 64, 0, stream>>>(ftb, el, er, emx, maskT, b1, fea);

    k_headmean<<<BB * NN * 64 / 256, 256, 0, stream>>>(fea, out);
}

// Round 6
// 225.469 us; speedup vs baseline: 2.3176x; 1.3724x over previous
//
#include <hip/hip_runtime.h>
#include <hip/hip_bf16.h>
#include <stdint.h>

#define BB   16
#define NN   1024
#define KSEL 170   // (32*32)/6
#define LOG2E 1.4426950408889634f

typedef __attribute__((ext_vector_type(8))) short short8;
typedef __attribute__((ext_vector_type(4))) short short4v;
typedef __attribute__((ext_vector_type(4))) float f32x4;

static __device__ __forceinline__ short f2bf(float x) {
    __hip_bfloat16 h = __float2bfloat16(x);
    return *reinterpret_cast<short*>(&h);
}
static __device__ __forceinline__ float bf2f(short x) {
    uint32_t u = ((uint32_t)(uint16_t)x) << 16;
    return __uint_as_float(u);
}
static __device__ __forceinline__ float fast_exp2(float x) {
    float r; asm("v_exp_f32 %0, %1" : "=v"(r) : "v"(x)); return r;
}

// ---------------- K1: exact k-th-largest per row (radix select) + packed mask --------
__global__ __launch_bounds__(256) void k_topk_mask(
    const float* __restrict__ adj, uint64_t* __restrict__ mask)
{
    const int row = blockIdx.x;                 // b*N + u
    const float* a = adj + (size_t)row * NN;
    __shared__ uint32_t hist[256];
    __shared__ uint32_t wtot[4];
    __shared__ uint32_t s_prefix, s_k;
    const int t = threadIdx.x;
    const int lane = t & 63, w = t >> 6;

    uint32_t key[4];
    #pragma unroll
    for (int j = 0; j < 4; ++j) {
        uint32_t u = __float_as_uint(a[j * 256 + t]);
        key[j] = u ^ ((u >> 31) ? 0xFFFFFFFFu : 0x80000000u);   // order-preserving map
    }
    if (t == 0) { s_prefix = 0u; s_k = KSEL; }
    __syncthreads();

    for (int pass = 0; pass < 4; ++pass) {
        const int shift = 24 - 8 * pass;
        const uint32_t prefix = s_prefix;
        const uint32_t kk = s_k;
        const uint32_t hi_mask = pass ? (0xFFFFFFFFu << (shift + 8)) : 0u;
        hist[t] = 0u;
        __syncthreads();
        #pragma unroll
        for (int j = 0; j < 4; ++j) {
            if ((key[j] & hi_mask) == prefix)
                atomicAdd(&hist[(key[j] >> shift) & 255], 1u);
        }
        __syncthreads();
        uint32_t c = hist[t];
        uint32_t s = c;
        #pragma unroll
        for (int off = 1; off < 64; off <<= 1) {     // in-wave inclusive suffix sum
            uint32_t vsh = __shfl_down(s, off);
            s += (lane + off < 64) ? vsh : 0u;
        }
        if (lane == 0) wtot[w] = s;
        __syncthreads();
        uint32_t above = 0;
        for (int w2 = w + 1; w2 < 4; ++w2) above += wtot[w2];
        uint32_t cum_incl = s + above;               // count of bins >= t
        uint32_t cum_excl = cum_incl - c;            // count of bins >  t
        if (cum_excl < kk && kk <= cum_incl) {       // exactly one winner
            s_prefix = prefix | ((uint32_t)t << shift);
            s_k = kk - cum_excl;
        }
        __syncthreads();
    }

    const uint32_t thr_key = s_prefix;               // key of k-th largest (exact)
    #pragma unroll
    for (int j = 0; j < 4; ++j) {
        bool pred = (key[j] >= thr_key) && (key[j] > 0x80000000u);   // adj>=thr && adj>0
        uint64_t bal = __ballot(pred);
        if (lane == 0) mask[(size_t)row * 16 + j * 4 + w] = bal;
    }
}

// ---------------- K1b: 64x64 bit-transpose of the mask (ballot-based) ----------------
__global__ __launch_bounds__(256) void k_maskT(
    const uint64_t* __restrict__ mask, uint64_t* __restrict__ maskT)
{
    const int tile = blockIdx.x * 4 + (threadIdx.x >> 6);  // b*256 + uw*16 + vw
    const int lane = threadIdx.x & 63;
    const int b  = tile >> 8;
    const int uw = (tile >> 4) & 15;
    const int vw = tile & 15;
    const size_t bN = (size_t)b * NN;
    uint64_t w = mask[(bN + uw * 64 + lane) * 16 + vw];
    uint64_t r_out = 0;
    #pragma unroll
    for (int j = 0; j < 64; ++j) {
        uint64_t r = __ballot((w >> j) & 1ull);
        if (lane == j) r_out = r;
    }
    maskT[(bN + vw * 64 + lane) * 16 + uw] = r_out;
}

// ---------------- K1c: transpose W [K][256] fp32 -> Wt [256][K] bf16 -----------------
__global__ __launch_bounds__(256) void k_prep(
    const float* __restrict__ W, short* __restrict__ Wt, int K)
{
    int idx = blockIdx.x * 256 + threadIdx.x;    // over 256*K
    int o = idx / K, k = idx - o * K;
    Wt[idx] = f2bf(W[(size_t)k * 256 + o]);
}

// ---------------- K1d: fp32 -> bf16 flat convert -------------------------------------
__global__ __launch_bounds__(256) void k_cvt(
    const float* __restrict__ src, short* __restrict__ dst)
{
    int i = (blockIdx.x * 256 + threadIdx.x) * 4;
    float4 v = *(const float4*)(src + i);
    short4v o;
    o[0] = f2bf(v.x); o[1] = f2bf(v.y); o[2] = f2bf(v.z); o[3] = f2bf(v.w);
    *(short4v*)(dst + i) = o;
}

// ---------------- K2: MFMA features: tiled f^T bf16, res bf16, el/er -----------------
// Per wave: 16 nodes x all 256 outputs. ft layout: [bh][ut16][g8][d64][ui8] (LDS image).
template<int K>
__global__ __launch_bounds__(256) void k_features_mfma(
    const short* __restrict__ xb,   // [B*N][K] bf16 row-major
    const short* __restrict__ Wt,   // [256][K] bf16
    const short* __restrict__ rWt,  // [256][K] bf16
    const float* __restrict__ al,   // [256]
    const float* __restrict__ ar,   // [256]
    short* __restrict__ ft,         // tiled transposed features (see above)
    short* __restrict__ fea,        // [B*N][256] bf16: res written here
    float* __restrict__ el_t,       // [(b*4+h)][NN] scaled by LOG2E
    float* __restrict__ er_t)       // [(b*4+h)][NN] scaled by LOG2E
{
    const int t = threadIdx.x, lane = t & 63, g = t >> 6;
    const int l15 = lane & 15, l4 = lane >> 4;
    const int n0 = blockIdx.x * 64 + g * 16;     // wave's 16-node strip
    const int b_idx = n0 >> 10;                  // NN = 1024
    const int nloc = n0 & (NN - 1);
    const short* xrow = xb + ((size_t)n0 + l15) * K + l4 * 8;

    // ---- pass 1: f = x @ W ----
    f32x4 accf[16];
    #pragma unroll
    for (int i = 0; i < 16; ++i) accf[i] = (f32x4){0.f, 0.f, 0.f, 0.f};
    #pragma unroll
    for (int ks = 0; ks < K / 32; ++ks) {
        short8 av = *(const short8*)(xrow + ks * 32);
        #pragma unroll
        for (int ot = 0; ot < 16; ++ot) {
            short8 bw = *(const short8*)(Wt + ((size_t)(ot * 16 + l15)) * K + ks * 32 + l4 * 8);
            accf[ot] = __builtin_amdgcn_mfma_f32_16x16x32_bf16(av, bw, accf[ot], 0, 0, 0);
        }
    }
    // store f^T tiled: u = nloc + (g*16 + l4*4 + r); lane col o = ot*16+l15
    #pragma unroll
    for (int ot = 0; ot < 16; ++ot) {
        short4v pk;
        #pragma unroll
        for (int r = 0; r < 4; ++r) pk[r] = f2bf(accf[ot][r]);
        const int hh = ot >> 2;
        const int dl = (ot & 3) * 16 + l15;
        const size_t idx = ((size_t)(b_idx * 4 + hh) << 16)
                         + (size_t)(nloc >> 6) * 4096
                         + (size_t)(g * 2 + (l4 >> 1)) * 512
                         + (size_t)dl * 8 + (l4 & 1) * 4;
        *(short4v*)(ft + idx) = pk;
    }
    // el/er dots over o within each head (16 l15-lanes cover the 64 o's of a head)
    float elh[4][4], erh[4][4];
    #pragma unroll
    for (int hh = 0; hh < 4; ++hh)
        #pragma unroll
        for (int r = 0; r < 4; ++r) { elh[hh][r] = 0.f; erh[hh][r] = 0.f; }
    #pragma unroll
    for (int hh = 0; hh < 4; ++hh) {
        #pragma unroll
        for (int q = 0; q < 4; ++q) {
            const int ot = hh * 4 + q;
            const float alv = al[ot * 16 + l15];
            const float arv = ar[ot * 16 + l15];
            #pragma unroll
            for (int r = 0; r < 4; ++r) {
                elh[hh][r] = fmaf(accf[ot][r], alv, elh[hh][r]);
                erh[hh][r] = fmaf(accf[ot][r], arv, erh[hh][r]);
            }
        }
    }
    #pragma unroll
    for (int hh = 0; hh < 4; ++hh)
        #pragma unroll
        for (int r = 0; r < 4; ++r) {
            float e = elh[hh][r], rr = erh[hh][r];
            #pragma unroll
            for (int off = 1; off < 16; off <<= 1) {
                e  += __shfl_xor(e,  off);
                rr += __shfl_xor(rr, off);
            }
            elh[hh][r] = e; erh[hh][r] = rr;
        }
    #pragma unroll
    for (int hh = 0; hh < 4; ++hh) {
        if (l15 == hh) {
            #pragma unroll
            for (int r = 0; r < 4; ++r)
                el_t[((size_t)b_idx * 4 + hh) * NN + nloc + l4 * 4 + r] = elh[hh][r] * LOG2E;
        }
        if (l15 == hh + 4) {
            #pragma unroll
            for (int r = 0; r < 4; ++r)
                er_t[((size_t)b_idx * 4 + hh) * NN + nloc + l4 * 4 + r] = erh[hh][r] * LOG2E;
        }
    }
    // ---- pass 2: res = x @ rW ----
    f32x4 accr[16];
    #pragma unroll
    for (int i = 0; i < 16; ++i) accr[i] = (f32x4){0.f, 0.f, 0.f, 0.f};
    #pragma unroll
    for (int ks = 0; ks < K / 32; ++ks) {
        short8 av = *(const short8*)(xrow + ks * 32);
        #pragma unroll
        for (int ot = 0; ot < 16; ++ot) {
            short8 bw = *(const short8*)(rWt + ((size_t)(ot * 16 + l15)) * K + ks * 32 + l4 * 8);
            accr[ot] = __builtin_amdgcn_mfma_f32_16x16x32_bf16(av, bw, accr[ot], 0, 0, 0);
        }
    }
    #pragma unroll
    for (int ot = 0; ot < 16; ++ot)
        #pragma unroll
        for (int r = 0; r < 4; ++r)
            fea[((size_t)n0 + l4 * 4 + r) * 256 + ot * 16 + l15] = f2bf(accr[ot][r]);
}

// ---------------- K3: unmasked max over src nodes of el (per (b,h)) ----------------
__global__ __launch_bounds__(256) void k_elmax(
    const float* __restrict__ el_t, float* __restrict__ elmax)
{
    const int bh = blockIdx.x;
    const int t = threadIdx.x;
    float m = -1e30f;
    for (int n = t; n < NN; n += 256)
        m = fmaxf(m, el_t[(size_t)bh * NN + n]);
    #pragma unroll
    for (int off = 32; off; off >>= 1) m = fmaxf(m, __shfl_xor(m, off));
    __shared__ float sm[4];
    if ((t & 63) == 0) sm[t >> 6] = m;
    __syncthreads();
    if (t == 0) elmax[bh] = fmaxf(fmaxf(sm[0], sm[1]), fmaxf(sm[2], sm[3]));
}

// ---------------- K4: masked softmax + MFMA PV + residual + bias (+ELU) --------------
// 4 waves x 32 v (v-tile 128); f-tile double-buffered in LDS, 2-phase pipeline:
// issue global loads for tile t+1 -> compute tile t -> ds_write t+1 -> barrier.
template<int ELU_ON>
__global__ __launch_bounds__(256, 4) void k_attn(
    const short* __restrict__ ft,     // tiled [bh][ut16][g8][d64][ui8]
    const float* __restrict__ el_t,   // [(b*4+h)][NN] scaled
    const float* __restrict__ er_t,   // [(b*4+h)][NN] scaled
    const float* __restrict__ elmax,  // [(b*4+h)]
    const uint64_t* __restrict__ maskT,// [b*N + v][16] u-words
    const float* __restrict__ bias,   // [256]
    short* fea)                       // [B*N][256] bf16: res in, out in-place
{
    // XCD swizzle: 512 blocks, 64 per XCD -> 2 full b's per XCD
    const int id = blockIdx.x;
    const int swz = (id & 7) * 64 + (id >> 3);
    const int b  = swz >> 5;
    const int h  = (swz >> 3) & 3;
    const int vt = swz & 7;
    const int tid = threadIdx.x;
    const int lane = tid & 63, wid = tid >> 6;
    const int l15 = lane & 15, l4 = lane >> 4;
    const int bh = b * 4 + h;
    const size_t bN = (size_t)b * NN;
    const int v0 = vt * 128;

    __shared__ __align__(16) short f_lds[2][4096];      // [buf][g*512 + d*8 + ui]
    __shared__ __align__(16) float el_lds[NN];
    __shared__ __align__(16) uint64_t m_lds[128 * 17];  // 136B row stride

    const short* gsrc = ft + ((size_t)bh << 16);

    // ---- prologue staging: tile 0, el strip, mask rows ----
    {
        short8 sa = *(const short8*)(gsrc + tid * 8);
        short8 sb = *(const short8*)(gsrc + 2048 + tid * 8);
        ((float4*)el_lds)[tid] = ((const float4*)(el_t + (size_t)bh * NN))[tid];
        #pragma unroll
        for (int i = 0; i < 8; ++i) {
            int idx = tid + i * 256;           // 2048 uint64 words
            m_lds[(idx >> 4) * 17 + (idx & 15)] =
                maskT[(bN + v0 + (idx >> 4)) * 16 + (idx & 15)];
        }
        *(short8*)&f_lds[0][tid * 8] = sa;
        *(short8*)&f_lds[0][2048 + tid * 8] = sb;
    }

    const int vlo = wid * 32 + l15, vhi = vlo + 16;
    const float er_lo = er_t[(size_t)bh * NN + v0 + vlo];
    const float er_hi = er_t[(size_t)bh * NN + v0 + vhi];
    const float emx = elmax[bh];
    const float e0 = emx + er_lo;
    const float cv_lo = fmaxf(e0, 0.2f * e0);    // lrelu monotone -> valid shift
    const float e1 = emx + er_hi;
    const float cv_hi = fmaxf(e1, 0.2f * e1);
    const float c1_lo = er_lo - cv_lo, c2_lo = 0.2f * er_lo - cv_lo;
    const float c1_hi = er_hi - cv_hi, c2_hi = 0.2f * er_hi - cv_hi;

    const uint8_t* mbytes = (const uint8_t*)m_lds;
    const int moff_lo = vlo * 136, moff_hi = vhi * 136;

    short8 ones8;
    #pragma unroll
    for (int i = 0; i < 8; ++i) ones8[i] = (short)0x3F80;   // bf16 1.0

    f32x4 accLo[4], accHi[4];
    #pragma unroll
    for (int i = 0; i < 4; ++i) {
        accLo[i] = (f32x4){0.f, 0.f, 0.f, 0.f};
        accHi[i] = (f32x4){0.f, 0.f, 0.f, 0.f};
    }
    f32x4 dLo = (f32x4){0.f, 0.f, 0.f, 0.f};
    f32x4 dHi = (f32x4){0.f, 0.f, 0.f, 0.f};

    __syncthreads();

    short8 Ra, Rb;
    #pragma unroll 1
    for (int tt = 0; tt < 16; ++tt) {
        if (tt < 15) {                      // issue next-tile loads early (T14 split)
            Ra = *(const short8*)(gsrc + (tt + 1) * 4096 + tid * 8);
            Rb = *(const short8*)(gsrc + (tt + 1) * 4096 + 2048 + tid * 8);
            __builtin_amdgcn_sched_barrier(0);
        }
        const short* fb = f_lds[tt & 1];
        #pragma unroll
        for (int kc = 0; kc < 2; ++kc) {
            const float* ep = &el_lds[tt * 64 + kc * 32 + l4 * 8];
            float4 ev0 = *(const float4*)ep;
            float4 ev1 = *(const float4*)(ep + 4);
            const float ev[8] = {ev0.x, ev0.y, ev0.z, ev0.w, ev1.x, ev1.y, ev1.z, ev1.w};
            uint32_t mLo = mbytes[moff_lo + tt * 8 + kc * 4 + l4];
            uint32_t mHi = mbytes[moff_hi + tt * 8 + kc * 4 + l4];
            short8 aLo, aHi;
            #pragma unroll
            for (int j = 0; j < 8; ++j) {
                float e = ev[j];
                float argL = fmaxf(e + c1_lo, fmaf(0.2f, e, c2_lo));
                float argH = fmaxf(e + c1_hi, fmaf(0.2f, e, c2_hi));
                float pL = ((mLo >> j) & 1u) ? fast_exp2(argL) : 0.f;
                float pH = ((mHi >> j) & 1u) ? fast_exp2(argH) : 0.f;
                aLo[j] = f2bf(pL);
                aHi[j] = f2bf(pH);
            }
            const int fo = (kc * 4 + l4) * 512 + l15 * 8;
            short8 bw0 = *(const short8*)(fb + fo);
            short8 bw1 = *(const short8*)(fb + fo + 128);
            short8 bw2 = *(const short8*)(fb + fo + 256);
            short8 bw3 = *(const short8*)(fb + fo + 384);
            __builtin_amdgcn_s_setprio(1);
            accLo[0] = __builtin_amdgcn_mfma_f32_16x16x32_bf16(aLo, bw0, accLo[0], 0, 0, 0);
            accLo[1] = __builtin_amdgcn_mfma_f32_16x16x32_bf16(aLo, bw1, accLo[1], 0, 0, 0);
            accLo[2] = __builtin_amdgcn_mfma_f32_16x16x32_bf16(aLo, bw2, accLo[2], 0, 0, 0);
            accLo[3] = __builtin_amdgcn_mfma_f32_16x16x32_bf16(aLo, bw3, accLo[3], 0, 0, 0);
            dLo      = __builtin_amdgcn_mfma_f32_16x16x32_bf16(aLo, ones8, dLo, 0, 0, 0);
            accHi[0] = __builtin_amdgcn_mfma_f32_16x16x32_bf16(aHi, bw0, accHi[0], 0, 0, 0);
            accHi[1] = __builtin_amdgcn_mfma_f32_16x16x32_bf16(aHi, bw1, accHi[1], 0, 0, 0);
            accHi[2] = __builtin_amdgcn_mfma_f32_16x16x32_bf16(aHi, bw2, accHi[2], 0, 0, 0);
            accHi[3] = __builtin_amdgcn_mfma_f32_16x16x32_bf16(aHi, bw3, accHi[3], 0, 0, 0);
            dHi      = __builtin_amdgcn_mfma_f32_16x16x32_bf16(aHi, ones8, dHi, 0, 0, 0);
            __builtin_amdgcn_s_setprio(0);
        }
        if (tt < 15) {                      // land prefetch into the other buffer
            *(short8*)&f_lds[(tt + 1) & 1][tid * 8] = Ra;
            *(short8*)&f_lds[(tt + 1) & 1][2048 + tid * 8] = Rb;
        }
        __syncthreads();
    }

    // ---- epilogue: normalize, +res, +bias, (ELU), store bf16 in place ----
    float rcpLo[4], rcpHi[4];
    #pragma unroll
    for (int r = 0; r < 4; ++r) {
        rcpLo[r] = 1.f / fmaxf(dLo[r], 1e-9f);     // jnp.clip(sum, 1e-9)
        rcpHi[r] = 1.f / fmaxf(dHi[r], 1e-9f);
    }
    #pragma unroll
    for (int dt = 0; dt < 4; ++dt) {
        const int d = dt * 16 + l15;
        const float bv = bias[h * 64 + d];
        #pragma unroll
        for (int r = 0; r < 4; ++r) {
            const int vl = v0 + wid * 32 + l4 * 4 + r;
            const size_t rowL = (bN + vl) * 256 + h * 64 + d;
            float ov = accLo[dt][r] * rcpLo[r] + bf2f(fea[rowL]) + bv;
            if (ELU_ON) ov = ov > 0.f ? ov : __expf(ov) - 1.f;
            fea[rowL] = f2bf(ov);
            const size_t rowH = (bN + vl + 16) * 256 + h * 64 + d;
            float ov2 = accHi[dt][r] * rcpHi[r] + bf2f(fea[rowH]) + bv;
            if (ELU_ON) ov2 = ov2 > 0.f ? ov2 : __expf(ov2) - 1.f;
            fea[rowH] = f2bf(ov2);
        }
    }
}

// ---------------- K5: mean over heads (bf16 in) -> d_out fp32 ----------------
__global__ __launch_bounds__(256) void k_headmean(
    const short* __restrict__ fea, float* __restrict__ outp)
{
    int i = blockIdx.x * 256 + threadIdx.x;     // i over B*N*64
    int d = i & 63;
    size_t node = (size_t)(i >> 6);
    const short* p = fea + node * 256;
    outp[i] = 0.25f * (bf2f(p[d]) + bf2f(p[64 + d]) + bf2f(p[128 + d]) + bf2f(p[192 + d]));
}

extern "C" void kernel_launch(void* const* d_in, const int* in_sizes, int n_in,
                              void* d_out, int out_size, void* d_ws, size_t ws_size,
                              hipStream_t stream) {
    const float* seg = (const float*)d_in[0];
    const float* adj = (const float*)d_in[1];
    const float* W0  = (const float*)d_in[2];
    const float* al0 = (const float*)d_in[3];
    const float* ar0 = (const float*)d_in[4];
    const float* rW0 = (const float*)d_in[5];
    const float* b0  = (const float*)d_in[6];
    const float* W1  = (const float*)d_in[7];
    const float* al1 = (const float*)d_in[8];
    const float* ar1 = (const float*)d_in[9];
    const float* rW1 = (const float*)d_in[10];
    const float* b1  = (const float*)d_in[11];
    float* out = (float*)d_out;

    char* ws = (char*)d_ws;
    size_t off = 0;
    uint64_t* mask  = (uint64_t*)ws;                 // 2 MB (dead after k_maskT)
    off += (size_t)BB * NN * 16 * 8;
    uint64_t* maskT = (uint64_t*)(ws + off); off += (size_t)BB * NN * 16 * 8;  // 2 MB
    short* ftb = (short*)(ws + off); off += (size_t)BB * 256 * NN * 2;         // 8 MB
    short* fea = (short*)(ws + off); off += (size_t)BB * NN * 256 * 2;         // 8 MB
    short* xb0 = (short*)(ws + off); off += (size_t)BB * NN * 64 * 2;          // 2 MB
    // small buffers reuse the dead `mask` region (valid after k_maskT completes)
    char* r0 = (char*)mask;
    short* Wt0  = (short*)r0;                 r0 += 256 * 64 * 2;
    short* rWt0 = (short*)r0;                 r0 += 256 * 64 * 2;
    short* Wt1  = (short*)r0;                 r0 += 256 * 256 * 2;
    short* rWt1 = (short*)r0;                 r0 += 256 * 256 * 2;
    float* el   = (float*)r0;                 r0 += (size_t)BB * 4 * NN * 4;
    float* er   = (float*)r0;                 r0 += (size_t)BB * 4 * NN * 4;
    float* emx  = (float*)r0;                 r0 += BB * 4 * 4;

    k_topk_mask<<<BB * NN, 256, 0, stream>>>(adj, mask);
    k_maskT<<<BB * 256 / 4, 256, 0, stream>>>(mask, maskT);
    // mask region now dead -> safe to fill Wt/el/er
    k_prep<<<64, 256, 0, stream>>>(W0, Wt0, 64);
    k_prep<<<64, 256, 0, stream>>>(rW0, rWt0, 64);
    k_prep<<<256, 256, 0, stream>>>(W1, Wt1, 256);
    k_prep<<<256, 256, 0, stream>>>(rW1, rWt1, 256);
    k_cvt<<<BB * NN * 64 / 1024, 256, 0, stream>>>(seg, xb0);

    // layer 0 (K=64)
    k_features_mfma<64><<<BB * NN / 64, 256, 0, stream>>>(xb0, Wt0, rWt0, al0, ar0,
                                                          ftb, fea, el, er);
    k_elmax<<<BB * 4, 256, 0, stream>>>(el, emx);
    k_attn<1><<<512, 256, 0, stream>>>(ftb, el, er, emx, maskT, b0, fea);
    // layer 1 (K=256)
    k_features_mfma<256><<<BB * NN / 64, 256, 0, stream>>>(fea, Wt1, rWt1, al1, ar1,
                                                           ftb, fea, el, er);
    k_elmax<<<BB * 4, 256, 0, stream>>>(el, emx);
    k_attn<0><<<512, 256, 0, stream>>>(ftb, el, er, emx, maskT, b1, fea);

    k_headmean<<<BB * NN * 64 / 256, 256, 0, stream>>>(fea, out);
}

// Round 7
// 199.481 us; speedup vs baseline: 2.6195x; 1.1303x over previous
//
#include <hip/hip_runtime.h>
#include <hip/hip_bf16.h>
#include <stdint.h>

#define BB   16
#define NN   1024
#define KSEL 170   // (32*32)/6
#define LOG2E 1.4426950408889634f

typedef __attribute__((ext_vector_type(8))) short short8;
typedef __attribute__((ext_vector_type(4))) short short4v;
typedef __attribute__((ext_vector_type(4))) float f32x4;

static __device__ __forceinline__ short f2bf(float x) {
    __hip_bfloat16 h = __float2bfloat16(x);
    return *reinterpret_cast<short*>(&h);
}
static __device__ __forceinline__ float bf2f(short x) {
    uint32_t u = ((uint32_t)(uint16_t)x) << 16;
    return __uint_as_float(u);
}
static __device__ __forceinline__ float fast_exp2(float x) {
    float r; asm("v_exp_f32 %0, %1" : "=v"(r) : "v"(x)); return r;
}

// ---------------- K1: exact k-th-largest per row — ONE ROW PER WAVE ------------------
// Wave-synchronous radix select: keys in registers, per-wave 256-bin LDS histogram,
// suffix-scan in-register + shfl. Zero __syncthreads.
__global__ __launch_bounds__(256) void k_topk_mask(
    const float* __restrict__ adj, uint64_t* __restrict__ mask)
{
    const int wid = threadIdx.x >> 6, lane = threadIdx.x & 63;
    const int row = blockIdx.x * 4 + wid;              // b*N + u
    const float* a = adj + (size_t)row * NN;
    __shared__ uint32_t hist[4][256];
    uint32_t* h = hist[wid];

    uint32_t key[16];
    #pragma unroll
    for (int j = 0; j < 16; ++j) {
        uint32_t u = __float_as_uint(a[lane + j * 64]);
        key[j] = u ^ ((u >> 31) ? 0xFFFFFFFFu : 0x80000000u);   // order-preserving map
    }

    uint32_t prefix = 0u, kk = KSEL;
    #pragma unroll
    for (int pass = 0; pass < 4; ++pass) {
        const int shift = 24 - 8 * pass;
        const uint32_t hi_mask = pass ? (0xFFFFFFFFu << (shift + 8)) : 0u;
        *(uint4*)&h[lane * 4] = make_uint4(0u, 0u, 0u, 0u);
        __builtin_amdgcn_wave_barrier();
        #pragma unroll
        for (int j = 0; j < 16; ++j)
            if ((key[j] & hi_mask) == prefix)
                atomicAdd(&h[(key[j] >> shift) & 255], 1u);
        __builtin_amdgcn_wave_barrier();
        const uint4 c4 = *(const uint4*)&h[lane * 4];  // bins 4L..4L+3
        const uint32_t T = c4.x + c4.y + c4.z + c4.w;
        uint32_t s = T;
        #pragma unroll
        for (int off = 1; off < 64; off <<= 1) {       // inclusive suffix sum over lanes
            uint32_t v = __shfl_down(s, off);
            s += (lane + off < 64) ? v : 0u;
        }
        const uint32_t E = s - T;                      // sum over lanes above
        const uint32_t s3 = c4.w;
        const uint32_t s2 = c4.z + s3;
        const uint32_t s1 = c4.y + s2;
        const uint32_t s0 = c4.x + s1;
        const uint32_t ci[4] = {c4.x, c4.y, c4.z, c4.w};
        const uint32_t si[4] = {s0, s1, s2, s3};
        uint32_t found = 0u, nb = 0u, nk = 0u;
        #pragma unroll
        for (int i = 0; i < 4; ++i) {
            uint32_t incl = E + si[i];                 // count of keys in bins >= this
            uint32_t excl = incl - ci[i];
            if (excl < kk && kk <= incl) { found = 1u; nb = (uint32_t)(lane * 4 + i); nk = kk - excl; }
        }
        uint64_t bal = __ballot(found != 0u);
        int wl = __ffsll((unsigned long long)bal) - 1; // exactly one winner
        prefix = prefix | ((uint32_t)__shfl((int)nb, wl) << shift);
        kk = (uint32_t)__shfl((int)nk, wl);
    }

    const uint32_t thr_key = prefix;                   // key of k-th largest (exact)
    #pragma unroll
    for (int j = 0; j < 16; ++j) {
        bool pred = (key[j] >= thr_key) && (key[j] > 0x80000000u);   // adj>=thr && adj>0
        uint64_t bal = __ballot(pred);
        if (lane == 0) mask[(size_t)row * 16 + j] = bal;
    }
}

// ---------------- K1b: 64x64 bit-transpose of the mask (ballot-based) ----------------
__global__ __launch_bounds__(256) void k_maskT(
    const uint64_t* __restrict__ mask, uint64_t* __restrict__ maskT)
{
    const int tile = blockIdx.x * 4 + (threadIdx.x >> 6);  // b*256 + uw*16 + vw
    const int lane = threadIdx.x & 63;
    const int b  = tile >> 8;
    const int uw = (tile >> 4) & 15;
    const int vw = tile & 15;
    const size_t bN = (size_t)b * NN;
    uint64_t w = mask[(bN + uw * 64 + lane) * 16 + vw];
    uint64_t r_out = 0;
    #pragma unroll
    for (int j = 0; j < 64; ++j) {
        uint64_t r = __ballot((w >> j) & 1ull);
        if (lane == j) r_out = r;
    }
    maskT[(bN + vw * 64 + lane) * 16 + uw] = r_out;
}

// ---------------- K1c: merged prep: weight transposes (fp32->bf16) + seg convert -----
__global__ __launch_bounds__(256) void k_prepare(
    const float* __restrict__ W0, const float* __restrict__ rW0,
    const float* __restrict__ W1, const float* __restrict__ rW1,
    const float* __restrict__ seg,
    short* __restrict__ Wt0, short* __restrict__ rWt0,
    short* __restrict__ Wt1, short* __restrict__ rWt1,
    short* __restrict__ xb0)
{
    const int bid = blockIdx.x, t = threadIdx.x;
    if (bid < 64) {                      // Wt0 [256][64]
        int idx = bid * 256 + t;
        int o = idx >> 6, k = idx & 63;
        Wt0[idx] = f2bf(W0[(size_t)k * 256 + o]);
    } else if (bid < 128) {              // rWt0 [256][64]
        int idx = (bid - 64) * 256 + t;
        int o = idx >> 6, k = idx & 63;
        rWt0[idx] = f2bf(rW0[(size_t)k * 256 + o]);
    } else if (bid < 384) {              // Wt1 [256][256]
        int idx = (bid - 128) * 256 + t;
        int o = idx >> 8, k = idx & 255;
        Wt1[idx] = f2bf(W1[(size_t)k * 256 + o]);
    } else if (bid < 640) {              // rWt1 [256][256]
        int idx = (bid - 384) * 256 + t;
        int o = idx >> 8, k = idx & 255;
        rWt1[idx] = f2bf(rW1[(size_t)k * 256 + o]);
    } else {                             // seg fp32 -> bf16 (1M elems, 4/thread)
        int i = ((bid - 640) * 256 + t) * 4;
        float4 v = *(const float4*)(seg + i);
        short4v o4;
        o4[0] = f2bf(v.x); o4[1] = f2bf(v.y); o4[2] = f2bf(v.z); o4[3] = f2bf(v.w);
        *(short4v*)(xb0 + i) = o4;
    }
}

// ---------------- K2: MFMA features: tiled f^T bf16, res bf16, el/er -----------------
// Per wave: 16 nodes x all 256 outputs. ft layout: [bh][ut16][g8][d64][ui8] (LDS image).
template<int K>
__global__ __launch_bounds__(256) void k_features_mfma(
    const short* __restrict__ xb,   // [B*N][K] bf16 row-major
    const short* __restrict__ Wt,   // [256][K] bf16
    const short* __restrict__ rWt,  // [256][K] bf16
    const float* __restrict__ al,   // [256]
    const float* __restrict__ ar,   // [256]
    short* __restrict__ ft,         // tiled transposed features (see above)
    short* __restrict__ fea,        // [B*N][256] bf16: res written here
    float* __restrict__ el_t,       // [(b*4+h)][NN] scaled by LOG2E
    float* __restrict__ er_t)       // [(b*4+h)][NN] scaled by LOG2E
{
    const int t = threadIdx.x, lane = t & 63, g = t >> 6;
    const int l15 = lane & 15, l4 = lane >> 4;
    const int n0 = blockIdx.x * 64 + g * 16;     // wave's 16-node strip
    const int b_idx = n0 >> 10;                  // NN = 1024
    const int nloc = n0 & (NN - 1);
    const short* xrow = xb + ((size_t)n0 + l15) * K + l4 * 8;

    // ---- pass 1: f = x @ W ----
    f32x4 accf[16];
    #pragma unroll
    for (int i = 0; i < 16; ++i) accf[i] = (f32x4){0.f, 0.f, 0.f, 0.f};
    #pragma unroll
    for (int ks = 0; ks < K / 32; ++ks) {
        short8 av = *(const short8*)(xrow + ks * 32);
        #pragma unroll
        for (int ot = 0; ot < 16; ++ot) {
            short8 bw = *(const short8*)(Wt + ((size_t)(ot * 16 + l15)) * K + ks * 32 + l4 * 8);
            accf[ot] = __builtin_amdgcn_mfma_f32_16x16x32_bf16(av, bw, accf[ot], 0, 0, 0);
        }
    }
    // store f^T tiled: u = nloc + (g*16 + l4*4 + r); lane col o = ot*16+l15
    #pragma unroll
    for (int ot = 0; ot < 16; ++ot) {
        short4v pk;
        #pragma unroll
        for (int r = 0; r < 4; ++r) pk[r] = f2bf(accf[ot][r]);
        const int hh = ot >> 2;
        const int dl = (ot & 3) * 16 + l15;
        const size_t idx = ((size_t)(b_idx * 4 + hh) << 16)
                         + (size_t)(nloc >> 6) * 4096
                         + (size_t)(g * 2 + (l4 >> 1)) * 512
                         + (size_t)dl * 8 + (l4 & 1) * 4;
        *(short4v*)(ft + idx) = pk;
    }
    // el/er dots over o within each head (16 l15-lanes cover the 64 o's of a head)
    float elh[4][4], erh[4][4];
    #pragma unroll
    for (int hh = 0; hh < 4; ++hh)
        #pragma unroll
        for (int r = 0; r < 4; ++r) { elh[hh][r] = 0.f; erh[hh][r] = 0.f; }
    #pragma unroll
    for (int hh = 0; hh < 4; ++hh) {
        #pragma unroll
        for (int q = 0; q < 4; ++q) {
            const int ot = hh * 4 + q;
            const float alv = al[ot * 16 + l15];
            const float arv = ar[ot * 16 + l15];
            #pragma unroll
            for (int r = 0; r < 4; ++r) {
                elh[hh][r] = fmaf(accf[ot][r], alv, elh[hh][r]);
                erh[hh][r] = fmaf(accf[ot][r], arv, erh[hh][r]);
            }
        }
    }
    #pragma unroll
    for (int hh = 0; hh < 4; ++hh)
        #pragma unroll
        for (int r = 0; r < 4; ++r) {
            float e = elh[hh][r], rr = erh[hh][r];
            #pragma unroll
            for (int off = 1; off < 16; off <<= 1) {
                e  += __shfl_xor(e,  off);
                rr += __shfl_xor(rr, off);
            }
            elh[hh][r] = e; erh[hh][r] = rr;
        }
    #pragma unroll
    for (int hh = 0; hh < 4; ++hh) {
        if (l15 == hh) {
            #pragma unroll
            for (int r = 0; r < 4; ++r)
                el_t[((size_t)b_idx * 4 + hh) * NN + nloc + l4 * 4 + r] = elh[hh][r] * LOG2E;
        }
        if (l15 == hh + 4) {
            #pragma unroll
            for (int r = 0; r < 4; ++r)
                er_t[((size_t)b_idx * 4 + hh) * NN + nloc + l4 * 4 + r] = erh[hh][r] * LOG2E;
        }
    }
    // ---- pass 2: res = x @ rW ----
    f32x4 accr[16];
    #pragma unroll
    for (int i = 0; i < 16; ++i) accr[i] = (f32x4){0.f, 0.f, 0.f, 0.f};
    #pragma unroll
    for (int ks = 0; ks < K / 32; ++ks) {
        short8 av = *(const short8*)(xrow + ks * 32);
        #pragma unroll
        for (int ot = 0; ot < 16; ++ot) {
            short8 bw = *(const short8*)(rWt + ((size_t)(ot * 16 + l15)) * K + ks * 32 + l4 * 8);
            accr[ot] = __builtin_amdgcn_mfma_f32_16x16x32_bf16(av, bw, accr[ot], 0, 0, 0);
        }
    }
    #pragma unroll
    for (int ot = 0; ot < 16; ++ot)
        #pragma unroll
        for (int r = 0; r < 4; ++r)
            fea[((size_t)n0 + l4 * 4 + r) * 256 + ot * 16 + l15] = f2bf(accr[ot][r]);
}

// ---------------- K3: unmasked max over src nodes of el (per (b,h)) ----------------
__global__ __launch_bounds__(256) void k_elmax(
    const float* __restrict__ el_t, float* __restrict__ elmax)
{
    const int bh = blockIdx.x;
    const int t = threadIdx.x;
    float m = -1e30f;
    for (int n = t; n < NN; n += 256)
        m = fmaxf(m, el_t[(size_t)bh * NN + n]);
    #pragma unroll
    for (int off = 32; off; off >>= 1) m = fmaxf(m, __shfl_xor(m, off));
    __shared__ float sm[4];
    if ((t & 63) == 0) sm[t >> 6] = m;
    __syncthreads();
    if (t == 0) elmax[bh] = fmaxf(fmaxf(sm[0], sm[1]), fmaxf(sm[2], sm[3]));
}

// ---------------- K4: masked softmax + MFMA PV + residual + bias (+ELU) --------------
// 4 waves x 32 v (v-tile 128); f-tile double-buffered in LDS, 2-phase pipeline:
// issue global loads for tile t+1 -> compute tile t -> ds_write t+1 -> barrier.
template<int ELU_ON>
__global__ __launch_bounds__(256, 4) void k_attn(
    const short* __restrict__ ft,     // tiled [bh][ut16][g8][d64][ui8]
    const float* __restrict__ el_t,   // [(b*4+h)][NN] scaled
    const float* __restrict__ er_t,   // [(b*4+h)][NN] scaled
    const float* __restrict__ elmax,  // [(b*4+h)]
    const uint64_t* __restrict__ maskT,// [b*N + v][16] u-words
    const float* __restrict__ bias,   // [256]
    short* fea)                       // [B*N][256] bf16: res in, out in-place
{
    // XCD swizzle: 512 blocks, 64 per XCD -> 2 full b's per XCD
    const int id = blockIdx.x;
    const int swz = (id & 7) * 64 + (id >> 3);
    const int b  = swz >> 5;
    const int h  = (swz >> 3) & 3;
    const int vt = swz & 7;
    const int tid = threadIdx.x;
    const int lane = tid & 63, wid = tid >> 6;
    const int l15 = lane & 15, l4 = lane >> 4;
    const int bh = b * 4 + h;
    const size_t bN = (size_t)b * NN;
    const int v0 = vt * 128;

    __shared__ __align__(16) short f_lds[2][4096];      // [buf][g*512 + d*8 + ui]
    __shared__ __align__(16) float el_lds[NN];
    __shared__ __align__(16) uint64_t m_lds[128 * 17];  // 136B row stride

    const short* gsrc = ft + ((size_t)bh << 16);

    // ---- prologue staging: tile 0, el strip, mask rows ----
    {
        short8 sa = *(const short8*)(gsrc + tid * 8);
        short8 sb = *(const short8*)(gsrc + 2048 + tid * 8);
        ((float4*)el_lds)[tid] = ((const float4*)(el_t + (size_t)bh * NN))[tid];
        #pragma unroll
        for (int i = 0; i < 8; ++i) {
            int idx = tid + i * 256;           // 2048 uint64 words
            m_lds[(idx >> 4) * 17 + (idx & 15)] =
                maskT[(bN + v0 + (idx >> 4)) * 16 + (idx & 15)];
        }
        *(short8*)&f_lds[0][tid * 8] = sa;
        *(short8*)&f_lds[0][2048 + tid * 8] = sb;
    }

    const int vlo = wid * 32 + l15, vhi = vlo + 16;
    const float er_lo = er_t[(size_t)bh * NN + v0 + vlo];
    const float er_hi = er_t[(size_t)bh * NN + v0 + vhi];
    const float emx = elmax[bh];
    const float e0 = emx + er_lo;
    const float cv_lo = fmaxf(e0, 0.2f * e0);    // lrelu monotone -> valid shift
    const float e1 = emx + er_hi;
    const float cv_hi = fmaxf(e1, 0.2f * e1);
    const float c1_lo = er_lo - cv_lo, c2_lo = 0.2f * er_lo - cv_lo;
    const float c1_hi = er_hi - cv_hi, c2_hi = 0.2f * er_hi - cv_hi;

    const uint8_t* mbytes = (const uint8_t*)m_lds;
    const int moff_lo = vlo * 136, moff_hi = vhi * 136;

    short8 ones8;
    #pragma unroll
    for (int i = 0; i < 8; ++i) ones8[i] = (short)0x3F80;   // bf16 1.0

    f32x4 accLo[4], accHi[4];
    #pragma unroll
    for (int i = 0; i < 4; ++i) {
        accLo[i] = (f32x4){0.f, 0.f, 0.f, 0.f};
        accHi[i] = (f32x4){0.f, 0.f, 0.f, 0.f};
    }
    f32x4 dLo = (f32x4){0.f, 0.f, 0.f, 0.f};
    f32x4 dHi = (f32x4){0.f, 0.f, 0.f, 0.f};

    __syncthreads();

    short8 Ra, Rb;
    #pragma unroll 1
    for (int tt = 0; tt < 16; ++tt) {
        if (tt < 15) {                      // issue next-tile loads early (T14 split)
            Ra = *(const short8*)(gsrc + (tt + 1) * 4096 + tid * 8);
            Rb = *(const short8*)(gsrc + (tt + 1) * 4096 + 2048 + tid * 8);
            __builtin_amdgcn_sched_barrier(0);
        }
        const short* fb = f_lds[tt & 1];
        #pragma unroll
        for (int kc = 0; kc < 2; ++kc) {
            const float* ep = &el_lds[tt * 64 + kc * 32 + l4 * 8];
            float4 ev0 = *(const float4*)ep;
            float4 ev1 = *(const float4*)(ep + 4);
            const float ev[8] = {ev0.x, ev0.y, ev0.z, ev0.w, ev1.x, ev1.y, ev1.z, ev1.w};
            uint32_t mLo = mbytes[moff_lo + tt * 8 + kc * 4 + l4];
            uint32_t mHi = mbytes[moff_hi + tt * 8 + kc * 4 + l4];
            short8 aLo, aHi;
            #pragma unroll
            for (int j = 0; j < 8; ++j) {
                float e = ev[j];
                float argL = fmaxf(e + c1_lo, fmaf(0.2f, e, c2_lo));
                float argH = fmaxf(e + c1_hi, fmaf(0.2f, e, c2_hi));
                float pL = ((mLo >> j) & 1u) ? fast_exp2(argL) : 0.f;
                float pH = ((mHi >> j) & 1u) ? fast_exp2(argH) : 0.f;
                aLo[j] = f2bf(pL);
                aHi[j] = f2bf(pH);
            }
            const int fo = (kc * 4 + l4) * 512 + l15 * 8;
            short8 bw0 = *(const short8*)(fb + fo);
            short8 bw1 = *(const short8*)(fb + fo + 128);
            short8 bw2 = *(const short8*)(fb + fo + 256);
            short8 bw3 = *(const short8*)(fb + fo + 384);
            __builtin_amdgcn_s_setprio(1);
            accLo[0] = __builtin_amdgcn_mfma_f32_16x16x32_bf16(aLo, bw0, accLo[0], 0, 0, 0);
            accLo[1] = __builtin_amdgcn_mfma_f32_16x16x32_bf16(aLo, bw1, accLo[1], 0, 0, 0);
            accLo[2] = __builtin_amdgcn_mfma_f32_16x16x32_bf16(aLo, bw2, accLo[2], 0, 0, 0);
            accLo[3] = __builtin_amdgcn_mfma_f32_16x16x32_bf16(aLo, bw3, accLo[3], 0, 0, 0);
            dLo      = __builtin_amdgcn_mfma_f32_16x16x32_bf16(aLo, ones8, dLo, 0, 0, 0);
            accHi[0] = __builtin_amdgcn_mfma_f32_16x16x32_bf16(aHi, bw0, accHi[0], 0, 0, 0);
            accHi[1] = __builtin_amdgcn_mfma_f32_16x16x32_bf16(aHi, bw1, accHi[1], 0, 0, 0);
            accHi[2] = __builtin_amdgcn_mfma_f32_16x16x32_bf16(aHi, bw2, accHi[2], 0, 0, 0);
            accHi[3] = __builtin_amdgcn_mfma_f32_16x16x32_bf16(aHi, bw3, accHi[3], 0, 0, 0);
            dHi      = __builtin_amdgcn_mfma_f32_16x16x32_bf16(aHi, ones8, dHi, 0, 0, 0);
            __builtin_amdgcn_s_setprio(0);
        }
        if (tt < 15) {                      // land prefetch into the other buffer
            *(short8*)&f_lds[(tt + 1) & 1][tid * 8] = Ra;
            *(short8*)&f_lds[(tt + 1) & 1][2048 + tid * 8] = Rb;
        }
        __syncthreads();
    }

    // ---- epilogue: normalize, +res, +bias, (ELU), store bf16 in place ----
    float rcpLo[4], rcpHi[4];
    #pragma unroll
    for (int r = 0; r < 4; ++r) {
        rcpLo[r] = 1.f / fmaxf(dLo[r], 1e-9f);     // jnp.clip(sum, 1e-9)
        rcpHi[r] = 1.f / fmaxf(dHi[r], 1e-9f);
    }
    #pragma unroll
    for (int dt = 0; dt < 4; ++dt) {
        const int d = dt * 16 + l15;
        const float bv = bias[h * 64 + d];
        #pragma unroll
        for (int r = 0; r < 4; ++r) {
            const int vl = v0 + wid * 32 + l4 * 4 + r;
            const size_t rowL = (bN + vl) * 256 + h * 64 + d;
            float ov = accLo[dt][r] * rcpLo[r] + bf2f(fea[rowL]) + bv;
            if (ELU_ON) ov = ov > 0.f ? ov : __expf(ov) - 1.f;
            fea[rowL] = f2bf(ov);
            const size_t rowH = (bN + vl + 16) * 256 + h * 64 + d;
            float ov2 = accHi[dt][r] * rcpHi[r] + bf2f(fea[rowH]) + bv;
            if (ELU_ON) ov2 = ov2 > 0.f ? ov2 : __expf(ov2) - 1.f;
            fea[rowH] = f2bf(ov2);
        }
    }
}

// ---------------- K5: mean over heads (bf16 in) -> d_out fp32 ----------------
__global__ __launch_bounds__(256) void k_headmean(
    const short* __restrict__ fea, float* __restrict__ outp)
{
    int i = blockIdx.x * 256 + threadIdx.x;     // i over B*N*64
    int d = i & 63;
    size_t node = (size_t)(i >> 6);
    const short* p = fea + node * 256;
    outp[i] = 0.25f * (bf2f(p[d]) + bf2f(p[64 + d]) + bf2f(p[128 + d]) + bf2f(p[192 + d]));
}

extern "C" void kernel_launch(void* const* d_in, const int* in_sizes, int n_in,
                              void* d_out, int out_size, void* d_ws, size_t ws_size,
                              hipStream_t stream) {
    const float* seg = (const float*)d_in[0];
    const float* adj = (const float*)d_in[1];
    const float* W0  = (const float*)d_in[2];
    const float* al0 = (const float*)d_in[3];
    const float* ar0 = (const float*)d_in[4];
    const float* rW0 = (const float*)d_in[5];
    const float* b0  = (const float*)d_in[6];
    const float* W1  = (const float*)d_in[7];
    const float* al1 = (const float*)d_in[8];
    const float* ar1 = (const float*)d_in[9];
    const float* rW1 = (const float*)d_in[10];
    const float* b1  = (const float*)d_in[11];
    float* out = (float*)d_out;

    char* ws = (char*)d_ws;
    size_t off = 0;
    uint64_t* mask  = (uint64_t*)ws;                 // 2 MB (dead after k_maskT)
    off += (size_t)BB * NN * 16 * 8;
    uint64_t* maskT = (uint64_t*)(ws + off); off += (size_t)BB * NN * 16 * 8;  // 2 MB
    short* ftb = (short*)(ws + off); off += (size_t)BB * 256 * NN * 2;         // 8 MB
    short* fea = (short*)(ws + off); off += (size_t)BB * NN * 256 * 2;         // 8 MB
    short* xb0 = (short*)(ws + off); off += (size_t)BB * NN * 64 * 2;          // 2 MB
    // small buffers reuse the dead `mask` region (valid after k_maskT completes)
    char* r0 = (char*)mask;
    short* Wt0  = (short*)r0;                 r0 += 256 * 64 * 2;
    short* rWt0 = (short*)r0;                 r0 += 256 * 64 * 2;
    short* Wt1  = (short*)r0;                 r0 += 256 * 256 * 2;
    short* rWt1 = (short*)r0;                 r0 += 256 * 256 * 2;
    float* el   = (float*)r0;                 r0 += (size_t)BB * 4 * NN * 4;
    float* er   = (float*)r0;                 r0 += (size_t)BB * 4 * NN * 4;
    float* emx  = (float*)r0;                 r0 += BB * 4 * 4;

    k_topk_mask<<<BB * NN / 4, 256, 0, stream>>>(adj, mask);
    k_maskT<<<BB * 256 / 4, 256, 0, stream>>>(mask, maskT);
    // mask region now dead -> safe to fill Wt/el/er
    k_prepare<<<640 + BB * NN * 64 / 1024, 256, 0, stream>>>(
        W0, rW0, W1, rW1, seg, Wt0, rWt0, Wt1, rWt1, xb0);

    // layer 0 (K=64)
    k_features_mfma<64><<<BB * NN / 64, 256, 0, stream>>>(xb0, Wt0, rWt0, al0, ar0,
                                                          ftb, fea, el, er);
    k_elmax<<<BB * 4, 256, 0, stream>>>(el, emx);
    k_attn<1><<<512, 256, 0, stream>>>(ftb, el, er, emx, maskT, b0, fea);
    // layer 1 (K=256)
    k_features_mfma<256><<<BB * NN / 64, 256, 0, stream>>>(fea, Wt1, rWt1, al1, ar1,
                                                           ftb, fea, el, er);
    k_elmax<<<BB * 4, 256, 0, stream>>>(el, emx);
    k_attn<0><<<512, 256, 0, stream>>>(ftb, el, er, emx, maskT, b1, fea);

    k_headmean<<<BB * NN * 64 / 256, 256, 0, stream>>>(fea, out);
}

// Round 8
// 175.741 us; speedup vs baseline: 2.9734x; 1.1351x over previous
//
#include <hip/hip_runtime.h>
#include <hip/hip_bf16.h>
#include <stdint.h>

#define BB   16
#define NN   1024
#define KSEL 170   // (32*32)/6
#define LOG2E 1.4426950408889634f

typedef __attribute__((ext_vector_type(8))) short short8;
typedef __attribute__((ext_vector_type(4))) short short4v;
typedef __attribute__((ext_vector_type(4))) float f32x4;

static __device__ __forceinline__ short f2bf(float x) {
    __hip_bfloat16 h = __float2bfloat16(x);
    return *reinterpret_cast<short*>(&h);
}
static __device__ __forceinline__ float bf2f(short x) {
    uint32_t u = ((uint32_t)(uint16_t)x) << 16;
    return __uint_as_float(u);
}
static __device__ __forceinline__ float fast_exp2(float x) {
    float r; asm("v_exp_f32 %0, %1" : "=v"(r) : "v"(x)); return r;
}

// ---------------- K1: exact k-th-largest per row — ONE ROW PER WAVE ------------------
__global__ __launch_bounds__(256) void k_topk_mask(
    const float* __restrict__ adj, uint64_t* __restrict__ mask)
{
    const int wid = threadIdx.x >> 6, lane = threadIdx.x & 63;
    const int row = blockIdx.x * 4 + wid;              // b*N + u
    const float* a = adj + (size_t)row * NN;
    __shared__ uint32_t hist[4][256];
    uint32_t* h = hist[wid];

    uint32_t key[16];
    #pragma unroll
    for (int j = 0; j < 16; ++j) {
        uint32_t u = __float_as_uint(a[lane + j * 64]);
        key[j] = u ^ ((u >> 31) ? 0xFFFFFFFFu : 0x80000000u);   // order-preserving map
    }

    uint32_t prefix = 0u, kk = KSEL;
    #pragma unroll
    for (int pass = 0; pass < 4; ++pass) {
        const int shift = 24 - 8 * pass;
        const uint32_t hi_mask = pass ? (0xFFFFFFFFu << (shift + 8)) : 0u;
        *(uint4*)&h[lane * 4] = make_uint4(0u, 0u, 0u, 0u);
        __builtin_amdgcn_wave_barrier();
        #pragma unroll
        for (int j = 0; j < 16; ++j)
            if ((key[j] & hi_mask) == prefix)
                atomicAdd(&h[(key[j] >> shift) & 255], 1u);
        __builtin_amdgcn_wave_barrier();
        const uint4 c4 = *(const uint4*)&h[lane * 4];  // bins 4L..4L+3
        const uint32_t T = c4.x + c4.y + c4.z + c4.w;
        uint32_t s = T;
        #pragma unroll
        for (int off = 1; off < 64; off <<= 1) {       // inclusive suffix sum over lanes
            uint32_t v = __shfl_down(s, off);
            s += (lane + off < 64) ? v : 0u;
        }
        const uint32_t E = s - T;                      // sum over lanes above
        const uint32_t s3 = c4.w;
        const uint32_t s2 = c4.z + s3;
        const uint32_t s1 = c4.y + s2;
        const uint32_t s0 = c4.x + s1;
        const uint32_t ci[4] = {c4.x, c4.y, c4.z, c4.w};
        const uint32_t si[4] = {s0, s1, s2, s3};
        uint32_t found = 0u, nb = 0u, nk = 0u;
        #pragma unroll
        for (int i = 0; i < 4; ++i) {
            uint32_t incl = E + si[i];                 // count of keys in bins >= this
            uint32_t excl = incl - ci[i];
            if (excl < kk && kk <= incl) { found = 1u; nb = (uint32_t)(lane * 4 + i); nk = kk - excl; }
        }
        uint64_t bal = __ballot(found != 0u);
        int wl = __ffsll((unsigned long long)bal) - 1; // exactly one winner
        prefix = prefix | ((uint32_t)__shfl((int)nb, wl) << shift);
        kk = (uint32_t)__shfl((int)nk, wl);
    }

    const uint32_t thr_key = prefix;                   // key of k-th largest (exact)
    #pragma unroll
    for (int j = 0; j < 16; ++j) {
        bool pred = (key[j] >= thr_key) && (key[j] > 0x80000000u);   // adj>=thr && adj>0
        uint64_t bal = __ballot(pred);
        if (lane == 0) mask[(size_t)row * 16 + j] = bal;
    }
}

// ---------------- K1b: 64x64 bit-transpose of the mask (ballot-based) ----------------
__global__ __launch_bounds__(256) void k_maskT(
    const uint64_t* __restrict__ mask, uint64_t* __restrict__ maskT)
{
    const int tile = blockIdx.x * 4 + (threadIdx.x >> 6);  // b*256 + uw*16 + vw
    const int lane = threadIdx.x & 63;
    const int b  = tile >> 8;
    const int uw = (tile >> 4) & 15;
    const int vw = tile & 15;
    const size_t bN = (size_t)b * NN;
    uint64_t w = mask[(bN + uw * 64 + lane) * 16 + vw];
    uint64_t r_out = 0;
    #pragma unroll
    for (int j = 0; j < 64; ++j) {
        uint64_t r = __ballot((w >> j) & 1ull);
        if (lane == j) r_out = r;
    }
    maskT[(bN + vw * 64 + lane) * 16 + uw] = r_out;
}

// ---------------- K1c: merged prep: weight transposes (fp32->bf16) + seg convert -----
__global__ __launch_bounds__(256) void k_prepare(
    const float* __restrict__ W0, const float* __restrict__ rW0,
    const float* __restrict__ W1, const float* __restrict__ rW1,
    const float* __restrict__ seg,
    short* __restrict__ Wt0, short* __restrict__ rWt0,
    short* __restrict__ Wt1, short* __restrict__ rWt1,
    short* __restrict__ xb0)
{
    const int bid = blockIdx.x, t = threadIdx.x;
    if (bid < 64) {                      // Wt0 [256][64]
        int idx = bid * 256 + t;
        int o = idx >> 6, k = idx & 63;
        Wt0[idx] = f2bf(W0[(size_t)k * 256 + o]);
    } else if (bid < 128) {              // rWt0 [256][64]
        int idx = (bid - 64) * 256 + t;
        int o = idx >> 6, k = idx & 63;
        rWt0[idx] = f2bf(rW0[(size_t)k * 256 + o]);
    } else if (bid < 384) {              // Wt1 [256][256]
        int idx = (bid - 128) * 256 + t;
        int o = idx >> 8, k = idx & 255;
        Wt1[idx] = f2bf(W1[(size_t)k * 256 + o]);
    } else if (bid < 640) {              // rWt1 [256][256]
        int idx = (bid - 384) * 256 + t;
        int o = idx >> 8, k = idx & 255;
        rWt1[idx] = f2bf(rW1[(size_t)k * 256 + o]);
    } else {                             // seg fp32 -> bf16 (1M elems, 4/thread)
        int i = ((bid - 640) * 256 + t) * 4;
        float4 v = *(const float4*)(seg + i);
        short4v o4;
        o4[0] = f2bf(v.x); o4[1] = f2bf(v.y); o4[2] = f2bf(v.z); o4[3] = f2bf(v.w);
        *(short4v*)(xb0 + i) = o4;
    }
}

// ---------------- K2: MFMA features — 16 nodes/block, 1 head/wave --------------------
// Wave hh: 4 ot-blocks (head's 64 outputs). Fused W/rW passes share the x fragment.
// Pass-2 operands swapped -> D transposed -> vectorized fea stores.
template<int K>
__global__ __launch_bounds__(256, 4) void k_features_mfma(
    const short* __restrict__ xb,   // [B*N][K] bf16 row-major
    const short* __restrict__ Wt,   // [256][K] bf16
    const short* __restrict__ rWt,  // [256][K] bf16
    const float* __restrict__ al,   // [256]
    const float* __restrict__ ar,   // [256]
    short* __restrict__ ft,         // tiled transposed features [bh][ut16][g8][d64][ui8]
    short* __restrict__ fea,        // [B*N][256] bf16: res written here (may alias xb)
    float* __restrict__ el_t,       // [(b*4+h)][NN] scaled by LOG2E
    float* __restrict__ er_t)       // [(b*4+h)][NN] scaled by LOG2E
{
    const int t = threadIdx.x, lane = t & 63, hh = t >> 6;
    const int l15 = lane & 15, l4 = lane >> 4;
    const int n0 = blockIdx.x * 16;              // block's 16-node strip
    const int b_idx = n0 >> 10;                  // NN = 1024
    const int nloc = n0 & (NN - 1);
    const int bh = b_idx * 4 + hh;

    const short* xrow = xb  + ((size_t)n0 + l15) * K + l4 * 8;
    const short* wrow = Wt  + ((size_t)(hh * 64 + l15)) * K + l4 * 8;
    const short* rrow = rWt + ((size_t)(hh * 64 + l15)) * K + l4 * 8;

    f32x4 accf[4], accr[4];
    #pragma unroll
    for (int q = 0; q < 4; ++q) {
        accf[q] = (f32x4){0.f, 0.f, 0.f, 0.f};
        accr[q] = (f32x4){0.f, 0.f, 0.f, 0.f};
    }
    #pragma unroll
    for (int ks = 0; ks < K / 32; ++ks) {
        short8 xv = *(const short8*)(xrow + ks * 32);
        #pragma unroll
        for (int q = 0; q < 4; ++q) {
            short8 wv = *(const short8*)(wrow + (size_t)q * 16 * K + ks * 32);
            short8 rv = *(const short8*)(rrow + (size_t)q * 16 * K + ks * 32);
            accf[q] = __builtin_amdgcn_mfma_f32_16x16x32_bf16(xv, wv, accf[q], 0, 0, 0);
            accr[q] = __builtin_amdgcn_mfma_f32_16x16x32_bf16(rv, xv, accr[q], 0, 0, 0);
        }
    }

    // ---- ft store (pass1 D): accf[q][r] = f[n0 + l4*4 + r][hh*64 + q*16 + l15] ----
    #pragma unroll
    for (int q = 0; q < 4; ++q) {
        short4v pk;
        #pragma unroll
        for (int r = 0; r < 4; ++r) pk[r] = f2bf(accf[q][r]);
        const int dl = q * 16 + l15;             // head-local d
        const size_t idx = ((size_t)bh << 16)
                         + (size_t)(nloc >> 6) * 4096
                         + (size_t)(((nloc & 63) >> 3) + (l4 >> 1)) * 512
                         + (size_t)dl * 8 + (l4 & 1) * 4;
        *(short4v*)(ft + idx) = pk;
    }

    // ---- el/er head dots: reduce over d (16 l15-lanes x 4 q) ----
    float elv[4] = {0.f, 0.f, 0.f, 0.f}, erv[4] = {0.f, 0.f, 0.f, 0.f};
    #pragma unroll
    for (int q = 0; q < 4; ++q) {
        const float alv = al[hh * 64 + q * 16 + l15];
        const float arv = ar[hh * 64 + q * 16 + l15];
        #pragma unroll
        for (int r = 0; r < 4; ++r) {
            elv[r] = fmaf(accf[q][r], alv, elv[r]);
            erv[r] = fmaf(accf[q][r], arv, erv[r]);
        }
    }
    #pragma unroll
    for (int r = 0; r < 4; ++r) {
        #pragma unroll
        for (int off = 1; off < 16; off <<= 1) {
            elv[r] += __shfl_xor(elv[r], off);
            erv[r] += __shfl_xor(erv[r], off);
        }
    }
    if (l15 == 0) {                              // 4 lanes (l4=0..3), rows n0+l4*4+r
        float4 e4, r4;
        e4.x = elv[0] * LOG2E; e4.y = elv[1] * LOG2E;
        e4.z = elv[2] * LOG2E; e4.w = elv[3] * LOG2E;
        r4.x = erv[0] * LOG2E; r4.y = erv[1] * LOG2E;
        r4.z = erv[2] * LOG2E; r4.w = erv[3] * LOG2E;
        *(float4*)(el_t + (size_t)bh * NN + nloc + l4 * 4) = e4;
        *(float4*)(er_t + (size_t)bh * NN + nloc + l4 * 4) = r4;
    }

    // all x reads done before fea overwrite (layer 1 reads/writes same rows in-place)
    __syncthreads();

    // ---- fea store (pass2 D, swapped): accr[q][r] = res[hh*64+q*16+l4*4+r][n0+l15] --
    #pragma unroll
    for (int q = 0; q < 4; ++q) {
        short4v pk;
        #pragma unroll
        for (int r = 0; r < 4; ++r) pk[r] = f2bf(accr[q][r]);
        *(short4v*)(fea + ((size_t)n0 + l15) * 256 + hh * 64 + q * 16 + l4 * 4) = pk;
    }
}

// ---------------- K4: masked softmax + MFMA PV + residual + bias (+ELU) --------------
// 4 waves x 32 v (v-tile 128); f-tile double-buffered in LDS, 2-phase pipeline.
// elmax computed in-block from the staged el strip (k_elmax kernel eliminated).
template<int ELU_ON>
__global__ __launch_bounds__(256, 4) void k_attn(
    const short* __restrict__ ft,     // tiled [bh][ut16][g8][d64][ui8]
    const float* __restrict__ el_t,   // [(b*4+h)][NN] scaled
    const float* __restrict__ er_t,   // [(b*4+h)][NN] scaled
    const uint64_t* __restrict__ maskT,// [b*N + v][16] u-words
    const float* __restrict__ bias,   // [256]
    short* fea)                       // [B*N][256] bf16: res in, out in-place
{
    // XCD swizzle: 512 blocks, 64 per XCD -> 2 full b's per XCD
    const int id = blockIdx.x;
    const int swz = (id & 7) * 64 + (id >> 3);
    const int b  = swz >> 5;
    const int h  = (swz >> 3) & 3;
    const int vt = swz & 7;
    const int tid = threadIdx.x;
    const int lane = tid & 63, wid = tid >> 6;
    const int l15 = lane & 15, l4 = lane >> 4;
    const int bh = b * 4 + h;
    const size_t bN = (size_t)b * NN;
    const int v0 = vt * 128;

    __shared__ __align__(16) short f_lds[2][4096];      // [buf][g*512 + d*8 + ui]
    __shared__ __align__(16) float el_lds[NN];
    __shared__ __align__(16) uint64_t m_lds[128 * 17];  // 136B row stride
    __shared__ float smax[4];

    const short* gsrc = ft + ((size_t)bh << 16);

    // ---- prologue staging: tile 0, el strip (+ block-local max), mask rows ----
    {
        short8 sa = *(const short8*)(gsrc + tid * 8);
        short8 sb = *(const short8*)(gsrc + 2048 + tid * 8);
        float4 ev4 = ((const float4*)(el_t + (size_t)bh * NN))[tid];
        ((float4*)el_lds)[tid] = ev4;
        float m = fmaxf(fmaxf(ev4.x, ev4.y), fmaxf(ev4.z, ev4.w));
        #pragma unroll
        for (int off = 32; off; off >>= 1) m = fmaxf(m, __shfl_xor(m, off));
        if (lane == 0) smax[wid] = m;
        #pragma unroll
        for (int i = 0; i < 8; ++i) {
            int idx = tid + i * 256;           // 2048 uint64 words
            m_lds[(idx >> 4) * 17 + (idx & 15)] =
                maskT[(bN + v0 + (idx >> 4)) * 16 + (idx & 15)];
        }
        *(short8*)&f_lds[0][tid * 8] = sa;
        *(short8*)&f_lds[0][2048 + tid * 8] = sb;
    }

    const int vlo = wid * 32 + l15, vhi = vlo + 16;
    const float er_lo = er_t[(size_t)bh * NN + v0 + vlo];
    const float er_hi = er_t[(size_t)bh * NN + v0 + vhi];

    __syncthreads();

    const float emx = fmaxf(fmaxf(smax[0], smax[1]), fmaxf(smax[2], smax[3]));
    const float e0 = emx + er_lo;
    const float cv_lo = fmaxf(e0, 0.2f * e0);    // lrelu monotone -> valid shift
    const float e1 = emx + er_hi;
    const float cv_hi = fmaxf(e1, 0.2f * e1);
    const float c1_lo = er_lo - cv_lo, c2_lo = 0.2f * er_lo - cv_lo;
    const float c1_hi = er_hi - cv_hi, c2_hi = 0.2f * er_hi - cv_hi;

    const uint8_t* mbytes = (const uint8_t*)m_lds;
    const int moff_lo = vlo * 136, moff_hi = vhi * 136;

    short8 ones8;
    #pragma unroll
    for (int i = 0; i < 8; ++i) ones8[i] = (short)0x3F80;   // bf16 1.0

    f32x4 accLo[4], accHi[4];
    #pragma unroll
    for (int i = 0; i < 4; ++i) {
        accLo[i] = (f32x4){0.f, 0.f, 0.f, 0.f};
        accHi[i] = (f32x4){0.f, 0.f, 0.f, 0.f};
    }
    f32x4 dLo = (f32x4){0.f, 0.f, 0.f, 0.f};
    f32x4 dHi = (f32x4){0.f, 0.f, 0.f, 0.f};

    short8 Ra, Rb;
    #pragma unroll 1
    for (int tt = 0; tt < 16; ++tt) {
        if (tt < 15) {                      // issue next-tile loads early (T14 split)
            Ra = *(const short8*)(gsrc + (tt + 1) * 4096 + tid * 8);
            Rb = *(const short8*)(gsrc + (tt + 1) * 4096 + 2048 + tid * 8);
            __builtin_amdgcn_sched_barrier(0);
        }
        const short* fb = f_lds[tt & 1];
        #pragma unroll
        for (int kc = 0; kc < 2; ++kc) {
            const float* ep = &el_lds[tt * 64 + kc * 32 + l4 * 8];
            float4 ev0 = *(const float4*)ep;
            float4 ev1 = *(const float4*)(ep + 4);
            const float ev[8] = {ev0.x, ev0.y, ev0.z, ev0.w, ev1.x, ev1.y, ev1.z, ev1.w};
            uint32_t mLo = mbytes[moff_lo + tt * 8 + kc * 4 + l4];
            uint32_t mHi = mbytes[moff_hi + tt * 8 + kc * 4 + l4];
            short8 aLo, aHi;
            #pragma unroll
            for (int j = 0; j < 8; ++j) {
                float e = ev[j];
                float argL = fmaxf(e + c1_lo, fmaf(0.2f, e, c2_lo));
                float argH = fmaxf(e + c1_hi, fmaf(0.2f, e, c2_hi));
                float pL = ((mLo >> j) & 1u) ? fast_exp2(argL) : 0.f;
                float pH = ((mHi >> j) & 1u) ? fast_exp2(argH) : 0.f;
                aLo[j] = f2bf(pL);
                aHi[j] = f2bf(pH);
            }
            const int fo = (kc * 4 + l4) * 512 + l15 * 8;
            short8 bw0 = *(const short8*)(fb + fo);
            short8 bw1 = *(const short8*)(fb + fo + 128);
            short8 bw2 = *(const short8*)(fb + fo + 256);
            short8 bw3 = *(const short8*)(fb + fo + 384);
            __builtin_amdgcn_s_setprio(1);
            accLo[0] = __builtin_amdgcn_mfma_f32_16x16x32_bf16(aLo, bw0, accLo[0], 0, 0, 0);
            accLo[1] = __builtin_amdgcn_mfma_f32_16x16x32_bf16(aLo, bw1, accLo[1], 0, 0, 0);
            accLo[2] = __builtin_amdgcn_mfma_f32_16x16x32_bf16(aLo, bw2, accLo[2], 0, 0, 0);
            accLo[3] = __builtin_amdgcn_mfma_f32_16x16x32_bf16(aLo, bw3, accLo[3], 0, 0, 0);
            dLo      = __builtin_amdgcn_mfma_f32_16x16x32_bf16(aLo, ones8, dLo, 0, 0, 0);
            accHi[0] = __builtin_amdgcn_mfma_f32_16x16x32_bf16(aHi, bw0, accHi[0], 0, 0, 0);
            accHi[1] = __builtin_amdgcn_mfma_f32_16x16x32_bf16(aHi, bw1, accHi[1], 0, 0, 0);
            accHi[2] = __builtin_amdgcn_mfma_f32_16x16x32_bf16(aHi, bw2, accHi[2], 0, 0, 0);
            accHi[3] = __builtin_amdgcn_mfma_f32_16x16x32_bf16(aHi, bw3, accHi[3], 0, 0, 0);
            dHi      = __builtin_amdgcn_mfma_f32_16x16x32_bf16(aHi, ones8, dHi, 0, 0, 0);
            __builtin_amdgcn_s_setprio(0);
        }
        if (tt < 15) {                      // land prefetch into the other buffer
            *(short8*)&f_lds[(tt + 1) & 1][tid * 8] = Ra;
            *(short8*)&f_lds[(tt + 1) & 1][2048 + tid * 8] = Rb;
        }
        __syncthreads();
    }

    // ---- epilogue: normalize, +res, +bias, (ELU), store bf16 in place ----
    float rcpLo[4], rcpHi[4];
    #pragma unroll
    for (int r = 0; r < 4; ++r) {
        rcpLo[r] = 1.f / fmaxf(dLo[r], 1e-9f);     // jnp.clip(sum, 1e-9)
        rcpHi[r] = 1.f / fmaxf(dHi[r], 1e-9f);
    }
    #pragma unroll
    for (int dt = 0; dt < 4; ++dt) {
        const int d = dt * 16 + l15;
        const float bv = bias[h * 64 + d];
        #pragma unroll
        for (int r = 0; r < 4; ++r) {
            const int vl = v0 + wid * 32 + l4 * 4 + r;
            const size_t rowL = (bN + vl) * 256 + h * 64 + d;
            float ov = accLo[dt][r] * rcpLo[r] + bf2f(fea[rowL]) + bv;
            if (ELU_ON) ov = ov > 0.f ? ov : __expf(ov) - 1.f;
            fea[rowL] = f2bf(ov);
            const size_t rowH = (bN + vl + 16) * 256 + h * 64 + d;
            float ov2 = accHi[dt][r] * rcpHi[r] + bf2f(fea[rowH]) + bv;
            if (ELU_ON) ov2 = ov2 > 0.f ? ov2 : __expf(ov2) - 1.f;
            fea[rowH] = f2bf(ov2);
        }
    }
}

// ---------------- K5: mean over heads (bf16 in) -> d_out fp32 ----------------
__global__ __launch_bounds__(256) void k_headmean(
    const short* __restrict__ fea, float* __restrict__ outp)
{
    int i = blockIdx.x * 256 + threadIdx.x;     // i over B*N*64
    int d = i & 63;
    size_t node = (size_t)(i >> 6);
    const short* p = fea + node * 256;
    outp[i] = 0.25f * (bf2f(p[d]) + bf2f(p[64 + d]) + bf2f(p[128 + d]) + bf2f(p[192 + d]));
}

extern "C" void kernel_launch(void* const* d_in, const int* in_sizes, int n_in,
                              void* d_out, int out_size, void* d_ws, size_t ws_size,
                              hipStream_t stream) {
    const float* seg = (const float*)d_in[0];
    const float* adj = (const float*)d_in[1];
    const float* W0  = (const float*)d_in[2];
    const float* al0 = (const float*)d_in[3];
    const float* ar0 = (const float*)d_in[4];
    const float* rW0 = (const float*)d_in[5];
    const float* b0  = (const float*)d_in[6];
    const float* W1  = (const float*)d_in[7];
    const float* al1 = (const float*)d_in[8];
    const float* ar1 = (const float*)d_in[9];
    const float* rW1 = (const float*)d_in[10];
    const float* b1  = (const float*)d_in[11];
    float* out = (float*)d_out;

    char* ws = (char*)d_ws;
    size_t off = 0;
    uint64_t* mask  = (uint64_t*)ws;                 // 2 MB (dead after k_maskT)
    off += (size_t)BB * NN * 16 * 8;
    uint64_t* maskT = (uint64_t*)(ws + off); off += (size_t)BB * NN * 16 * 8;  // 2 MB
    short* ftb = (short*)(ws + off); off += (size_t)BB * 256 * NN * 2;         // 8 MB
    short* fea = (short*)(ws + off); off += (size_t)BB * NN * 256 * 2;         // 8 MB
    short* xb0 = (short*)(ws + off); off += (size_t)BB * NN * 64 * 2;          // 2 MB
    // small buffers reuse the dead `mask` region (valid after k_maskT completes)
    char* r0 = (char*)mask;
    short* Wt0  = (short*)r0;                 r0 += 256 * 64 * 2;
    short* rWt0 = (short*)r0;                 r0 += 256 * 64 * 2;
    short* Wt1  = (short*)r0;                 r0 += 256 * 256 * 2;
    short* rWt1 = (short*)r0;                 r0 += 256 * 256 * 2;
    float* el   = (float*)r0;                 r0 += (size_t)BB * 4 * NN * 4;
    float* er   = (float*)r0;                 r0 += (size_t)BB * 4 * NN * 4;

    k_topk_mask<<<BB * NN / 4, 256, 0, stream>>>(adj, mask);
    k_maskT<<<BB * 256 / 4, 256, 0, stream>>>(mask, maskT);
    // mask region now dead -> safe to fill Wt/el/er
    k_prepare<<<640 + BB * NN * 64 / 1024, 256, 0, stream>>>(
        W0, rW0, W1, rW1, seg, Wt0, rWt0, Wt1, rWt1, xb0);

    // layer 0 (K=64)
    k_features_mfma<64><<<BB * NN / 16, 256, 0, stream>>>(xb0, Wt0, rWt0, al0, ar0,
                                                          ftb, fea, el, er);
    k_attn<1><<<512, 256, 0, stream>>>(ftb, el, er, maskT, b0, fea);
    // layer 1 (K=256): x = fea in-place (protected by in-kernel syncthreads)
    k_features_mfma<256><<<BB * NN / 16, 256, 0, stream>>>(fea, Wt1, rWt1, al1, ar1,
                                                           ftb, fea, el, er);
    k_attn<0><<<512, 256, 0, stream>>>(ftb, el, er, maskT, b1, fea);

    k_headmean<<<BB * NN * 64 / 256, 256, 0, stream>>>(fea, out);
}

// Round 9
// 159.434 us; speedup vs baseline: 3.2775x; 1.1023x over previous
//
#include <hip/hip_runtime.h>
#include <hip/hip_bf16.h>
#include <stdint.h>

#define BB   16
#define NN   1024
#define KSEL 170   // (32*32)/6
#define LOG2E 1.4426950408889634f

typedef __attribute__((ext_vector_type(8))) short short8;
typedef __attribute__((ext_vector_type(4))) short short4v;
typedef __attribute__((ext_vector_type(4))) float f32x4;

static __device__ __forceinline__ short f2bf(float x) {
    __hip_bfloat16 h = __float2bfloat16(x);
    return *reinterpret_cast<short*>(&h);
}
static __device__ __forceinline__ float bf2f(short x) {
    uint32_t u = ((uint32_t)(uint16_t)x) << 16;
    return __uint_as_float(u);
}
static __device__ __forceinline__ float fast_exp2(float x) {
    float r; asm("v_exp_f32 %0, %1" : "=v"(r) : "v"(x)); return r;
}

// ---------------- K1: exact k-th-largest per row — ONE ROW PER WAVE ------------------
__global__ __launch_bounds__(256) void k_topk_mask(
    const float* __restrict__ adj, uint64_t* __restrict__ mask)
{
    const int wid = threadIdx.x >> 6, lane = threadIdx.x & 63;
    const int row = blockIdx.x * 4 + wid;              // b*N + u
    const float* a = adj + (size_t)row * NN;
    __shared__ uint32_t hist[4][256];
    uint32_t* h = hist[wid];

    uint32_t key[16];
    #pragma unroll
    for (int j = 0; j < 16; ++j) {
        uint32_t u = __float_as_uint(a[lane + j * 64]);
        key[j] = u ^ ((u >> 31) ? 0xFFFFFFFFu : 0x80000000u);   // order-preserving map
    }

    uint32_t prefix = 0u, kk = KSEL;
    #pragma unroll
    for (int pass = 0; pass < 4; ++pass) {
        const int shift = 24 - 8 * pass;
        const uint32_t hi_mask = pass ? (0xFFFFFFFFu << (shift + 8)) : 0u;
        *(uint4*)&h[lane * 4] = make_uint4(0u, 0u, 0u, 0u);
        __builtin_amdgcn_wave_barrier();
        #pragma unroll
        for (int j = 0; j < 16; ++j)
            if ((key[j] & hi_mask) == prefix)
                atomicAdd(&h[(key[j] >> shift) & 255], 1u);
        __builtin_amdgcn_wave_barrier();
        const uint4 c4 = *(const uint4*)&h[lane * 4];  // bins 4L..4L+3
        const uint32_t T = c4.x + c4.y + c4.z + c4.w;
        uint32_t s = T;
        #pragma unroll
        for (int off = 1; off < 64; off <<= 1) {       // inclusive suffix sum over lanes
            uint32_t v = __shfl_down(s, off);
            s += (lane + off < 64) ? v : 0u;
        }
        const uint32_t E = s - T;                      // sum over lanes above
        const uint32_t s3 = c4.w;
        const uint32_t s2 = c4.z + s3;
        const uint32_t s1 = c4.y + s2;
        const uint32_t s0 = c4.x + s1;
        const uint32_t ci[4] = {c4.x, c4.y, c4.z, c4.w};
        const uint32_t si[4] = {s0, s1, s2, s3};
        uint32_t found = 0u, nb = 0u, nk = 0u;
        #pragma unroll
        for (int i = 0; i < 4; ++i) {
            uint32_t incl = E + si[i];                 // count of keys in bins >= this
            uint32_t excl = incl - ci[i];
            if (excl < kk && kk <= incl) { found = 1u; nb = (uint32_t)(lane * 4 + i); nk = kk - excl; }
        }
        uint64_t bal = __ballot(found != 0u);
        int wl = __ffsll((unsigned long long)bal) - 1; // exactly one winner
        prefix = prefix | ((uint32_t)__shfl((int)nb, wl) << shift);
        kk = (uint32_t)__shfl((int)nk, wl);
    }

    const uint32_t thr_key = prefix;                   // key of k-th largest (exact)
    #pragma unroll
    for (int j = 0; j < 16; ++j) {
        bool pred = (key[j] >= thr_key) && (key[j] > 0x80000000u);   // adj>=thr && adj>0
        uint64_t bal = __ballot(pred);
        if (lane == 0) mask[(size_t)row * 16 + j] = bal;
    }
}

// ---------------- K1b: 64x64 bit-transpose of the mask (ballot-based) ----------------
__global__ __launch_bounds__(256) void k_maskT(
    const uint64_t* __restrict__ mask, uint64_t* __restrict__ maskT)
{
    const int tile = blockIdx.x * 4 + (threadIdx.x >> 6);  // b*256 + uw*16 + vw
    const int lane = threadIdx.x & 63;
    const int b  = tile >> 8;
    const int uw = (tile >> 4) & 15;
    const int vw = tile & 15;
    const size_t bN = (size_t)b * NN;
    uint64_t w = mask[(bN + uw * 64 + lane) * 16 + vw];
    uint64_t r_out = 0;
    #pragma unroll
    for (int j = 0; j < 64; ++j) {
        uint64_t r = __ballot((w >> j) & 1ull);
        if (lane == j) r_out = r;
    }
    maskT[(bN + vw * 64 + lane) * 16 + uw] = r_out;
}

// ---------------- K1c: merged prep: weight transposes (fp32->bf16) + seg convert -----
__global__ __launch_bounds__(256) void k_prepare(
    const float* __restrict__ W0, const float* __restrict__ rW0,
    const float* __restrict__ W1, const float* __restrict__ rW1,
    const float* __restrict__ seg,
    short* __restrict__ Wt0, short* __restrict__ rWt0,
    short* __restrict__ Wt1, short* __restrict__ rWt1,
    short* __restrict__ xb0)
{
    const int bid = blockIdx.x, t = threadIdx.x;
    if (bid < 64) {                      // Wt0 [256][64]
        int idx = bid * 256 + t;
        int o = idx >> 6, k = idx & 63;
        Wt0[idx] = f2bf(W0[(size_t)k * 256 + o]);
    } else if (bid < 128) {              // rWt0 [256][64]
        int idx = (bid - 64) * 256 + t;
        int o = idx >> 6, k = idx & 63;
        rWt0[idx] = f2bf(rW0[(size_t)k * 256 + o]);
    } else if (bid < 384) {              // Wt1 [256][256]
        int idx = (bid - 128) * 256 + t;
        int o = idx >> 8, k = idx & 255;
        Wt1[idx] = f2bf(W1[(size_t)k * 256 + o]);
    } else if (bid < 640) {              // rWt1 [256][256]
        int idx = (bid - 384) * 256 + t;
        int o = idx >> 8, k = idx & 255;
        rWt1[idx] = f2bf(rW1[(size_t)k * 256 + o]);
    } else {                             // seg fp32 -> bf16 (1M elems, 4/thread)
        int i = ((bid - 640) * 256 + t) * 4;
        float4 v = *(const float4*)(seg + i);
        short4v o4;
        o4[0] = f2bf(v.x); o4[1] = f2bf(v.y); o4[2] = f2bf(v.z); o4[3] = f2bf(v.w);
        *(short4v*)(xb0 + i) = o4;
    }
}

// ---------------- K2: MFMA features — 32 nodes/block, 1 head/wave --------------------
// x tile staged in LDS (shared by the 4 head-waves); weights double-buffered in
// registers (explicit prefetch); each weight fragment feeds 2 node-strips.
template<int K>
__global__ __launch_bounds__(256, 2) void k_features_mfma(
    const short* __restrict__ xb,   // [B*N][K] bf16 row-major
    const short* __restrict__ Wt,   // [256][K] bf16
    const short* __restrict__ rWt,  // [256][K] bf16
    const float* __restrict__ al,   // [256]
    const float* __restrict__ ar,   // [256]
    short* __restrict__ ft,         // tiled transposed features [bh][ut16][g8][d64][ui8]
    short* __restrict__ fea,        // [B*N][256] bf16: res written here (may alias xb)
    float* __restrict__ el_t,       // [(b*4+h)][NN] scaled by LOG2E
    float* __restrict__ er_t)       // [(b*4+h)][NN] scaled by LOG2E
{
    const int tid = threadIdx.x, lane = tid & 63, hh = tid >> 6;
    const int l15 = lane & 15, l4 = lane >> 4;
    const int n0 = blockIdx.x * 32;              // block's 32-node strip
    const int b_idx = n0 >> 10;                  // NN = 1024
    const int nloc = n0 & (NN - 1);
    const int bh = b_idx * 4 + hh;
    const int XP = K + 8;                        // padded LDS row stride (shorts)

    __shared__ short x_lds[32 * (K + 8)];

    // ---- stage x tile to LDS (coalesced; all x reads done before fea overwrite) ----
    const int CH = K / 8;                        // short8 chunks per row
    #pragma unroll
    for (int c = tid; c < 32 * CH; c += 256) {
        const int row = c / CH, col = c - row * CH;
        *(short8*)&x_lds[row * XP + col * 8] =
            *(const short8*)(xb + ((size_t)n0 + row) * K + col * 8);
    }
    __syncthreads();

    const short* wbase = Wt  + (size_t)(hh * 64 + l15) * K + l4 * 8;
    const short* rbase = rWt + (size_t)(hh * 64 + l15) * K + l4 * 8;
    const size_t qs = (size_t)16 * K;

    f32x4 accf[2][4], accr[2][4];
    #pragma unroll
    for (int s = 0; s < 2; ++s)
        #pragma unroll
        for (int q = 0; q < 4; ++q) {
            accf[s][q] = (f32x4){0.f, 0.f, 0.f, 0.f};
            accr[s][q] = (f32x4){0.f, 0.f, 0.f, 0.f};
        }

    short8 bufW[2][4], bufR[2][4];
    #pragma unroll
    for (int q = 0; q < 4; ++q) {
        bufW[0][q] = *(const short8*)(wbase + q * qs);
        bufR[0][q] = *(const short8*)(rbase + q * qs);
    }

    #pragma unroll
    for (int ks = 0; ks < K / 32; ++ks) {
        const int cur = ks & 1, nxt = cur ^ 1;
        if (ks + 1 < K / 32) {                   // prefetch next ks weight fragments
            #pragma unroll
            for (int q = 0; q < 4; ++q) {
                bufW[nxt][q] = *(const short8*)(wbase + q * qs + (ks + 1) * 32);
                bufR[nxt][q] = *(const short8*)(rbase + q * qs + (ks + 1) * 32);
            }
            __builtin_amdgcn_sched_barrier(0);   // pin load-issue before MFMA block
        }
        short8 x0 = *(const short8*)&x_lds[l15 * XP + ks * 32 + l4 * 8];
        short8 x1 = *(const short8*)&x_lds[(16 + l15) * XP + ks * 32 + l4 * 8];
        #pragma unroll
        for (int q = 0; q < 4; ++q) {
            accf[0][q] = __builtin_amdgcn_mfma_f32_16x16x32_bf16(x0, bufW[cur][q], accf[0][q], 0, 0, 0);
            accf[1][q] = __builtin_amdgcn_mfma_f32_16x16x32_bf16(x1, bufW[cur][q], accf[1][q], 0, 0, 0);
            accr[0][q] = __builtin_amdgcn_mfma_f32_16x16x32_bf16(bufR[cur][q], x0, accr[0][q], 0, 0, 0);
            accr[1][q] = __builtin_amdgcn_mfma_f32_16x16x32_bf16(bufR[cur][q], x1, accr[1][q], 0, 0, 0);
        }
    }

    #pragma unroll
    for (int s = 0; s < 2; ++s) {
        const int nl = nloc + s * 16;
        // ---- ft store (pass1 D): accf[s][q][r] = f[nl + l4*4 + r][hh*64 + q*16 + l15]
        #pragma unroll
        for (int q = 0; q < 4; ++q) {
            short4v pk;
            #pragma unroll
            for (int r = 0; r < 4; ++r) pk[r] = f2bf(accf[s][q][r]);
            const int dl = q * 16 + l15;         // head-local d
            const size_t idx = ((size_t)bh << 16)
                             + (size_t)(nl >> 6) * 4096
                             + (size_t)(((nl & 63) >> 3) + (l4 >> 1)) * 512
                             + (size_t)dl * 8 + (l4 & 1) * 4;
            *(short4v*)(ft + idx) = pk;
        }
        // ---- el/er head dots: reduce over d (16 l15-lanes x 4 q) ----
        float elv[4] = {0.f, 0.f, 0.f, 0.f}, erv[4] = {0.f, 0.f, 0.f, 0.f};
        #pragma unroll
        for (int q = 0; q < 4; ++q) {
            const float alv = al[hh * 64 + q * 16 + l15];
            const float arv = ar[hh * 64 + q * 16 + l15];
            #pragma unroll
            for (int r = 0; r < 4; ++r) {
                elv[r] = fmaf(accf[s][q][r], alv, elv[r]);
                erv[r] = fmaf(accf[s][q][r], arv, erv[r]);
            }
        }
        #pragma unroll
        for (int r = 0; r < 4; ++r) {
            #pragma unroll
            for (int off = 1; off < 16; off <<= 1) {
                elv[r] += __shfl_xor(elv[r], off);
                erv[r] += __shfl_xor(erv[r], off);
            }
        }
        if (l15 == 0) {                          // 4 lanes (l4=0..3), rows nl+l4*4+r
            float4 e4, r4;
            e4.x = elv[0] * LOG2E; e4.y = elv[1] * LOG2E;
            e4.z = elv[2] * LOG2E; e4.w = elv[3] * LOG2E;
            r4.x = erv[0] * LOG2E; r4.y = erv[1] * LOG2E;
            r4.z = erv[2] * LOG2E; r4.w = erv[3] * LOG2E;
            *(float4*)(el_t + (size_t)bh * NN + nl + l4 * 4) = e4;
            *(float4*)(er_t + (size_t)bh * NN + nl + l4 * 4) = r4;
        }
        // ---- fea store (pass2 D, swapped): accr[s][q][r] = res[o=hh*64+q*16+l4*4+r][n]
        #pragma unroll
        for (int q = 0; q < 4; ++q) {
            short4v pk;
            #pragma unroll
            for (int r = 0; r < 4; ++r) pk[r] = f2bf(accr[s][q][r]);
            *(short4v*)(fea + ((size_t)n0 + s * 16 + l15) * 256 + hh * 64 + q * 16 + l4 * 4) = pk;
        }
    }
}

// ---------------- K4: masked softmax + MFMA PV + residual + bias (+ELU) --------------
// 4 waves x 32 v (v-tile 128); f-tile double-buffered in LDS, 2-phase pipeline.
// elmax computed in-block from the staged el strip.
template<int ELU_ON>
__global__ __launch_bounds__(256, 4) void k_attn(
    const short* __restrict__ ft,     // tiled [bh][ut16][g8][d64][ui8]
    const float* __restrict__ el_t,   // [(b*4+h)][NN] scaled
    const float* __restrict__ er_t,   // [(b*4+h)][NN] scaled
    const uint64_t* __restrict__ maskT,// [b*N + v][16] u-words
    const float* __restrict__ bias,   // [256]
    short* fea)                       // [B*N][256] bf16: res in, out in-place
{
    // XCD swizzle: 512 blocks, 64 per XCD -> 2 full b's per XCD
    const int id = blockIdx.x;
    const int swz = (id & 7) * 64 + (id >> 3);
    const int b  = swz >> 5;
    const int h  = (swz >> 3) & 3;
    const int vt = swz & 7;
    const int tid = threadIdx.x;
    const int lane = tid & 63, wid = tid >> 6;
    const int l15 = lane & 15, l4 = lane >> 4;
    const int bh = b * 4 + h;
    const size_t bN = (size_t)b * NN;
    const int v0 = vt * 128;

    __shared__ __align__(16) short f_lds[2][4096];      // [buf][g*512 + d*8 + ui]
    __shared__ __align__(16) float el_lds[NN];
    __shared__ __align__(16) uint64_t m_lds[128 * 17];  // 136B row stride
    __shared__ float smax[4];

    const short* gsrc = ft + ((size_t)bh << 16);

    // ---- prologue staging: tile 0, el strip (+ block-local max), mask rows ----
    {
        short8 sa = *(const short8*)(gsrc + tid * 8);
        short8 sb = *(const short8*)(gsrc + 2048 + tid * 8);
        float4 ev4 = ((const float4*)(el_t + (size_t)bh * NN))[tid];
        ((float4*)el_lds)[tid] = ev4;
        float m = fmaxf(fmaxf(ev4.x, ev4.y), fmaxf(ev4.z, ev4.w));
        #pragma unroll
        for (int off = 32; off; off >>= 1) m = fmaxf(m, __shfl_xor(m, off));
        if (lane == 0) smax[wid] = m;
        #pragma unroll
        for (int i = 0; i < 8; ++i) {
            int idx = tid + i * 256;           // 2048 uint64 words
            m_lds[(idx >> 4) * 17 + (idx & 15)] =
                maskT[(bN + v0 + (idx >> 4)) * 16 + (idx & 15)];
        }
        *(short8*)&f_lds[0][tid * 8] = sa;
        *(short8*)&f_lds[0][2048 + tid * 8] = sb;
    }

    const int vlo = wid * 32 + l15, vhi = vlo + 16;
    const float er_lo = er_t[(size_t)bh * NN + v0 + vlo];
    const float er_hi = er_t[(size_t)bh * NN + v0 + vhi];

    __syncthreads();

    const float emx = fmaxf(fmaxf(smax[0], smax[1]), fmaxf(smax[2], smax[3]));
    const float e0 = emx + er_lo;
    const float cv_lo = fmaxf(e0, 0.2f * e0);    // lrelu monotone -> valid shift
    const float e1 = emx + er_hi;
    const float cv_hi = fmaxf(e1, 0.2f * e1);
    const float c1_lo = er_lo - cv_lo, c2_lo = 0.2f * er_lo - cv_lo;
    const float c1_hi = er_hi - cv_hi, c2_hi = 0.2f * er_hi - cv_hi;

    const uint8_t* mbytes = (const uint8_t*)m_lds;
    const int moff_lo = vlo * 136, moff_hi = vhi * 136;

    short8 ones8;
    #pragma unroll
    for (int i = 0; i < 8; ++i) ones8[i] = (short)0x3F80;   // bf16 1.0

    f32x4 accLo[4], accHi[4];
    #pragma unroll
    for (int i = 0; i < 4; ++i) {
        accLo[i] = (f32x4){0.f, 0.f, 0.f, 0.f};
        accHi[i] = (f32x4){0.f, 0.f, 0.f, 0.f};
    }
    f32x4 dLo = (f32x4){0.f, 0.f, 0.f, 0.f};
    f32x4 dHi = (f32x4){0.f, 0.f, 0.f, 0.f};

    short8 Ra, Rb;
    #pragma unroll 1
    for (int tt = 0; tt < 16; ++tt) {
        if (tt < 15) {                      // issue next-tile loads early (T14 split)
            Ra = *(const short8*)(gsrc + (tt + 1) * 4096 + tid * 8);
            Rb = *(const short8*)(gsrc + (tt + 1) * 4096 + 2048 + tid * 8);
            __builtin_amdgcn_sched_barrier(0);
        }
        const short* fb = f_lds[tt & 1];
        #pragma unroll
        for (int kc = 0; kc < 2; ++kc) {
            const float* ep = &el_lds[tt * 64 + kc * 32 + l4 * 8];
            float4 ev0 = *(const float4*)ep;
            float4 ev1 = *(const float4*)(ep + 4);
            const float ev[8] = {ev0.x, ev0.y, ev0.z, ev0.w, ev1.x, ev1.y, ev1.z, ev1.w};
            uint32_t mLo = mbytes[moff_lo + tt * 8 + kc * 4 + l4];
            uint32_t mHi = mbytes[moff_hi + tt * 8 + kc * 4 + l4];
            short8 aLo, aHi;
            #pragma unroll
            for (int j = 0; j < 8; ++j) {
                float e = ev[j];
                float argL = fmaxf(e + c1_lo, fmaf(0.2f, e, c2_lo));
                float argH = fmaxf(e + c1_hi, fmaf(0.2f, e, c2_hi));
                float pL = ((mLo >> j) & 1u) ? fast_exp2(argL) : 0.f;
                float pH = ((mHi >> j) & 1u) ? fast_exp2(argH) : 0.f;
                aLo[j] = f2bf(pL);
                aHi[j] = f2bf(pH);
            }
            const int fo = (kc * 4 + l4) * 512 + l15 * 8;
            short8 bw0 = *(const short8*)(fb + fo);
            short8 bw1 = *(const short8*)(fb + fo + 128);
            short8 bw2 = *(const short8*)(fb + fo + 256);
            short8 bw3 = *(const short8*)(fb + fo + 384);
            __builtin_amdgcn_s_setprio(1);
            accLo[0] = __builtin_amdgcn_mfma_f32_16x16x32_bf16(aLo, bw0, accLo[0], 0, 0, 0);
            accLo[1] = __builtin_amdgcn_mfma_f32_16x16x32_bf16(aLo, bw1, accLo[1], 0, 0, 0);
            accLo[2] = __builtin_amdgcn_mfma_f32_16x16x32_bf16(aLo, bw2, accLo[2], 0, 0, 0);
            accLo[3] = __builtin_amdgcn_mfma_f32_16x16x32_bf16(aLo, bw3, accLo[3], 0, 0, 0);
            dLo      = __builtin_amdgcn_mfma_f32_16x16x32_bf16(aLo, ones8, dLo, 0, 0, 0);
            accHi[0] = __builtin_amdgcn_mfma_f32_16x16x32_bf16(aHi, bw0, accHi[0], 0, 0, 0);
            accHi[1] = __builtin_amdgcn_mfma_f32_16x16x32_bf16(aHi, bw1, accHi[1], 0, 0, 0);
            accHi[2] = __builtin_amdgcn_mfma_f32_16x16x32_bf16(aHi, bw2, accHi[2], 0, 0, 0);
            accHi[3] = __builtin_amdgcn_mfma_f32_16x16x32_bf16(aHi, bw3, accHi[3], 0, 0, 0);
            dHi      = __builtin_amdgcn_mfma_f32_16x16x32_bf16(aHi, ones8, dHi, 0, 0, 0);
            __builtin_amdgcn_s_setprio(0);
        }
        if (tt < 15) {                      // land prefetch into the other buffer
            *(short8*)&f_lds[(tt + 1) & 1][tid * 8] = Ra;
            *(short8*)&f_lds[(tt + 1) & 1][2048 + tid * 8] = Rb;
        }
        __syncthreads();
    }

    // ---- epilogue: normalize, +res, +bias, (ELU), store bf16 in place ----
    float rcpLo[4], rcpHi[4];
    #pragma unroll
    for (int r = 0; r < 4; ++r) {
        rcpLo[r] = 1.f / fmaxf(dLo[r], 1e-9f);     // jnp.clip(sum, 1e-9)
        rcpHi[r] = 1.f / fmaxf(dHi[r], 1e-9f);
    }
    #pragma unroll
    for (int dt = 0; dt < 4; ++dt) {
        const int d = dt * 16 + l15;
        const float bv = bias[h * 64 + d];
        #pragma unroll
        for (int r = 0; r < 4; ++r) {
            const int vl = v0 + wid * 32 + l4 * 4 + r;
            const size_t rowL = (bN + vl) * 256 + h * 64 + d;
            float ov = accLo[dt][r] * rcpLo[r] + bf2f(fea[rowL]) + bv;
            if (ELU_ON) ov = ov > 0.f ? ov : __expf(ov) - 1.f;
            fea[rowL] = f2bf(ov);
            const size_t rowH = (bN + vl + 16) * 256 + h * 64 + d;
            float ov2 = accHi[dt][r] * rcpHi[r] + bf2f(fea[rowH]) + bv;
            if (ELU_ON) ov2 = ov2 > 0.f ? ov2 : __expf(ov2) - 1.f;
            fea[rowH] = f2bf(ov2);
        }
    }
}

// ---------------- K5: mean over heads (bf16 in) -> d_out fp32 ----------------
__global__ __launch_bounds__(256) void k_headmean(
    const short* __restrict__ fea, float* __restrict__ outp)
{
    int i = blockIdx.x * 256 + threadIdx.x;     // i over B*N*64
    int d = i & 63;
    size_t node = (size_t)(i >> 6);
    const short* p = fea + node * 256;
    outp[i] = 0.25f * (bf2f(p[d]) + bf2f(p[64 + d]) + bf2f(p[128 + d]) + bf2f(p[192 + d]));
}

extern "C" void kernel_launch(void* const* d_in, const int* in_sizes, int n_in,
                              void* d_out, int out_size, void* d_ws, size_t ws_size,
                              hipStream_t stream) {
    const float* seg = (const float*)d_in[0];
    const float* adj = (const float*)d_in[1];
    const float* W0  = (const float*)d_in[2];
    const float* al0 = (const float*)d_in[3];
    const float* ar0 = (const float*)d_in[4];
    const float* rW0 = (const float*)d_in[5];
    const float* b0  = (const float*)d_in[6];
    const float* W1  = (const float*)d_in[7];
    const float* al1 = (const float*)d_in[8];
    const float* ar1 = (const float*)d_in[9];
    const float* rW1 = (const float*)d_in[10];
    const float* b1  = (const float*)d_in[11];
    float* out = (float*)d_out;

    char* ws = (char*)d_ws;
    size_t off = 0;
    uint64_t* mask  = (uint64_t*)ws;                 // 2 MB (dead after k_maskT)
    off += (size_t)BB * NN * 16 * 8;
    uint64_t* maskT = (uint64_t*)(ws + off); off += (size_t)BB * NN * 16 * 8;  // 2 MB
    short* ftb = (short*)(ws + off); off += (size_t)BB * 256 * NN * 2;         // 8 MB
    short* fea = (short*)(ws + off); off += (size_t)BB * NN * 256 * 2;         // 8 MB
    short* xb0 = (short*)(ws + off); off += (size_t)BB * NN * 64 * 2;          // 2 MB
    // small buffers reuse the dead `mask` region (valid after k_maskT completes)
    char* r0 = (char*)mask;
    short* Wt0  = (short*)r0;                 r0 += 256 * 64 * 2;
    short* rWt0 = (short*)r0;                 r0 += 256 * 64 * 2;
    short* Wt1  = (short*)r0;                 r0 += 256 * 256 * 2;
    short* rWt1 = (short*)r0;                 r0 += 256 * 256 * 2;
    float* el   = (float*)r0;                 r0 += (size_t)BB * 4 * NN * 4;
    float* er   = (float*)r0;                 r0 += (size_t)BB * 4 * NN * 4;

    k_topk_mask<<<BB * NN / 4, 256, 0, stream>>>(adj, mask);
    k_maskT<<<BB * 256 / 4, 256, 0, stream>>>(mask, maskT);
    // mask region now dead -> safe to fill Wt/el/er
    k_prepare<<<640 + BB * NN * 64 / 1024, 256, 0, stream>>>(
        W0, rW0, W1, rW1, seg, Wt0, rWt0, Wt1, rWt1, xb0);

    // layer 0 (K=64)
    k_features_mfma<64><<<BB * NN / 32, 256, 0, stream>>>(xb0, Wt0, rWt0, al0, ar0,
                                                          ftb, fea, el, er);
    k_attn<1><<<512, 256, 0, stream>>>(ftb, el, er, maskT, b0, fea);
    // layer 1 (K=256): x = fea in-place (x fully LDS-resident before fea write)
    k_features_mfma<256><<<BB * NN / 32, 256, 0, stream>>>(fea, Wt1, rWt1, al1, ar1,
                                                           ftb, fea, el, er);
    k_attn<0><<<512, 256, 0, stream>>>(ftb, el, er, maskT, b1, fea);

    k_headmean<<<BB * NN * 64 / 256, 256, 0, stream>>>(fea, out);
}

// Round 10
// 153.354 us; speedup vs baseline: 3.4074x; 1.0396x over previous
//
#include <hip/hip_runtime.h>
#include <hip/hip_bf16.h>
#include <stdint.h>

#define BB   16
#define NN   1024
#define KSEL 170   // (32*32)/6
#define LOG2E 1.4426950408889634f

typedef __attribute__((ext_vector_type(8))) short short8;
typedef __attribute__((ext_vector_type(4))) short short4v;
typedef __attribute__((ext_vector_type(4))) float f32x4;

static __device__ __forceinline__ short f2bf(float x) {
    __hip_bfloat16 h = __float2bfloat16(x);
    return *reinterpret_cast<short*>(&h);
}
static __device__ __forceinline__ float bf2f(short x) {
    uint32_t u = ((uint32_t)(uint16_t)x) << 16;
    return __uint_as_float(u);
}
static __device__ __forceinline__ float fast_exp2(float x) {
    float r; asm("v_exp_f32 %0, %1" : "=v"(r) : "v"(x)); return r;
}

// ---------------- K1: exact k-th-largest per row — ONE ROW PER WAVE ------------------
// 2 radix passes (16 prefix bits) + wave-uniform survivor max-extraction. Exact.
__global__ __launch_bounds__(256) void k_topk_mask(
    const float* __restrict__ adj, uint64_t* __restrict__ mask)
{
    const int wid = threadIdx.x >> 6, lane = threadIdx.x & 63;
    const int row = blockIdx.x * 4 + wid;              // b*N + u
    const float* a = adj + (size_t)row * NN;
    __shared__ uint32_t hist[4][256];
    uint32_t* h = hist[wid];

    uint32_t key[16];
    #pragma unroll
    for (int j = 0; j < 16; ++j) {
        uint32_t u = __float_as_uint(a[lane + j * 64]);
        key[j] = u ^ ((u >> 31) ? 0xFFFFFFFFu : 0x80000000u);   // order-preserving map
    }

    uint32_t prefix = 0u, kk = KSEL;
    #pragma unroll
    for (int pass = 0; pass < 2; ++pass) {
        const int shift = 24 - 8 * pass;
        const uint32_t hi_mask = pass ? 0xFF000000u : 0u;
        *(uint4*)&h[lane * 4] = make_uint4(0u, 0u, 0u, 0u);
        __builtin_amdgcn_wave_barrier();
        #pragma unroll
        for (int j = 0; j < 16; ++j)
            if ((key[j] & hi_mask) == prefix)
                atomicAdd(&h[(key[j] >> shift) & 255], 1u);
        __builtin_amdgcn_wave_barrier();
        const uint4 c4 = *(const uint4*)&h[lane * 4];  // bins 4L..4L+3
        const uint32_t T = c4.x + c4.y + c4.z + c4.w;
        uint32_t s = T;
        #pragma unroll
        for (int off = 1; off < 64; off <<= 1) {       // inclusive suffix sum over lanes
            uint32_t v = __shfl_down(s, off);
            s += (lane + off < 64) ? v : 0u;
        }
        const uint32_t E = s - T;                      // sum over lanes above
        const uint32_t s3 = c4.w;
        const uint32_t s2 = c4.z + s3;
        const uint32_t s1 = c4.y + s2;
        const uint32_t s0 = c4.x + s1;
        const uint32_t ci[4] = {c4.x, c4.y, c4.z, c4.w};
        const uint32_t si[4] = {s0, s1, s2, s3};
        uint32_t found = 0u, nb = 0u, nk = 0u;
        #pragma unroll
        for (int i = 0; i < 4; ++i) {
            uint32_t incl = E + si[i];                 // count of keys in bins >= this
            uint32_t excl = incl - ci[i];
            if (excl < kk && kk <= incl) { found = 1u; nb = (uint32_t)(lane * 4 + i); nk = kk - excl; }
        }
        uint64_t bal = __ballot(found != 0u);
        int wl = __ffsll((unsigned long long)bal) - 1; // exactly one winner
        prefix = prefix | ((uint32_t)__shfl((int)nb, wl) << shift);
        kk = (uint32_t)__shfl((int)nk, wl);
    }

    // ---- survivors share the 16-bit prefix; select kk-th largest exactly ----
    uint32_t sv[16];
    #pragma unroll
    for (int j = 0; j < 16; ++j)
        sv[j] = ((key[j] ^ prefix) >> 16) == 0u ? key[j] : 0u;   // 0 = sentinel

    uint32_t thr_key;
    for (;;) {
        uint32_t m = 0u;
        #pragma unroll
        for (int j = 0; j < 16; ++j) m = m > sv[j] ? m : sv[j];
        #pragma unroll
        for (int off = 1; off < 64; off <<= 1) {       // butterfly max -> uniform
            uint32_t v = __shfl_xor(m, off);
            m = m > v ? m : v;
        }
        if (m == 0u) { thr_key = 0u; break; }          // degenerate: thr = min key
        uint32_t c = 0u;
        #pragma unroll
        for (int j = 0; j < 16; ++j) c += (sv[j] == m) ? 1u : 0u;
        #pragma unroll
        for (int off = 1; off < 64; off <<= 1)
            c += __shfl_xor(c, off);                   // uniform count of == m
        if (kk <= c) { thr_key = m; break; }
        kk -= c;
        #pragma unroll
        for (int j = 0; j < 16; ++j) if (sv[j] == m) sv[j] = 0u;
    }

    #pragma unroll
    for (int j = 0; j < 16; ++j) {
        bool pred = (key[j] >= thr_key) && (key[j] > 0x80000000u);   // adj>=thr && adj>0
        uint64_t bal = __ballot(pred);
        if (lane == 0) mask[(size_t)row * 16 + j] = bal;
    }
}

// ---------------- K1b: 64x64 bit-transpose of the mask (ballot-based) ----------------
__global__ __launch_bounds__(256) void k_maskT(
    const uint64_t* __restrict__ mask, uint64_t* __restrict__ maskT)
{
    const int tile = blockIdx.x * 4 + (threadIdx.x >> 6);  // b*256 + uw*16 + vw
    const int lane = threadIdx.x & 63;
    const int b  = tile >> 8;
    const int uw = (tile >> 4) & 15;
    const int vw = tile & 15;
    const size_t bN = (size_t)b * NN;
    uint64_t w = mask[(bN + uw * 64 + lane) * 16 + vw];
    uint64_t r_out = 0;
    #pragma unroll
    for (int j = 0; j < 64; ++j) {
        uint64_t r = __ballot((w >> j) & 1ull);
        if (lane == j) r_out = r;
    }
    maskT[(bN + vw * 64 + lane) * 16 + uw] = r_out;
}

// ---------------- K1c: merged prep: weight transposes (fp32->bf16) + seg convert -----
__global__ __launch_bounds__(256) void k_prepare(
    const float* __restrict__ W0, const float* __restrict__ rW0,
    const float* __restrict__ W1, const float* __restrict__ rW1,
    const float* __restrict__ seg,
    short* __restrict__ Wt0, short* __restrict__ rWt0,
    short* __restrict__ Wt1, short* __restrict__ rWt1,
    short* __restrict__ xb0)
{
    const int bid = blockIdx.x, t = threadIdx.x;
    if (bid < 64) {                      // Wt0 [256][64]
        int idx = bid * 256 + t;
        int o = idx >> 6, k = idx & 63;
        Wt0[idx] = f2bf(W0[(size_t)k * 256 + o]);
    } else if (bid < 128) {              // rWt0 [256][64]
        int idx = (bid - 64) * 256 + t;
        int o = idx >> 6, k = idx & 63;
        rWt0[idx] = f2bf(rW0[(size_t)k * 256 + o]);
    } else if (bid < 384) {              // Wt1 [256][256]
        int idx = (bid - 128) * 256 + t;
        int o = idx >> 8, k = idx & 255;
        Wt1[idx] = f2bf(W1[(size_t)k * 256 + o]);
    } else if (bid < 640) {              // rWt1 [256][256]
        int idx = (bid - 384) * 256 + t;
        int o = idx >> 8, k = idx & 255;
        rWt1[idx] = f2bf(rW1[(size_t)k * 256 + o]);
    } else {                             // seg fp32 -> bf16 (1M elems, 4/thread)
        int i = ((bid - 640) * 256 + t) * 4;
        float4 v = *(const float4*)(seg + i);
        short4v o4;
        o4[0] = f2bf(v.x); o4[1] = f2bf(v.y); o4[2] = f2bf(v.z); o4[3] = f2bf(v.w);
        *(short4v*)(xb0 + i) = o4;
    }
}

// ---------------- K2: MFMA features — 32 nodes/block, 1 head/wave --------------------
template<int K>
__global__ __launch_bounds__(256, 2) void k_features_mfma(
    const short* __restrict__ xb,   // [B*N][K] bf16 row-major
    const short* __restrict__ Wt,   // [256][K] bf16
    const short* __restrict__ rWt,  // [256][K] bf16
    const float* __restrict__ al,   // [256]
    const float* __restrict__ ar,   // [256]
    short* __restrict__ ft,         // tiled transposed features [bh][ut16][g8][d64][ui8]
    short* __restrict__ fea,        // [B*N][256] bf16: res written here (may alias xb)
    float* __restrict__ el_t,       // [(b*4+h)][NN] scaled by LOG2E
    float* __restrict__ er_t)       // [(b*4+h)][NN] scaled by LOG2E
{
    const int tid = threadIdx.x, lane = tid & 63, hh = tid >> 6;
    const int l15 = lane & 15, l4 = lane >> 4;
    const int n0 = blockIdx.x * 32;              // block's 32-node strip
    const int b_idx = n0 >> 10;                  // NN = 1024
    const int nloc = n0 & (NN - 1);
    const int bh = b_idx * 4 + hh;
    const int XP = K + 8;                        // padded LDS row stride (shorts)

    __shared__ short x_lds[32 * (K + 8)];

    const int CH = K / 8;                        // short8 chunks per row
    #pragma unroll
    for (int c = tid; c < 32 * CH; c += 256) {
        const int row = c / CH, col = c - row * CH;
        *(short8*)&x_lds[row * XP + col * 8] =
            *(const short8*)(xb + ((size_t)n0 + row) * K + col * 8);
    }
    __syncthreads();

    const short* wbase = Wt  + (size_t)(hh * 64 + l15) * K + l4 * 8;
    const short* rbase = rWt + (size_t)(hh * 64 + l15) * K + l4 * 8;
    const size_t qs = (size_t)16 * K;

    f32x4 accf[2][4], accr[2][4];
    #pragma unroll
    for (int s = 0; s < 2; ++s)
        #pragma unroll
        for (int q = 0; q < 4; ++q) {
            accf[s][q] = (f32x4){0.f, 0.f, 0.f, 0.f};
            accr[s][q] = (f32x4){0.f, 0.f, 0.f, 0.f};
        }

    short8 bufW[2][4], bufR[2][4];
    #pragma unroll
    for (int q = 0; q < 4; ++q) {
        bufW[0][q] = *(const short8*)(wbase + q * qs);
        bufR[0][q] = *(const short8*)(rbase + q * qs);
    }

    #pragma unroll
    for (int ks = 0; ks < K / 32; ++ks) {
        const int cur = ks & 1, nxt = cur ^ 1;
        if (ks + 1 < K / 32) {                   // prefetch next ks weight fragments
            #pragma unroll
            for (int q = 0; q < 4; ++q) {
                bufW[nxt][q] = *(const short8*)(wbase + q * qs + (ks + 1) * 32);
                bufR[nxt][q] = *(const short8*)(rbase + q * qs + (ks + 1) * 32);
            }
            __builtin_amdgcn_sched_barrier(0);   // pin load-issue before MFMA block
        }
        short8 x0 = *(const short8*)&x_lds[l15 * XP + ks * 32 + l4 * 8];
        short8 x1 = *(const short8*)&x_lds[(16 + l15) * XP + ks * 32 + l4 * 8];
        #pragma unroll
        for (int q = 0; q < 4; ++q) {
            accf[0][q] = __builtin_amdgcn_mfma_f32_16x16x32_bf16(x0, bufW[cur][q], accf[0][q], 0, 0, 0);
            accf[1][q] = __builtin_amdgcn_mfma_f32_16x16x32_bf16(x1, bufW[cur][q], accf[1][q], 0, 0, 0);
            accr[0][q] = __builtin_amdgcn_mfma_f32_16x16x32_bf16(bufR[cur][q], x0, accr[0][q], 0, 0, 0);
            accr[1][q] = __builtin_amdgcn_mfma_f32_16x16x32_bf16(bufR[cur][q], x1, accr[1][q], 0, 0, 0);
        }
    }

    #pragma unroll
    for (int s = 0; s < 2; ++s) {
        const int nl = nloc + s * 16;
        #pragma unroll
        for (int q = 0; q < 4; ++q) {
            short4v pk;
            #pragma unroll
            for (int r = 0; r < 4; ++r) pk[r] = f2bf(accf[s][q][r]);
            const int dl = q * 16 + l15;         // head-local d
            const size_t idx = ((size_t)bh << 16)
                             + (size_t)(nl >> 6) * 4096
                             + (size_t)(((nl & 63) >> 3) + (l4 >> 1)) * 512
                             + (size_t)dl * 8 + (l4 & 1) * 4;
            *(short4v*)(ft + idx) = pk;
        }
        float elv[4] = {0.f, 0.f, 0.f, 0.f}, erv[4] = {0.f, 0.f, 0.f, 0.f};
        #pragma unroll
        for (int q = 0; q < 4; ++q) {
            const float alv = al[hh * 64 + q * 16 + l15];
            const float arv = ar[hh * 64 + q * 16 + l15];
            #pragma unroll
            for (int r = 0; r < 4; ++r) {
                elv[r] = fmaf(accf[s][q][r], alv, elv[r]);
                erv[r] = fmaf(accf[s][q][r], arv, erv[r]);
            }
        }
        #pragma unroll
        for (int r = 0; r < 4; ++r) {
            #pragma unroll
            for (int off = 1; off < 16; off <<= 1) {
                elv[r] += __shfl_xor(elv[r], off);
                erv[r] += __shfl_xor(erv[r], off);
            }
        }
        if (l15 == 0) {                          // 4 lanes (l4=0..3), rows nl+l4*4+r
            float4 e4, r4;
            e4.x = elv[0] * LOG2E; e4.y = elv[1] * LOG2E;
            e4.z = elv[2] * LOG2E; e4.w = elv[3] * LOG2E;
            r4.x = erv[0] * LOG2E; r4.y = erv[1] * LOG2E;
            r4.z = erv[2] * LOG2E; r4.w = erv[3] * LOG2E;
            *(float4*)(el_t + (size_t)bh * NN + nl + l4 * 4) = e4;
            *(float4*)(er_t + (size_t)bh * NN + nl + l4 * 4) = r4;
        }
        #pragma unroll
        for (int q = 0; q < 4; ++q) {
            short4v pk;
            #pragma unroll
            for (int r = 0; r < 4; ++r) pk[r] = f2bf(accr[s][q][r]);
            *(short4v*)(fea + ((size_t)n0 + s * 16 + l15) * 256 + hh * 64 + q * 16 + l4 * 4) = pk;
        }
    }
}

// ---------------- K4: masked softmax + MFMA PV + residual + bias (+ELU) --------------
// 4 waves x 16 v (v-tile 64, grid 1024 = 4 blocks/CU); f-tile double-buffered in LDS.
template<int ELU_ON>
__global__ __launch_bounds__(256, 4) void k_attn(
    const short* __restrict__ ft,     // tiled [bh][ut16][g8][d64][ui8]
    const float* __restrict__ el_t,   // [(b*4+h)][NN] scaled
    const float* __restrict__ er_t,   // [(b*4+h)][NN] scaled
    const uint64_t* __restrict__ maskT,// [b*N + v][16] u-words
    const float* __restrict__ bias,   // [256]
    short* fea)                       // [B*N][256] bf16: res in, out in-place
{
    // XCD swizzle: 1024 blocks, 128 per XCD (8 full bh strips per XCD)
    const int id = blockIdx.x;
    const int swz = (id & 7) * 128 + (id >> 3);
    const int b  = swz >> 6;
    const int h  = (swz >> 4) & 3;
    const int vt = swz & 15;
    const int tid = threadIdx.x;
    const int lane = tid & 63, wid = tid >> 6;
    const int l15 = lane & 15, l4 = lane >> 4;
    const int bh = b * 4 + h;
    const size_t bN = (size_t)b * NN;
    const int v0 = vt * 64;

    __shared__ __align__(16) short f_lds[2][4096];      // [buf][g*512 + d*8 + ui]
    __shared__ __align__(16) float el_lds[NN];
    __shared__ __align__(16) uint64_t m_lds[64 * 17];   // 136B row stride
    __shared__ float smax[4];

    const short* gsrc = ft + ((size_t)bh << 16);

    // ---- prologue staging: tile 0, el strip (+ block-local max), mask rows ----
    {
        short8 sa = *(const short8*)(gsrc + tid * 8);
        short8 sb = *(const short8*)(gsrc + 2048 + tid * 8);
        float4 ev4 = ((const float4*)(el_t + (size_t)bh * NN))[tid];
        ((float4*)el_lds)[tid] = ev4;
        float m = fmaxf(fmaxf(ev4.x, ev4.y), fmaxf(ev4.z, ev4.w));
        #pragma unroll
        for (int off = 32; off; off >>= 1) m = fmaxf(m, __shfl_xor(m, off));
        if (lane == 0) smax[wid] = m;
        #pragma unroll
        for (int i = 0; i < 4; ++i) {
            int idx = tid + i * 256;           // 1024 uint64 words
            m_lds[(idx >> 4) * 17 + (idx & 15)] =
                maskT[(bN + v0 + (idx >> 4)) * 16 + (idx & 15)];
        }
        *(short8*)&f_lds[0][tid * 8] = sa;
        *(short8*)&f_lds[0][2048 + tid * 8] = sb;
    }

    const int vlo = wid * 16 + l15;
    const float er_lo = er_t[(size_t)bh * NN + v0 + vlo];

    __syncthreads();

    const float emx = fmaxf(fmaxf(smax[0], smax[1]), fmaxf(smax[2], smax[3]));
    const float e0 = emx + er_lo;
    const float cv_lo = fmaxf(e0, 0.2f * e0);    // lrelu monotone -> valid shift
    const float c1_lo = er_lo - cv_lo, c2_lo = 0.2f * er_lo - cv_lo;

    const uint8_t* mbytes = (const uint8_t*)m_lds;
    const int moff_lo = vlo * 136;

    short8 ones8;
    #pragma unroll
    for (int i = 0; i < 8; ++i) ones8[i] = (short)0x3F80;   // bf16 1.0

    f32x4 accLo[4];
    #pragma unroll
    for (int i = 0; i < 4; ++i) accLo[i] = (f32x4){0.f, 0.f, 0.f, 0.f};
    f32x4 dLo = (f32x4){0.f, 0.f, 0.f, 0.f};

    short8 Ra, Rb;
    #pragma unroll 1
    for (int tt = 0; tt < 16; ++tt) {
        if (tt < 15) {                      // issue next-tile loads early (T14 split)
            Ra = *(const short8*)(gsrc + (tt + 1) * 4096 + tid * 8);
            Rb = *(const short8*)(gsrc + (tt + 1) * 4096 + 2048 + tid * 8);
            __builtin_amdgcn_sched_barrier(0);
        }
        const short* fb = f_lds[tt & 1];
        #pragma unroll
        for (int kc = 0; kc < 2; ++kc) {
            const float* ep = &el_lds[tt * 64 + kc * 32 + l4 * 8];
            float4 ev0 = *(const float4*)ep;
            float4 ev1 = *(const float4*)(ep + 4);
            const float ev[8] = {ev0.x, ev0.y, ev0.z, ev0.w, ev1.x, ev1.y, ev1.z, ev1.w};
            uint32_t mLo = mbytes[moff_lo + tt * 8 + kc * 4 + l4];
            short8 aLo;
            #pragma unroll
            for (int j = 0; j < 8; ++j) {
                float e = ev[j];
                float argL = fmaxf(e + c1_lo, fmaf(0.2f, e, c2_lo));
                float pL = ((mLo >> j) & 1u) ? fast_exp2(argL) : 0.f;
                aLo[j] = f2bf(pL);
            }
            const int fo = (kc * 4 + l4) * 512 + l15 * 8;
            short8 bw0 = *(const short8*)(fb + fo);
            short8 bw1 = *(const short8*)(fb + fo + 128);
            short8 bw2 = *(const short8*)(fb + fo + 256);
            short8 bw3 = *(const short8*)(fb + fo + 384);
            __builtin_amdgcn_s_setprio(1);
            accLo[0] = __builtin_amdgcn_mfma_f32_16x16x32_bf16(aLo, bw0, accLo[0], 0, 0, 0);
            accLo[1] = __builtin_amdgcn_mfma_f32_16x16x32_bf16(aLo, bw1, accLo[1], 0, 0, 0);
            accLo[2] = __builtin_amdgcn_mfma_f32_16x16x32_bf16(aLo, bw2, accLo[2], 0, 0, 0);
            accLo[3] = __builtin_amdgcn_mfma_f32_16x16x32_bf16(aLo, bw3, accLo[3], 0, 0, 0);
            dLo      = __builtin_amdgcn_mfma_f32_16x16x32_bf16(aLo, ones8, dLo, 0, 0, 0);
            __builtin_amdgcn_s_setprio(0);
        }
        if (tt < 15) {                      // land prefetch into the other buffer
            *(short8*)&f_lds[(tt + 1) & 1][tid * 8] = Ra;
            *(short8*)&f_lds[(tt + 1) & 1][2048 + tid * 8] = Rb;
        }
        __syncthreads();
    }

    // ---- epilogue: normalize, +res, +bias, (ELU), store bf16 in place ----
    float rcpLo[4];
    #pragma unroll
    for (int r = 0; r < 4; ++r)
        rcpLo[r] = 1.f / fmaxf(dLo[r], 1e-9f);     // jnp.clip(sum, 1e-9)
    #pragma unroll
    for (int dt = 0; dt < 4; ++dt) {
        const int d = dt * 16 + l15;
        const float bv = bias[h * 64 + d];
        #pragma unroll
        for (int r = 0; r < 4; ++r) {
            const int vl = v0 + wid * 16 + l4 * 4 + r;
            const size_t rowL = (bN + vl) * 256 + h * 64 + d;
            float ov = accLo[dt][r] * rcpLo[r] + bf2f(fea[rowL]) + bv;
            if (ELU_ON) ov = ov > 0.f ? ov : __expf(ov) - 1.f;
            fea[rowL] = f2bf(ov);
        }
    }
}

// ---------------- K5: mean over heads (bf16 in) -> d_out fp32 ----------------
__global__ __launch_bounds__(256) void k_headmean(
    const short* __restrict__ fea, float* __restrict__ outp)
{
    int i = blockIdx.x * 256 + threadIdx.x;     // i over B*N*64
    int d = i & 63;
    size_t node = (size_t)(i >> 6);
    const short* p = fea + node * 256;
    outp[i] = 0.25f * (bf2f(p[d]) + bf2f(p[64 + d]) + bf2f(p[128 + d]) + bf2f(p[192 + d]));
}

extern "C" void kernel_launch(void* const* d_in, const int* in_sizes, int n_in,
                              void* d_out, int out_size, void* d_ws, size_t ws_size,
                              hipStream_t stream) {
    const float* seg = (const float*)d_in[0];
    const float* adj = (const float*)d_in[1];
    const float* W0  = (const float*)d_in[2];
    const float* al0 = (const float*)d_in[3];
    const float* ar0 = (const float*)d_in[4];
    const float* rW0 = (const float*)d_in[5];
    const float* b0  = (const float*)d_in[6];
    const float* W1  = (const float*)d_in[7];
    const float* al1 = (const float*)d_in[8];
    const float* ar1 = (const float*)d_in[9];
    const float* rW1 = (const float*)d_in[10];
    const float* b1  = (const float*)d_in[11];
    float* out = (float*)d_out;

    char* ws = (char*)d_ws;
    size_t off = 0;
    uint64_t* mask  = (uint64_t*)ws;                 // 2 MB (dead after k_maskT)
    off += (size_t)BB * NN * 16 * 8;
    uint64_t* maskT = (uint64_t*)(ws + off); off += (size_t)BB * NN * 16 * 8;  // 2 MB
    short* ftb = (short*)(ws + off); off += (size_t)BB * 256 * NN * 2;         // 8 MB
    short* fea = (short*)(ws + off); off += (size_t)BB * NN * 256 * 2;         // 8 MB
    short* xb0 = (short*)(ws + off); off += (size_t)BB * NN * 64 * 2;          // 2 MB
    // small buffers reuse the dead `mask` region (valid after k_maskT completes)
    char* r0 = (char*)mask;
    short* Wt0  = (short*)r0;                 r0 += 256 * 64 * 2;
    short* rWt0 = (short*)r0;                 r0 += 256 * 64 * 2;
    short* Wt1  = (short*)r0;                 r0 += 256 * 256 * 2;
    short* rWt1 = (short*)r0;                 r0 += 256 * 256 * 2;
    float* el   = (float*)r0;                 r0 += (size_t)BB * 4 * NN * 4;
    float* er   = (float*)r0;                 r0 += (size_t)BB * 4 * NN * 4;

    k_topk_mask<<<BB * NN / 4, 256, 0, stream>>>(adj, mask);
    k_maskT<<<BB * 256 / 4, 256, 0, stream>>>(mask, maskT);
    // mask region now dead -> safe to fill Wt/el/er
    k_prepare<<<640 + BB * NN * 64 / 1024, 256, 0, stream>>>(
        W0, rW0, W1, rW1, seg, Wt0, rWt0, Wt1, rWt1, xb0);

    // layer 0 (K=64)
    k_features_mfma<64><<<BB * NN / 32, 256, 0, stream>>>(xb0, Wt0, rWt0, al0, ar0,
                                                          ftb, fea, el, er);
    k_attn<1><<<1024, 256, 0, stream>>>(ftb, el, er, maskT, b0, fea);
    // layer 1 (K=256): x = fea in-place (x fully LDS-resident before fea write)
    k_features_mfma<256><<<BB * NN / 32, 256, 0, stream>>>(fea, Wt1, rWt1, al1, ar1,
                                                           ftb, fea, el, er);
    k_attn<0><<<1024, 256, 0, stream>>>(ftb, el, er, maskT, b1, fea);

    k_headmean<<<BB * NN * 64 / 256, 256, 0, stream>>>(fea, out);
}

// Round 11
// 150.341 us; speedup vs baseline: 3.4757x; 1.0200x over previous
//
#include <hip/hip_runtime.h>
#include <hip/hip_bf16.h>
#include <stdint.h>

#define BB   16
#define NN   1024
#define KSEL 170   // (32*32)/6
#define LOG2E 1.4426950408889634f

typedef __attribute__((ext_vector_type(8))) short short8;
typedef __attribute__((ext_vector_type(4))) short short4v;
typedef __attribute__((ext_vector_type(4))) float f32x4;
typedef __attribute__((ext_vector_type(2))) float float2v;

static __device__ __forceinline__ short f2bf(float x) {
    __hip_bfloat16 h = __float2bfloat16(x);
    return *reinterpret_cast<short*>(&h);
}
static __device__ __forceinline__ float bf2f(short x) {
    uint32_t u = ((uint32_t)(uint16_t)x) << 16;
    return __uint_as_float(u);
}
static __device__ __forceinline__ float fast_exp2(float x) {
    float r; asm("v_exp_f32 %0, %1" : "=v"(r) : "v"(x)); return r;
}

// ---------------- K1: exact k-th-largest per row — ONE ROW PER WAVE ------------------
// 2 radix passes (16 prefix bits) + wave-uniform survivor max-extraction. Exact.
__global__ __launch_bounds__(256) void k_topk_mask(
    const float* __restrict__ adj, uint64_t* __restrict__ mask)
{
    const int wid = threadIdx.x >> 6, lane = threadIdx.x & 63;
    const int row = blockIdx.x * 4 + wid;              // b*N + u
    const float* a = adj + (size_t)row * NN;
    __shared__ uint32_t hist[4][256];
    uint32_t* h = hist[wid];

    uint32_t key[16];
    #pragma unroll
    for (int j = 0; j < 16; ++j) {
        uint32_t u = __float_as_uint(a[lane + j * 64]);
        key[j] = u ^ ((u >> 31) ? 0xFFFFFFFFu : 0x80000000u);   // order-preserving map
    }

    uint32_t prefix = 0u, kk = KSEL;
    #pragma unroll
    for (int pass = 0; pass < 2; ++pass) {
        const int shift = 24 - 8 * pass;
        const uint32_t hi_mask = pass ? 0xFF000000u : 0u;
        *(uint4*)&h[lane * 4] = make_uint4(0u, 0u, 0u, 0u);
        __builtin_amdgcn_wave_barrier();
        #pragma unroll
        for (int j = 0; j < 16; ++j)
            if ((key[j] & hi_mask) == prefix)
                atomicAdd(&h[(key[j] >> shift) & 255], 1u);
        __builtin_amdgcn_wave_barrier();
        const uint4 c4 = *(const uint4*)&h[lane * 4];  // bins 4L..4L+3
        const uint32_t T = c4.x + c4.y + c4.z + c4.w;
        uint32_t s = T;
        #pragma unroll
        for (int off = 1; off < 64; off <<= 1) {       // inclusive suffix sum over lanes
            uint32_t v = __shfl_down(s, off);
            s += (lane + off < 64) ? v : 0u;
        }
        const uint32_t E = s - T;                      // sum over lanes above
        const uint32_t s3 = c4.w;
        const uint32_t s2 = c4.z + s3;
        const uint32_t s1 = c4.y + s2;
        const uint32_t s0 = c4.x + s1;
        const uint32_t ci[4] = {c4.x, c4.y, c4.z, c4.w};
        const uint32_t si[4] = {s0, s1, s2, s3};
        uint32_t found = 0u, nb = 0u, nk = 0u;
        #pragma unroll
        for (int i = 0; i < 4; ++i) {
            uint32_t incl = E + si[i];                 // count of keys in bins >= this
            uint32_t excl = incl - ci[i];
            if (excl < kk && kk <= incl) { found = 1u; nb = (uint32_t)(lane * 4 + i); nk = kk - excl; }
        }
        uint64_t bal = __ballot(found != 0u);
        int wl = __ffsll((unsigned long long)bal) - 1; // exactly one winner
        prefix = prefix | ((uint32_t)__shfl((int)nb, wl) << shift);
        kk = (uint32_t)__shfl((int)nk, wl);
    }

    // ---- survivors share the 16-bit prefix; select kk-th largest exactly ----
    uint32_t sv[16];
    #pragma unroll
    for (int j = 0; j < 16; ++j)
        sv[j] = ((key[j] ^ prefix) >> 16) == 0u ? key[j] : 0u;   // 0 = sentinel

    uint32_t thr_key;
    for (;;) {
        uint32_t m = 0u;
        #pragma unroll
        for (int j = 0; j < 16; ++j) m = m > sv[j] ? m : sv[j];
        #pragma unroll
        for (int off = 1; off < 64; off <<= 1) {       // butterfly max -> uniform
            uint32_t v = __shfl_xor(m, off);
            m = m > v ? m : v;
        }
        if (m == 0u) { thr_key = 0u; break; }          // degenerate: thr = min key
        uint32_t c = 0u;
        #pragma unroll
        for (int j = 0; j < 16; ++j) c += (sv[j] == m) ? 1u : 0u;
        #pragma unroll
        for (int off = 1; off < 64; off <<= 1)
            c += __shfl_xor(c, off);                   // uniform count of == m
        if (kk <= c) { thr_key = m; break; }
        kk -= c;
        #pragma unroll
        for (int j = 0; j < 16; ++j) if (sv[j] == m) sv[j] = 0u;
    }

    #pragma unroll
    for (int j = 0; j < 16; ++j) {
        bool pred = (key[j] >= thr_key) && (key[j] > 0x80000000u);   // adj>=thr && adj>0
        uint64_t bal = __ballot(pred);
        if (lane == 0) mask[(size_t)row * 16 + j] = bal;
    }
}

// ---------------- K1b: merged mask transpose + weight prep + seg convert -------------
// blocks [0,1024): 64x64 bit-transpose of mask; [1024,1664): weight transposes;
// [1664,2688): seg fp32->bf16. (Wt buffers do NOT alias mask.)
__global__ __launch_bounds__(256) void k_mask_prep(
    const uint64_t* __restrict__ mask, uint64_t* __restrict__ maskT,
    const float* __restrict__ W0, const float* __restrict__ rW0,
    const float* __restrict__ W1, const float* __restrict__ rW1,
    const float* __restrict__ seg,
    short* __restrict__ Wt0, short* __restrict__ rWt0,
    short* __restrict__ Wt1, short* __restrict__ rWt1,
    short* __restrict__ xb0)
{
    const int bid = blockIdx.x, t = threadIdx.x;
    if (bid < 1024) {
        const int tile = bid * 4 + (t >> 6);           // b*256 + uw*16 + vw
        const int lane = t & 63;
        const int b  = tile >> 8;
        const int uw = (tile >> 4) & 15;
        const int vw = tile & 15;
        const size_t bN = (size_t)b * NN;
        uint64_t w = mask[(bN + uw * 64 + lane) * 16 + vw];
        uint64_t r_out = 0;
        #pragma unroll
        for (int j = 0; j < 64; ++j) {
            uint64_t r = __ballot((w >> j) & 1ull);
            if (lane == j) r_out = r;
        }
        maskT[(bN + vw * 64 + lane) * 16 + uw] = r_out;
    } else if (bid < 1088) {             // Wt0 [256][64]
        int idx = (bid - 1024) * 256 + t;
        int o = idx >> 6, k = idx & 63;
        Wt0[idx] = f2bf(W0[(size_t)k * 256 + o]);
    } else if (bid < 1152) {             // rWt0 [256][64]
        int idx = (bid - 1088) * 256 + t;
        int o = idx >> 6, k = idx & 63;
        rWt0[idx] = f2bf(rW0[(size_t)k * 256 + o]);
    } else if (bid < 1408) {             // Wt1 [256][256]
        int idx = (bid - 1152) * 256 + t;
        int o = idx >> 8, k = idx & 255;
        Wt1[idx] = f2bf(W1[(size_t)k * 256 + o]);
    } else if (bid < 1664) {             // rWt1 [256][256]
        int idx = (bid - 1408) * 256 + t;
        int o = idx >> 8, k = idx & 255;
        rWt1[idx] = f2bf(rW1[(size_t)k * 256 + o]);
    } else {                             // seg fp32 -> bf16 (1M elems, 4/thread)
        int i = ((bid - 1664) * 256 + t) * 4;
        float4 v = *(const float4*)(seg + i);
        short4v o4;
        o4[0] = f2bf(v.x); o4[1] = f2bf(v.y); o4[2] = f2bf(v.z); o4[3] = f2bf(v.w);
        *(short4v*)(xb0 + i) = o4;
    }
}

// ---------------- K2: MFMA features — 32 nodes/block, 1 head/wave --------------------
template<int K>
__global__ __launch_bounds__(256, 2) void k_features_mfma(
    const short* __restrict__ xb,   // [B*N][K] bf16 row-major
    const short* __restrict__ Wt,   // [256][K] bf16
    const short* __restrict__ rWt,  // [256][K] bf16
    const float* __restrict__ al,   // [256]
    const float* __restrict__ ar,   // [256]
    short* __restrict__ ft,         // tiled transposed features [bh][ut16][g8][d64][ui8]
    short* __restrict__ fea,        // [B*N][256] bf16: res written here (may alias xb)
    float* __restrict__ el_t,       // [(b*4+h)][NN] scaled by LOG2E
    float* __restrict__ er_t)       // [(b*4+h)][NN] scaled by LOG2E
{
    const int tid = threadIdx.x, lane = tid & 63, hh = tid >> 6;
    const int l15 = lane & 15, l4 = lane >> 4;
    const int n0 = blockIdx.x * 32;              // block's 32-node strip
    const int b_idx = n0 >> 10;                  // NN = 1024
    const int nloc = n0 & (NN - 1);
    const int bh = b_idx * 4 + hh;
    const int XP = K + 8;                        // padded LDS row stride (shorts)

    __shared__ short x_lds[32 * (K + 8)];

    const int CH = K / 8;                        // short8 chunks per row
    #pragma unroll
    for (int c = tid; c < 32 * CH; c += 256) {
        const int row = c / CH, col = c - row * CH;
        *(short8*)&x_lds[row * XP + col * 8] =
            *(const short8*)(xb + ((size_t)n0 + row) * K + col * 8);
    }
    __syncthreads();

    const short* wbase = Wt  + (size_t)(hh * 64 + l15) * K + l4 * 8;
    const short* rbase = rWt + (size_t)(hh * 64 + l15) * K + l4 * 8;
    const size_t qs = (size_t)16 * K;

    f32x4 accf[2][4], accr[2][4];
    #pragma unroll
    for (int s = 0; s < 2; ++s)
        #pragma unroll
        for (int q = 0; q < 4; ++q) {
            accf[s][q] = (f32x4){0.f, 0.f, 0.f, 0.f};
            accr[s][q] = (f32x4){0.f, 0.f, 0.f, 0.f};
        }

    short8 bufW[2][4], bufR[2][4];
    #pragma unroll
    for (int q = 0; q < 4; ++q) {
        bufW[0][q] = *(const short8*)(wbase + q * qs);
        bufR[0][q] = *(const short8*)(rbase + q * qs);
    }

    #pragma unroll
    for (int ks = 0; ks < K / 32; ++ks) {
        const int cur = ks & 1, nxt = cur ^ 1;
        if (ks + 1 < K / 32) {                   // prefetch next ks weight fragments
            #pragma unroll
            for (int q = 0; q < 4; ++q) {
                bufW[nxt][q] = *(const short8*)(wbase + q * qs + (ks + 1) * 32);
                bufR[nxt][q] = *(const short8*)(rbase + q * qs + (ks + 1) * 32);
            }
            __builtin_amdgcn_sched_barrier(0);   // pin load-issue before MFMA block
        }
        short8 x0 = *(const short8*)&x_lds[l15 * XP + ks * 32 + l4 * 8];
        short8 x1 = *(const short8*)&x_lds[(16 + l15) * XP + ks * 32 + l4 * 8];
        #pragma unroll
        for (int q = 0; q < 4; ++q) {
            accf[0][q] = __builtin_amdgcn_mfma_f32_16x16x32_bf16(x0, bufW[cur][q], accf[0][q], 0, 0, 0);
            accf[1][q] = __builtin_amdgcn_mfma_f32_16x16x32_bf16(x1, bufW[cur][q], accf[1][q], 0, 0, 0);
            accr[0][q] = __builtin_amdgcn_mfma_f32_16x16x32_bf16(bufR[cur][q], x0, accr[0][q], 0, 0, 0);
            accr[1][q] = __builtin_amdgcn_mfma_f32_16x16x32_bf16(bufR[cur][q], x1, accr[1][q], 0, 0, 0);
        }
    }

    #pragma unroll
    for (int s = 0; s < 2; ++s) {
        const int nl = nloc + s * 16;
        #pragma unroll
        for (int q = 0; q < 4; ++q) {
            short4v pk;
            #pragma unroll
            for (int r = 0; r < 4; ++r) pk[r] = f2bf(accf[s][q][r]);
            const int dl = q * 16 + l15;         // head-local d
            const size_t idx = ((size_t)bh << 16)
                             + (size_t)(nl >> 6) * 4096
                             + (size_t)(((nl & 63) >> 3) + (l4 >> 1)) * 512
                             + (size_t)dl * 8 + (l4 & 1) * 4;
            *(short4v*)(ft + idx) = pk;
        }
        float elv[4] = {0.f, 0.f, 0.f, 0.f}, erv[4] = {0.f, 0.f, 0.f, 0.f};
        #pragma unroll
        for (int q = 0; q < 4; ++q) {
            const float alv = al[hh * 64 + q * 16 + l15];
            const float arv = ar[hh * 64 + q * 16 + l15];
            #pragma unroll
            for (int r = 0; r < 4; ++r) {
                elv[r] = fmaf(accf[s][q][r], alv, elv[r]);
                erv[r] = fmaf(accf[s][q][r], arv, erv[r]);
            }
        }
        #pragma unroll
        for (int r = 0; r < 4; ++r) {
            #pragma unroll
            for (int off = 1; off < 16; off <<= 1) {
                elv[r] += __shfl_xor(elv[r], off);
                erv[r] += __shfl_xor(erv[r], off);
            }
        }
        if (l15 == 0) {                          // 4 lanes (l4=0..3), rows nl+l4*4+r
            float4 e4, r4;
            e4.x = elv[0] * LOG2E; e4.y = elv[1] * LOG2E;
            e4.z = elv[2] * LOG2E; e4.w = elv[3] * LOG2E;
            r4.x = erv[0] * LOG2E; r4.y = erv[1] * LOG2E;
            r4.z = erv[2] * LOG2E; r4.w = erv[3] * LOG2E;
            *(float4*)(el_t + (size_t)bh * NN + nl + l4 * 4) = e4;
            *(float4*)(er_t + (size_t)bh * NN + nl + l4 * 4) = r4;
        }
        #pragma unroll
        for (int q = 0; q < 4; ++q) {
            short4v pk;
            #pragma unroll
            for (int r = 0; r < 4; ++r) pk[r] = f2bf(accr[s][q][r]);
            *(short4v*)(fea + ((size_t)n0 + s * 16 + l15) * 256 + hh * 64 + q * 16 + l4 * 4) = pk;
        }
    }
}

// ---------------- K4: masked softmax + MFMA PV + residual + bias (+ELU) --------------
// 4 waves x 16 v (v-tile 64, grid 1024 = 4 blocks/CU); f-tile double-buffered in LDS.
// p-gen uses packed fp32 (float2 -> v_pk_*).
template<int ELU_ON>
__global__ __launch_bounds__(256, 4) void k_attn(
    const short* __restrict__ ft,     // tiled [bh][ut16][g8][d64][ui8]
    const float* __restrict__ el_t,   // [(b*4+h)][NN] scaled
    const float* __restrict__ er_t,   // [(b*4+h)][NN] scaled
    const uint64_t* __restrict__ maskT,// [b*N + v][16] u-words
    const float* __restrict__ bias,   // [256]
    short* fea)                       // [B*N][256] bf16: res in, out in-place
{
    // XCD swizzle: 1024 blocks, 128 per XCD (8 full bh strips per XCD)
    const int id = blockIdx.x;
    const int swz = (id & 7) * 128 + (id >> 3);
    const int b  = swz >> 6;
    const int h  = (swz >> 4) & 3;
    const int vt = swz & 15;
    const int tid = threadIdx.x;
    const int lane = tid & 63, wid = tid >> 6;
    const int l15 = lane & 15, l4 = lane >> 4;
    const int bh = b * 4 + h;
    const size_t bN = (size_t)b * NN;
    const int v0 = vt * 64;

    __shared__ __align__(16) short f_lds[2][4096];      // [buf][g*512 + d*8 + ui]
    __shared__ __align__(16) float el_lds[NN];
    __shared__ __align__(16) uint64_t m_lds[64 * 17];   // 136B row stride
    __shared__ float smax[4];

    const short* gsrc = ft + ((size_t)bh << 16);

    // ---- prologue staging: tile 0, el strip (+ block-local max), mask rows ----
    {
        short8 sa = *(const short8*)(gsrc + tid * 8);
        short8 sb = *(const short8*)(gsrc + 2048 + tid * 8);
        float4 ev4 = ((const float4*)(el_t + (size_t)bh * NN))[tid];
        ((float4*)el_lds)[tid] = ev4;
        float m = fmaxf(fmaxf(ev4.x, ev4.y), fmaxf(ev4.z, ev4.w));
        #pragma unroll
        for (int off = 32; off; off >>= 1) m = fmaxf(m, __shfl_xor(m, off));
        if (lane == 0) smax[wid] = m;
        #pragma unroll
        for (int i = 0; i < 4; ++i) {
            int idx = tid + i * 256;           // 1024 uint64 words
            m_lds[(idx >> 4) * 17 + (idx & 15)] =
                maskT[(bN + v0 + (idx >> 4)) * 16 + (idx & 15)];
        }
        *(short8*)&f_lds[0][tid * 8] = sa;
        *(short8*)&f_lds[0][2048 + tid * 8] = sb;
    }

    const int vlo = wid * 16 + l15;
    const float er_lo = er_t[(size_t)bh * NN + v0 + vlo];

    __syncthreads();

    const float emx = fmaxf(fmaxf(smax[0], smax[1]), fmaxf(smax[2], smax[3]));
    const float e0 = emx + er_lo;
    const float cv_lo = fmaxf(e0, 0.2f * e0);    // lrelu monotone -> valid shift
    const float c1_lo = er_lo - cv_lo, c2_lo = 0.2f * er_lo - cv_lo;
    const float2v c1s = {c1_lo, c1_lo};
    const float2v c2s = {c2_lo, c2_lo};
    const float2v k02 = {0.2f, 0.2f};

    const uint8_t* mbytes = (const uint8_t*)m_lds;
    const int moff_lo = vlo * 136;

    short8 ones8;
    #pragma unroll
    for (int i = 0; i < 8; ++i) ones8[i] = (short)0x3F80;   // bf16 1.0

    f32x4 accLo[4];
    #pragma unroll
    for (int i = 0; i < 4; ++i) accLo[i] = (f32x4){0.f, 0.f, 0.f, 0.f};
    f32x4 dLo = (f32x4){0.f, 0.f, 0.f, 0.f};

    short8 Ra, Rb;
    #pragma unroll 1
    for (int tt = 0; tt < 16; ++tt) {
        if (tt < 15) {                      // issue next-tile loads early (T14 split)
            Ra = *(const short8*)(gsrc + (tt + 1) * 4096 + tid * 8);
            Rb = *(const short8*)(gsrc + (tt + 1) * 4096 + 2048 + tid * 8);
            __builtin_amdgcn_sched_barrier(0);
        }
        const short* fb = f_lds[tt & 1];
        #pragma unroll
        for (int kc = 0; kc < 2; ++kc) {
            const float2v* ep2 = (const float2v*)&el_lds[tt * 64 + kc * 32 + l4 * 8];
            uint32_t mLo = mbytes[moff_lo + tt * 8 + kc * 4 + l4];
            short8 aLo;
            #pragma unroll
            for (int jj = 0; jj < 4; ++jj) {
                float2v e2 = ep2[jj];
                float2v arg = __builtin_elementwise_max(e2 + c1s, e2 * k02 + c2s);
                float p0 = ((mLo >> (2 * jj)) & 1u)     ? fast_exp2(arg.x) : 0.f;
                float p1 = ((mLo >> (2 * jj + 1)) & 1u) ? fast_exp2(arg.y) : 0.f;
                aLo[2 * jj]     = f2bf(p0);
                aLo[2 * jj + 1] = f2bf(p1);
            }
            const int fo = (kc * 4 + l4) * 512 + l15 * 8;
            short8 bw0 = *(const short8*)(fb + fo);
            short8 bw1 = *(const short8*)(fb + fo + 128);
            short8 bw2 = *(const short8*)(fb + fo + 256);
            short8 bw3 = *(const short8*)(fb + fo + 384);
            __builtin_amdgcn_s_setprio(1);
            accLo[0] = __builtin_amdgcn_mfma_f32_16x16x32_bf16(aLo, bw0, accLo[0], 0, 0, 0);
            accLo[1] = __builtin_amdgcn_mfma_f32_16x16x32_bf16(aLo, bw1, accLo[1], 0, 0, 0);
            accLo[2] = __builtin_amdgcn_mfma_f32_16x16x32_bf16(aLo, bw2, accLo[2], 0, 0, 0);
            accLo[3] = __builtin_amdgcn_mfma_f32_16x16x32_bf16(aLo, bw3, accLo[3], 0, 0, 0);
            dLo      = __builtin_amdgcn_mfma_f32_16x16x32_bf16(aLo, ones8, dLo, 0, 0, 0);
            __builtin_amdgcn_s_setprio(0);
        }
        if (tt < 15) {                      // land prefetch into the other buffer
            *(short8*)&f_lds[(tt + 1) & 1][tid * 8] = Ra;
            *(short8*)&f_lds[(tt + 1) & 1][2048 + tid * 8] = Rb;
        }
        __syncthreads();
    }

    // ---- epilogue: normalize, +res, +bias, (ELU), store bf16 in place ----
    float rcpLo[4];
    #pragma unroll
    for (int r = 0; r < 4; ++r)
        rcpLo[r] = 1.f / fmaxf(dLo[r], 1e-9f);     // jnp.clip(sum, 1e-9)
    #pragma unroll
    for (int dt = 0; dt < 4; ++dt) {
        const int d = dt * 16 + l15;
        const float bv = bias[h * 64 + d];
        #pragma unroll
        for (int r = 0; r < 4; ++r) {
            const int vl = v0 + wid * 16 + l4 * 4 + r;
            const size_t rowL = (bN + vl) * 256 + h * 64 + d;
            float ov = accLo[dt][r] * rcpLo[r] + bf2f(fea[rowL]) + bv;
            if (ELU_ON) ov = ov > 0.f ? ov : __expf(ov) - 1.f;
            fea[rowL] = f2bf(ov);
        }
    }
}

// ---------------- K5: mean over heads (bf16 in) -> d_out fp32, 8-wide ----------------
__global__ __launch_bounds__(256) void k_headmean(
    const short* __restrict__ fea, float* __restrict__ outp)
{
    const int i = (blockIdx.x * 256 + threadIdx.x) * 8;   // over B*N*64, 8 d's/thread
    const int d0 = i & 63;
    const size_t node = (size_t)(i >> 6);
    const short* p = fea + node * 256 + d0;
    short8 h0 = *(const short8*)(p);
    short8 h1 = *(const short8*)(p + 64);
    short8 h2 = *(const short8*)(p + 128);
    short8 h3 = *(const short8*)(p + 192);
    float4 o0, o1;
    #pragma unroll
    for (int j = 0; j < 4; ++j) {
        float v = 0.25f * (bf2f(h0[j]) + bf2f(h1[j]) + bf2f(h2[j]) + bf2f(h3[j]));
        (&o0.x)[j] = v;
    }
    #pragma unroll
    for (int j = 0; j < 4; ++j) {
        float v = 0.25f * (bf2f(h0[4 + j]) + bf2f(h1[4 + j]) + bf2f(h2[4 + j]) + bf2f(h3[4 + j]));
        (&o1.x)[j] = v;
    }
    *(float4*)(outp + i) = o0;
    *(float4*)(outp + i + 4) = o1;
}

extern "C" void kernel_launch(void* const* d_in, const int* in_sizes, int n_in,
                              void* d_out, int out_size, void* d_ws, size_t ws_size,
                              hipStream_t stream) {
    const float* seg = (const float*)d_in[0];
    const float* adj = (const float*)d_in[1];
    const float* W0  = (const float*)d_in[2];
    const float* al0 = (const float*)d_in[3];
    const float* ar0 = (const float*)d_in[4];
    const float* rW0 = (const float*)d_in[5];
    const float* b0  = (const float*)d_in[6];
    const float* W1  = (const float*)d_in[7];
    const float* al1 = (const float*)d_in[8];
    const float* ar1 = (const float*)d_in[9];
    const float* rW1 = (const float*)d_in[10];
    const float* b1  = (const float*)d_in[11];
    float* out = (float*)d_out;

    char* ws = (char*)d_ws;
    size_t off = 0;
    uint64_t* mask  = (uint64_t*)ws;                 // 2 MB (dead after k_mask_prep)
    off += (size_t)BB * NN * 16 * 8;
    uint64_t* maskT = (uint64_t*)(ws + off); off += (size_t)BB * NN * 16 * 8;  // 2 MB
    short* ftb = (short*)(ws + off); off += (size_t)BB * 256 * NN * 2;         // 8 MB
    short* fea = (short*)(ws + off); off += (size_t)BB * NN * 256 * 2;         // 8 MB
    short* xb0 = (short*)(ws + off); off += (size_t)BB * NN * 64 * 2;          // 2 MB
    short* Wt0  = (short*)(ws + off); off += 256 * 64 * 2;
    short* rWt0 = (short*)(ws + off); off += 256 * 64 * 2;
    short* Wt1  = (short*)(ws + off); off += 256 * 256 * 2;
    short* rWt1 = (short*)(ws + off); off += 256 * 256 * 2;
    // el/er reuse the dead `mask` region (mask consumed inside k_mask_prep)
    char* r0 = (char*)mask;
    float* el   = (float*)r0;                 r0 += (size_t)BB * 4 * NN * 4;
    float* er   = (float*)r0;                 r0 += (size_t)BB * 4 * NN * 4;

    k_topk_mask<<<BB * NN / 4, 256, 0, stream>>>(adj, mask);
    k_mask_prep<<<2688, 256, 0, stream>>>(mask, maskT, W0, rW0, W1, rW1, seg,
                                          Wt0, rWt0, Wt1, rWt1, xb0);

    // layer 0 (K=64)
    k_features_mfma<64><<<BB * NN / 32, 256, 0, stream>>>(xb0, Wt0, rWt0, al0, ar0,
                                                          ftb, fea, el, er);
    k_attn<1><<<1024, 256, 0, stream>>>(ftb, el, er, maskT, b0, fea);
    // layer 1 (K=256): x = fea in-place (x fully LDS-resident before fea write)
    k_features_mfma<256><<<BB * NN / 32, 256, 0, stream>>>(fea, Wt1, rWt1, al1, ar1,
                                                           ftb, fea, el, er);
    k_attn<0><<<1024, 256, 0, stream>>>(ftb, el, er, maskT, b1, fea);

    k_headmean<<<BB * NN * 64 / 2048, 256, 0, stream>>>(fea, out);
}

// Round 12
// 150.278 us; speedup vs baseline: 3.4772x; 1.0004x over previous
//
#include <hip/hip_runtime.h>
#include <hip/hip_bf16.h>
#include <stdint.h>

#define BB   16
#define NN   1024
#define KSEL 170   // (32*32)/6
#define LOG2E 1.4426950408889634f

typedef __attribute__((ext_vector_type(8))) short short8;
typedef __attribute__((ext_vector_type(4))) short short4v;
typedef __attribute__((ext_vector_type(4))) float f32x4;
typedef __attribute__((ext_vector_type(2))) float float2v;

static __device__ __forceinline__ short f2bf(float x) {
    __hip_bfloat16 h = __float2bfloat16(x);
    return *reinterpret_cast<short*>(&h);
}
static __device__ __forceinline__ float bf2f(short x) {
    uint32_t u = ((uint32_t)(uint16_t)x) << 16;
    return __uint_as_float(u);
}
static __device__ __forceinline__ float fast_exp2(float x) {
    float r; asm("v_exp_f32 %0, %1" : "=v"(r) : "v"(x)); return r;
}

// ---------------- K1: exact k-th-largest per row (one row/wave) + fused prep ---------
// blocks [0,4096): radix-2-pass top-k per row; blocks [4096,5760): independent prep
// (weight transposes fp32->bf16 + seg convert) folded in to fill the tail.
__global__ __launch_bounds__(256) void k_topk_mask(
    const float* __restrict__ adj, uint64_t* __restrict__ mask,
    const float* __restrict__ W0, const float* __restrict__ rW0,
    const float* __restrict__ W1, const float* __restrict__ rW1,
    const float* __restrict__ seg,
    short* __restrict__ Wt0, short* __restrict__ rWt0,
    short* __restrict__ Wt1, short* __restrict__ rWt1,
    short* __restrict__ xb0)
{
    const int bid = blockIdx.x, t = threadIdx.x;
    if (bid >= 4096) {                                 // ---- prep roles ----
        const int pid = bid - 4096;
        if (pid < 64) {                  // Wt0 [256][64]
            int idx = pid * 256 + t;
            int o = idx >> 6, k = idx & 63;
            Wt0[idx] = f2bf(W0[(size_t)k * 256 + o]);
        } else if (pid < 128) {          // rWt0 [256][64]
            int idx = (pid - 64) * 256 + t;
            int o = idx >> 6, k = idx & 63;
            rWt0[idx] = f2bf(rW0[(size_t)k * 256 + o]);
        } else if (pid < 384) {          // Wt1 [256][256]
            int idx = (pid - 128) * 256 + t;
            int o = idx >> 8, k = idx & 255;
            Wt1[idx] = f2bf(W1[(size_t)k * 256 + o]);
        } else if (pid < 640) {          // rWt1 [256][256]
            int idx = (pid - 384) * 256 + t;
            int o = idx >> 8, k = idx & 255;
            rWt1[idx] = f2bf(rW1[(size_t)k * 256 + o]);
        } else {                         // seg fp32 -> bf16 (1M elems, 4/thread)
            int i = ((pid - 640) * 256 + t) * 4;
            float4 v = *(const float4*)(seg + i);
            short4v o4;
            o4[0] = f2bf(v.x); o4[1] = f2bf(v.y); o4[2] = f2bf(v.z); o4[3] = f2bf(v.w);
            *(short4v*)(xb0 + i) = o4;
        }
        return;
    }

    const int wid = t >> 6, lane = t & 63;
    const int row = bid * 4 + wid;                     // b*N + u
    const float* a = adj + (size_t)row * NN;
    __shared__ uint32_t hist[4][256];
    uint32_t* h = hist[wid];

    uint32_t key[16];
    #pragma unroll
    for (int j = 0; j < 16; ++j) {
        uint32_t u = __float_as_uint(a[lane + j * 64]);
        key[j] = u ^ ((u >> 31) ? 0xFFFFFFFFu : 0x80000000u);   // order-preserving map
    }

    uint32_t prefix = 0u, kk = KSEL;
    #pragma unroll
    for (int pass = 0; pass < 2; ++pass) {
        const int shift = 24 - 8 * pass;
        const uint32_t hi_mask = pass ? 0xFF000000u : 0u;
        *(uint4*)&h[lane * 4] = make_uint4(0u, 0u, 0u, 0u);
        __builtin_amdgcn_wave_barrier();
        #pragma unroll
        for (int j = 0; j < 16; ++j)
            if ((key[j] & hi_mask) == prefix)
                atomicAdd(&h[(key[j] >> shift) & 255], 1u);
        __builtin_amdgcn_wave_barrier();
        const uint4 c4 = *(const uint4*)&h[lane * 4];  // bins 4L..4L+3
        const uint32_t T = c4.x + c4.y + c4.z + c4.w;
        uint32_t s = T;
        #pragma unroll
        for (int off = 1; off < 64; off <<= 1) {       // inclusive suffix sum over lanes
            uint32_t v = __shfl_down(s, off);
            s += (lane + off < 64) ? v : 0u;
        }
        const uint32_t E = s - T;                      // sum over lanes above
        const uint32_t s3 = c4.w;
        const uint32_t s2 = c4.z + s3;
        const uint32_t s1 = c4.y + s2;
        const uint32_t s0 = c4.x + s1;
        const uint32_t ci[4] = {c4.x, c4.y, c4.z, c4.w};
        const uint32_t si[4] = {s0, s1, s2, s3};
        uint32_t found = 0u, nb = 0u, nk = 0u;
        #pragma unroll
        for (int i = 0; i < 4; ++i) {
            uint32_t incl = E + si[i];                 // count of keys in bins >= this
            uint32_t excl = incl - ci[i];
            if (excl < kk && kk <= incl) { found = 1u; nb = (uint32_t)(lane * 4 + i); nk = kk - excl; }
        }
        uint64_t bal = __ballot(found != 0u);
        int wl = __ffsll((unsigned long long)bal) - 1; // exactly one winner
        prefix = prefix | ((uint32_t)__shfl((int)nb, wl) << shift);
        kk = (uint32_t)__shfl((int)nk, wl);
    }

    // ---- survivors share the 16-bit prefix; select kk-th largest exactly ----
    uint32_t sv[16];
    #pragma unroll
    for (int j = 0; j < 16; ++j)
        sv[j] = ((key[j] ^ prefix) >> 16) == 0u ? key[j] : 0u;   // 0 = sentinel

    uint32_t thr_key;
    for (;;) {
        uint32_t m = 0u;
        #pragma unroll
        for (int j = 0; j < 16; ++j) m = m > sv[j] ? m : sv[j];
        #pragma unroll
        for (int off = 1; off < 64; off <<= 1) {       // butterfly max -> uniform
            uint32_t v = __shfl_xor(m, off);
            m = m > v ? m : v;
        }
        if (m == 0u) { thr_key = 0u; break; }          // degenerate: thr = min key
        uint32_t c = 0u;
        #pragma unroll
        for (int j = 0; j < 16; ++j) c += (sv[j] == m) ? 1u : 0u;
        #pragma unroll
        for (int off = 1; off < 64; off <<= 1)
            c += __shfl_xor(c, off);                   // uniform count of == m
        if (kk <= c) { thr_key = m; break; }
        kk -= c;
        #pragma unroll
        for (int j = 0; j < 16; ++j) if (sv[j] == m) sv[j] = 0u;
    }

    #pragma unroll
    for (int j = 0; j < 16; ++j) {
        bool pred = (key[j] >= thr_key) && (key[j] > 0x80000000u);   // adj>=thr && adj>0
        uint64_t bal = __ballot(pred);
        if (lane == 0) mask[(size_t)row * 16 + j] = bal;
    }
}

// ---------------- K1b: 64x64 bit-transpose of the mask (ballot-based) ----------------
__global__ __launch_bounds__(256) void k_maskT(
    const uint64_t* __restrict__ mask, uint64_t* __restrict__ maskT)
{
    const int tile = blockIdx.x * 4 + (threadIdx.x >> 6);  // b*256 + uw*16 + vw
    const int lane = threadIdx.x & 63;
    const int b  = tile >> 8;
    const int uw = (tile >> 4) & 15;
    const int vw = tile & 15;
    const size_t bN = (size_t)b * NN;
    uint64_t w = mask[(bN + uw * 64 + lane) * 16 + vw];
    uint64_t r_out = 0;
    #pragma unroll
    for (int j = 0; j < 64; ++j) {
        uint64_t r = __ballot((w >> j) & 1ull);
        if (lane == j) r_out = r;
    }
    maskT[(bN + vw * 64 + lane) * 16 + uw] = r_out;
}

// ---------------- K2: MFMA features — 32 nodes/block, 1 head/wave --------------------
template<int K>
__global__ __launch_bounds__(256, 2) void k_features_mfma(
    const short* __restrict__ xb,   // [B*N][K] bf16 row-major
    const short* __restrict__ Wt,   // [256][K] bf16
    const short* __restrict__ rWt,  // [256][K] bf16
    const float* __restrict__ al,   // [256]
    const float* __restrict__ ar,   // [256]
    short* __restrict__ ft,         // tiled transposed features [bh][ut16][g8][d64][ui8]
    short* __restrict__ fea,        // [B*N][256] bf16: res written here (may alias xb)
    float* __restrict__ el_t,       // [(b*4+h)][NN] scaled by LOG2E
    float* __restrict__ er_t)       // [(b*4+h)][NN] scaled by LOG2E
{
    const int tid = threadIdx.x, lane = tid & 63, hh = tid >> 6;
    const int l15 = lane & 15, l4 = lane >> 4;
    const int n0 = blockIdx.x * 32;              // block's 32-node strip
    const int b_idx = n0 >> 10;                  // NN = 1024
    const int nloc = n0 & (NN - 1);
    const int bh = b_idx * 4 + hh;
    const int XP = K + 8;                        // padded LDS row stride (shorts)

    __shared__ short x_lds[32 * (K + 8)];

    const int CH = K / 8;                        // short8 chunks per row
    #pragma unroll
    for (int c = tid; c < 32 * CH; c += 256) {
        const int row = c / CH, col = c - row * CH;
        *(short8*)&x_lds[row * XP + col * 8] =
            *(const short8*)(xb + ((size_t)n0 + row) * K + col * 8);
    }
    __syncthreads();

    const short* wbase = Wt  + (size_t)(hh * 64 + l15) * K + l4 * 8;
    const short* rbase = rWt + (size_t)(hh * 64 + l15) * K + l4 * 8;
    const size_t qs = (size_t)16 * K;

    f32x4 accf[2][4], accr[2][4];
    #pragma unroll
    for (int s = 0; s < 2; ++s)
        #pragma unroll
        for (int q = 0; q < 4; ++q) {
            accf[s][q] = (f32x4){0.f, 0.f, 0.f, 0.f};
            accr[s][q] = (f32x4){0.f, 0.f, 0.f, 0.f};
        }

    short8 bufW[2][4], bufR[2][4];
    #pragma unroll
    for (int q = 0; q < 4; ++q) {
        bufW[0][q] = *(const short8*)(wbase + q * qs);
        bufR[0][q] = *(const short8*)(rbase + q * qs);
    }

    #pragma unroll
    for (int ks = 0; ks < K / 32; ++ks) {
        const int cur = ks & 1, nxt = cur ^ 1;
        if (ks + 1 < K / 32) {                   // prefetch next ks weight fragments
            #pragma unroll
            for (int q = 0; q < 4; ++q) {
                bufW[nxt][q] = *(const short8*)(wbase + q * qs + (ks + 1) * 32);
                bufR[nxt][q] = *(const short8*)(rbase + q * qs + (ks + 1) * 32);
            }
            __builtin_amdgcn_sched_barrier(0);   // pin load-issue before MFMA block
        }
        short8 x0 = *(const short8*)&x_lds[l15 * XP + ks * 32 + l4 * 8];
        short8 x1 = *(const short8*)&x_lds[(16 + l15) * XP + ks * 32 + l4 * 8];
        #pragma unroll
        for (int q = 0; q < 4; ++q) {
            accf[0][q] = __builtin_amdgcn_mfma_f32_16x16x32_bf16(x0, bufW[cur][q], accf[0][q], 0, 0, 0);
            accf[1][q] = __builtin_amdgcn_mfma_f32_16x16x32_bf16(x1, bufW[cur][q], accf[1][q], 0, 0, 0);
            accr[0][q] = __builtin_amdgcn_mfma_f32_16x16x32_bf16(bufR[cur][q], x0, accr[0][q], 0, 0, 0);
            accr[1][q] = __builtin_amdgcn_mfma_f32_16x16x32_bf16(bufR[cur][q], x1, accr[1][q], 0, 0, 0);
        }
    }

    #pragma unroll
    for (int s = 0; s < 2; ++s) {
        const int nl = nloc + s * 16;
        #pragma unroll
        for (int q = 0; q < 4; ++q) {
            short4v pk;
            #pragma unroll
            for (int r = 0; r < 4; ++r) pk[r] = f2bf(accf[s][q][r]);
            const int dl = q * 16 + l15;         // head-local d
            const size_t idx = ((size_t)bh << 16)
                             + (size_t)(nl >> 6) * 4096
                             + (size_t)(((nl & 63) >> 3) + (l4 >> 1)) * 512
                             + (size_t)dl * 8 + (l4 & 1) * 4;
            *(short4v*)(ft + idx) = pk;
        }
        float elv[4] = {0.f, 0.f, 0.f, 0.f}, erv[4] = {0.f, 0.f, 0.f, 0.f};
        #pragma unroll
        for (int q = 0; q < 4; ++q) {
            const float alv = al[hh * 64 + q * 16 + l15];
            const float arv = ar[hh * 64 + q * 16 + l15];
            #pragma unroll
            for (int r = 0; r < 4; ++r) {
                elv[r] = fmaf(accf[s][q][r], alv, elv[r]);
                erv[r] = fmaf(accf[s][q][r], arv, erv[r]);
            }
        }
        #pragma unroll
        for (int r = 0; r < 4; ++r) {
            #pragma unroll
            for (int off = 1; off < 16; off <<= 1) {
                elv[r] += __shfl_xor(elv[r], off);
                erv[r] += __shfl_xor(erv[r], off);
            }
        }
        if (l15 == 0) {                          // 4 lanes (l4=0..3), rows nl+l4*4+r
            float4 e4, r4;
            e4.x = elv[0] * LOG2E; e4.y = elv[1] * LOG2E;
            e4.z = elv[2] * LOG2E; e4.w = elv[3] * LOG2E;
            r4.x = erv[0] * LOG2E; r4.y = erv[1] * LOG2E;
            r4.z = erv[2] * LOG2E; r4.w = erv[3] * LOG2E;
            *(float4*)(el_t + (size_t)bh * NN + nl + l4 * 4) = e4;
            *(float4*)(er_t + (size_t)bh * NN + nl + l4 * 4) = r4;
        }
        #pragma unroll
        for (int q = 0; q < 4; ++q) {
            short4v pk;
            #pragma unroll
            for (int r = 0; r < 4; ++r) pk[r] = f2bf(accr[s][q][r]);
            *(short4v*)(fea + ((size_t)n0 + s * 16 + l15) * 256 + hh * 64 + q * 16 + l4 * 4) = pk;
        }
    }
}

// ---------------- K4: masked softmax + MFMA PV + residual + bias (+ELU) --------------
// 4 waves x 16 v; f-tile TRIPLE-buffered in LDS, 2-deep prefetch: loads for tile t+2
// issue at iter t; the ds_write at iter t consumes data loaded a full iteration ago.
template<int ELU_ON>
__global__ __launch_bounds__(256, 4) void k_attn(
    const short* __restrict__ ft,     // tiled [bh][ut16][g8][d64][ui8]
    const float* __restrict__ el_t,   // [(b*4+h)][NN] scaled
    const float* __restrict__ er_t,   // [(b*4+h)][NN] scaled
    const uint64_t* __restrict__ maskT,// [b*N + v][16] u-words
    const float* __restrict__ bias,   // [256]
    short* fea)                       // [B*N][256] bf16: res in, out in-place
{
    // XCD swizzle: 1024 blocks, 128 per XCD (8 full bh strips per XCD)
    const int id = blockIdx.x;
    const int swz = (id & 7) * 128 + (id >> 3);
    const int b  = swz >> 6;
    const int h  = (swz >> 4) & 3;
    const int vt = swz & 15;
    const int tid = threadIdx.x;
    const int lane = tid & 63, wid = tid >> 6;
    const int l15 = lane & 15, l4 = lane >> 4;
    const int bh = b * 4 + h;
    const size_t bN = (size_t)b * NN;
    const int v0 = vt * 64;

    __shared__ __align__(16) short f_lds[3][4096];      // [buf][g*512 + d*8 + ui]
    __shared__ __align__(16) float el_lds[NN];
    __shared__ __align__(16) uint64_t m_lds[64 * 17];   // 136B row stride
    __shared__ float smax[4];

    const short* gsrc = ft + ((size_t)bh << 16);

    // ---- prologue staging: tile 0 -> buf0, el strip (+ block max), mask rows ----
    {
        short8 sa = *(const short8*)(gsrc + tid * 8);
        short8 sb = *(const short8*)(gsrc + 2048 + tid * 8);
        float4 ev4 = ((const float4*)(el_t + (size_t)bh * NN))[tid];
        ((float4*)el_lds)[tid] = ev4;
        float m = fmaxf(fmaxf(ev4.x, ev4.y), fmaxf(ev4.z, ev4.w));
        #pragma unroll
        for (int off = 32; off; off >>= 1) m = fmaxf(m, __shfl_xor(m, off));
        if (lane == 0) smax[wid] = m;
        #pragma unroll
        for (int i = 0; i < 4; ++i) {
            int idx = tid + i * 256;           // 1024 uint64 words
            m_lds[(idx >> 4) * 17 + (idx & 15)] =
                maskT[(bN + v0 + (idx >> 4)) * 16 + (idx & 15)];
        }
        *(short8*)&f_lds[0][tid * 8] = sa;
        *(short8*)&f_lds[0][2048 + tid * 8] = sb;
    }

    // prefetch tile 1 into register set A (lands during barrier + constants)
    short8 Aa = *(const short8*)(gsrc + 4096 + tid * 8);
    short8 Ab = *(const short8*)(gsrc + 4096 + 2048 + tid * 8);

    const int vlo = wid * 16 + l15;
    const float er_lo = er_t[(size_t)bh * NN + v0 + vlo];

    __syncthreads();

    const float emx = fmaxf(fmaxf(smax[0], smax[1]), fmaxf(smax[2], smax[3]));
    const float e0 = emx + er_lo;
    const float cv_lo = fmaxf(e0, 0.2f * e0);    // lrelu monotone -> valid shift
    const float c1_lo = er_lo - cv_lo, c2_lo = 0.2f * er_lo - cv_lo;
    const float2v c1s = {c1_lo, c1_lo};
    const float2v c2s = {c2_lo, c2_lo};
    const float2v k02 = {0.2f, 0.2f};

    const uint8_t* mbytes = (const uint8_t*)m_lds;
    const int moff_lo = vlo * 136;

    short8 ones8;
    #pragma unroll
    for (int i = 0; i < 8; ++i) ones8[i] = (short)0x3F80;   // bf16 1.0

    f32x4 accLo[4];
    #pragma unroll
    for (int i = 0; i < 4; ++i) accLo[i] = (f32x4){0.f, 0.f, 0.f, 0.f};
    f32x4 dLo = (f32x4){0.f, 0.f, 0.f, 0.f};

    auto compute = [&](const short* fb, int tt) {
        #pragma unroll
        for (int kc = 0; kc < 2; ++kc) {
            const float2v* ep2 = (const float2v*)&el_lds[tt * 64 + kc * 32 + l4 * 8];
            uint32_t mLo = mbytes[moff_lo + tt * 8 + kc * 4 + l4];
            short8 aLo;
            #pragma unroll
            for (int jj = 0; jj < 4; ++jj) {
                float2v e2 = ep2[jj];
                float2v arg = __builtin_elementwise_max(e2 + c1s, e2 * k02 + c2s);
                float p0 = ((mLo >> (2 * jj)) & 1u)     ? fast_exp2(arg.x) : 0.f;
                float p1 = ((mLo >> (2 * jj + 1)) & 1u) ? fast_exp2(arg.y) : 0.f;
                aLo[2 * jj]     = f2bf(p0);
                aLo[2 * jj + 1] = f2bf(p1);
            }
            const int fo = (kc * 4 + l4) * 512 + l15 * 8;
            short8 bw0 = *(const short8*)(fb + fo);
            short8 bw1 = *(const short8*)(fb + fo + 128);
            short8 bw2 = *(const short8*)(fb + fo + 256);
            short8 bw3 = *(const short8*)(fb + fo + 384);
            __builtin_amdgcn_s_setprio(1);
            accLo[0] = __builtin_amdgcn_mfma_f32_16x16x32_bf16(aLo, bw0, accLo[0], 0, 0, 0);
            accLo[1] = __builtin_amdgcn_mfma_f32_16x16x32_bf16(aLo, bw1, accLo[1], 0, 0, 0);
            accLo[2] = __builtin_amdgcn_mfma_f32_16x16x32_bf16(aLo, bw2, accLo[2], 0, 0, 0);
            accLo[3] = __builtin_amdgcn_mfma_f32_16x16x32_bf16(aLo, bw3, accLo[3], 0, 0, 0);
            dLo      = __builtin_amdgcn_mfma_f32_16x16x32_bf16(aLo, ones8, dLo, 0, 0, 0);
            __builtin_amdgcn_s_setprio(0);
        }
    };

    short8 Ba, Bb;
    #pragma unroll 1
    for (int tt = 0; tt < 16; tt += 2) {
        // ---- even iteration tt ----
        if (tt + 2 < 16) {                  // issue loads for tile tt+2
            Ba = *(const short8*)(gsrc + (tt + 2) * 4096 + tid * 8);
            Bb = *(const short8*)(gsrc + (tt + 2) * 4096 + 2048 + tid * 8);
            __builtin_amdgcn_sched_barrier(0);
        }
        compute(f_lds[tt % 3], tt);
        {   // land tile tt+1 (loaded one full iteration ago)
            short* dst = f_lds[(tt + 1) % 3];
            *(short8*)&dst[tid * 8] = Aa;
            *(short8*)&dst[2048 + tid * 8] = Ab;
        }
        __syncthreads();
        // ---- odd iteration tt+1 ----
        if (tt + 3 < 16) {                  // issue loads for tile tt+3
            Aa = *(const short8*)(gsrc + (tt + 3) * 4096 + tid * 8);
            Ab = *(const short8*)(gsrc + (tt + 3) * 4096 + 2048 + tid * 8);
            __builtin_amdgcn_sched_barrier(0);
        }
        compute(f_lds[(tt + 1) % 3], tt + 1);
        if (tt + 2 < 16) {                  // land tile tt+2
            short* dst = f_lds[(tt + 2) % 3];
            *(short8*)&dst[tid * 8] = Ba;
            *(short8*)&dst[2048 + tid * 8] = Bb;
            __syncthreads();
        }
    }

    // ---- epilogue: normalize, +res, +bias, (ELU), store bf16 in place ----
    float rcpLo[4];
    #pragma unroll
    for (int r = 0; r < 4; ++r)
        rcpLo[r] = 1.f / fmaxf(dLo[r], 1e-9f);     // jnp.clip(sum, 1e-9)
    #pragma unroll
    for (int dt = 0; dt < 4; ++dt) {
        const int d = dt * 16 + l15;
        const float bv = bias[h * 64 + d];
        #pragma unroll
        for (int r = 0; r < 4; ++r) {
            const int vl = v0 + wid * 16 + l4 * 4 + r;
            const size_t rowL = (bN + vl) * 256 + h * 64 + d;
            float ov = accLo[dt][r] * rcpLo[r] + bf2f(fea[rowL]) + bv;
            if (ELU_ON) ov = ov > 0.f ? ov : __expf(ov) - 1.f;
            fea[rowL] = f2bf(ov);
        }
    }
}

// ---------------- K5: mean over heads (bf16 in) -> d_out fp32, 8-wide ----------------
__global__ __launch_bounds__(256) void k_headmean(
    const short* __restrict__ fea, float* __restrict__ outp)
{
    const int i = (blockIdx.x * 256 + threadIdx.x) * 8;   // over B*N*64, 8 d's/thread
    const int d0 = i & 63;
    const size_t node = (size_t)(i >> 6);
    const short* p = fea + node * 256 + d0;
    short8 h0 = *(const short8*)(p);
    short8 h1 = *(const short8*)(p + 64);
    short8 h2 = *(const short8*)(p + 128);
    short8 h3 = *(const short8*)(p + 192);
    float4 o0, o1;
    #pragma unroll
    for (int j = 0; j < 4; ++j) {
        float v = 0.25f * (bf2f(h0[j]) + bf2f(h1[j]) + bf2f(h2[j]) + bf2f(h3[j]));
        (&o0.x)[j] = v;
    }
    #pragma unroll
    for (int j = 0; j < 4; ++j) {
        float v = 0.25f * (bf2f(h0[4 + j]) + bf2f(h1[4 + j]) + bf2f(h2[4 + j]) + bf2f(h3[4 + j]));
        (&o1.x)[j] = v;
    }
    *(float4*)(outp + i) = o0;
    *(float4*)(outp + i + 4) = o1;
}

extern "C" void kernel_launch(void* const* d_in, const int* in_sizes, int n_in,
                              void* d_out, int out_size, void* d_ws, size_t ws_size,
                              hipStream_t stream) {
    const float* seg = (const float*)d_in[0];
    const float* adj = (const float*)d_in[1];
    const float* W0  = (const float*)d_in[2];
    const float* al0 = (const float*)d_in[3];
    const float* ar0 = (const float*)d_in[4];
    const float* rW0 = (const float*)d_in[5];
    const float* b0  = (const float*)d_in[6];
    const float* W1  = (const float*)d_in[7];
    const float* al1 = (const float*)d_in[8];
    const float* ar1 = (const float*)d_in[9];
    const float* rW1 = (const float*)d_in[10];
    const float* b1  = (const float*)d_in[11];
    float* out = (float*)d_out;

    char* ws = (char*)d_ws;
    size_t off = 0;
    uint64_t* mask  = (uint64_t*)ws;                 // 2 MB (dead after k_maskT)
    off += (size_t)BB * NN * 16 * 8;
    uint64_t* maskT = (uint64_t*)(ws + off); off += (size_t)BB * NN * 16 * 8;  // 2 MB
    short* ftb = (short*)(ws + off); off += (size_t)BB * 256 * NN * 2;         // 8 MB
    short* fea = (short*)(ws + off); off += (size_t)BB * NN * 256 * 2;         // 8 MB
    short* xb0 = (short*)(ws + off); off += (size_t)BB * NN * 64 * 2;          // 2 MB
    short* Wt0  = (short*)(ws + off); off += 256 * 64 * 2;
    short* rWt0 = (short*)(ws + off); off += 256 * 64 * 2;
    short* Wt1  = (short*)(ws + off); off += 256 * 256 * 2;
    short* rWt1 = (short*)(ws + off); off += 256 * 256 * 2;
    // el/er reuse the dead `mask` region (mask consumed by k_maskT)
    char* r0 = (char*)mask;
    float* el   = (float*)r0;                 r0 += (size_t)BB * 4 * NN * 4;
    float* er   = (float*)r0;                 r0 += (size_t)BB * 4 * NN * 4;

    k_topk_mask<<<4096 + 1664, 256, 0, stream>>>(adj, mask, W0, rW0, W1, rW1, seg,
                                                 Wt0, rWt0, Wt1, rWt1, xb0);
    k_maskT<<<1024, 256, 0, stream>>>(mask, maskT);

    // layer 0 (K=64)
    k_features_mfma<64><<<BB * NN / 32, 256, 0, stream>>>(xb0, Wt0, rWt0, al0, ar0,
                                                          ftb, fea, el, er);
    k_attn<1><<<1024, 256, 0, stream>>>(ftb, el, er, maskT, b0, fea);
    // layer 1 (K=256): x = fea in-place (x fully LDS-resident before fea write)
    k_features_mfma<256><<<BB * NN / 32, 256, 0, stream>>>(fea, Wt1, rWt1, al1, ar1,
                                                           ftb, fea, el, er);
    k_attn<0><<<1024, 256, 0, stream>>>(ftb, el, er, maskT, b1, fea);

    k_headmean<<<BB * NN * 64 / 2048, 256, 0, stream>>>(fea, out);
}